// Round 9
// baseline (1656.897 us; speedup 1.0000x reference)
//
#include <hip/hip_runtime.h>
#include <hip/hip_bf16.h>
#include <cstdint>

typedef float f32x4 __attribute__((ext_vector_type(4)));
typedef __bf16 bf16x8 __attribute__((ext_vector_type(8)));

// ---------- bf16 pack helpers (RNE) ----------
__device__ __forceinline__ uint32_t bf1(float x) {
  uint32_t u = __float_as_uint(x);
  return (u + 0x7fffu + ((u >> 16) & 1u)) >> 16;
}
__device__ __forceinline__ uint32_t bpack(float lo, float hi) {
  return bf1(lo) | (bf1(hi) << 16);
}
__device__ __forceinline__ float blo(uint32_t u) { return __uint_as_float(u << 16); }
__device__ __forceinline__ float bhi(uint32_t u) { return __uint_as_float(u & 0xffff0000u); }
__device__ __forceinline__ float sigm(float x) {
  return __fdividef(1.f, 1.f + exp2f(x * -1.4426950408889634f));
}
__device__ __forceinline__ float tanhf_fast(float x) {
  float e2 = exp2f(x * 2.8853900817779268f);
  return 1.f - __fdividef(2.f, e2 + 1.f);
}

// packed-bf16 dot2: acc += a.lo*b.lo + a.hi*b.hi (fp32 accumulate)
__device__ __forceinline__ float dot2bf(uint32_t a, uint32_t b, float acc) {
  asm("v_dot2_f32_bf16 %0, %1, %2, %0" : "+v"(acc) : "v"(a), "v"(b));
  return acc;
}

#define GLOAD_LDS16(g, l)                                                     \
  __builtin_amdgcn_global_load_lds(                                           \
      (const __attribute__((address_space(1))) void*)(g),                     \
      (__attribute__((address_space(3))) void*)(l), 16, 0, 0)

// =====================================================================
// K0: all weight packing in one launch.
// bid<4096: Whf/Whb -> [dir][blk=128][64 k4p][16 c][4 e], col=(c>>2)*512+blk*4+(c&3)
// bid<6144: Whd -> [ug=64][64 q4][32 cc][4 e], col=(cc>>3)*512+ug*8+(cc&7)
// else:     W1[0:1536,:10] bf16-paired -> [768 q][12 j]
// =====================================================================
__global__ __launch_bounds__(256) void k0_pack(
    const float* __restrict__ Whf, const float* __restrict__ Whb,
    uint32_t* __restrict__ Wencp, const float* __restrict__ Whd,
    uint32_t* __restrict__ Wdp, const float* __restrict__ W1,
    uint32_t* __restrict__ W1pbAll)
{
  int bid = blockIdx.x;
  if (bid < 4096) {
    int p = bid * 256 + threadIdx.x;             // 0..2^20-1
    int e = p & 3, c = (p >> 2) & 15, k4p = (p >> 6) & 63;
    int blk = (p >> 12) & 127, dir = p >> 19;
    int k2 = 4 * k4p + e;
    const float* W = dir ? Whb : Whf;
    int col = (c >> 2) * 512 + blk * 4 + (c & 3);
    Wencp[p] = bpack(W[(size_t)(2 * k2) * 2048 + col],
                     W[(size_t)(2 * k2 + 1) * 2048 + col]);
  } else if (bid < 6144) {
    int p = (bid - 4096) * 256 + threadIdx.x;    // 0..524287
    int e = p & 3, cc = (p >> 2) & 31, q4 = (p >> 7) & 63, ug = p >> 13;
    int k2 = 4 * q4 + e;
    int col = (cc >> 3) * 512 + ug * 8 + (cc & 7);
    int k = 2 * k2;
    Wdp[p] = bpack(Whd[(size_t)k * 2048 + col], Whd[(size_t)(k + 1) * 2048 + col]);
  } else {
    int p = (bid - 6144) * 256 + threadIdx.x;    // 0..9215
    if (p < 9216) {
      int q = p / 12, j = p % 12;
      float v0 = (j < 10) ? W1[(size_t)(2 * q) * 10 + j] : 0.f;
      float v1 = (j < 10) ? W1[(size_t)(2 * q + 1) * 10 + j] : 0.f;
      W1pbAll[p] = bpack(v0, v1);
    }
  }
}

// =====================================================================
// K1: embedding gather + Xf = xe@Wxf + bf, Xb = xe@Wxb + bb (fp32 VALU)
// =====================================================================
__global__ __launch_bounds__(256) void k1_embed_gemm(
    const int* __restrict__ x, const float* __restrict__ emb,
    const float* __restrict__ Wxf, const float* __restrict__ Wxb,
    const float* __restrict__ bfv, const float* __restrict__ bbv,
    float* __restrict__ Xf, float* __restrict__ Xb)
{
  __shared__ float As[32 * 260];
  __shared__ float Bs[32 * 128];
  __shared__ int xid[32];
  const int t = threadIdx.x;
  const int ty = blockIdx.y;
  const int c0 = blockIdx.x * 128;
  if (t < 32) xid[t] = x[t * 64 + ty];
  __syncthreads();
  for (int i = 0; i < 8; ++i) {
    int f4 = t + 256 * i;
    int r = f4 >> 6, k4 = (f4 & 63) << 2;
    float4 v = *(const float4*)(emb + (size_t)xid[r] * 256 + k4);
    *(float4*)(&As[r * 260 + k4]) = v;
  }
  const int isB = (c0 >= 2048);
  const float* Wsrc = isB ? Wxb : Wxf;
  const float* bias = isB ? bbv : bfv;
  const int cbase = c0 & 2047;
  float acc[4][4] = {};
  const int rq = t >> 5;
  const int cq = t & 31;
  for (int kc = 0; kc < 8; ++kc) {
    int k0 = kc * 32;
    __syncthreads();
    for (int i = 0; i < 4; ++i) {
      int f4 = t + 256 * i;
      int k = f4 >> 5, c4 = (f4 & 31) << 2;
      *(float4*)(&Bs[k * 128 + c4]) =
          *(const float4*)(Wsrc + (size_t)(k0 + k) * 2048 + cbase + c4);
    }
    __syncthreads();
#pragma unroll
    for (int kk = 0; kk < 32; ++kk) {
      float a0 = As[(4 * rq + 0) * 260 + k0 + kk];
      float a1 = As[(4 * rq + 1) * 260 + k0 + kk];
      float a2 = As[(4 * rq + 2) * 260 + k0 + kk];
      float a3 = As[(4 * rq + 3) * 260 + k0 + kk];
      float4 b = *(const float4*)(&Bs[kk * 128 + 4 * cq]);
      acc[0][0] += a0 * b.x; acc[0][1] += a0 * b.y; acc[0][2] += a0 * b.z; acc[0][3] += a0 * b.w;
      acc[1][0] += a1 * b.x; acc[1][1] += a1 * b.y; acc[1][2] += a1 * b.z; acc[1][3] += a1 * b.w;
      acc[2][0] += a2 * b.x; acc[2][1] += a2 * b.y; acc[2][2] += a2 * b.z; acc[2][3] += a2 * b.w;
      acc[3][0] += a3 * b.x; acc[3][1] += a3 * b.y; acc[3][2] += a3 * b.z; acc[3][3] += a3 * b.w;
    }
  }
  float* Xout = isB ? Xb : Xf;
  for (int i = 0; i < 4; ++i) {
    int c = cbase + 4 * cq + i;
    float bi = bias[c];
    for (int j = 0; j < 4; ++j) {
      int b_ = 4 * rq + j;
      Xout[((size_t)ty * 2048 + c) * 32 + b_] = acc[j][i] + bi;
    }
  }
}

// =====================================================================
// K2: one encoder step both dirs; 256 blocks (4 units each), 2-cc
// register blocking: per iter 1 h-quad + 2 broadcast W-quads -> 8 dot2.
// =====================================================================
__global__ __launch_bounds__(256) void k2_enc_step(
    const float* __restrict__ Xf, const float* __restrict__ Xb,
    const uint32_t* __restrict__ Wencp,
    const uint32_t* __restrict__ hfi, uint32_t* __restrict__ hfo,
    const uint32_t* __restrict__ hbi, uint32_t* __restrict__ hbo,
    float* __restrict__ cf, float* __restrict__ cb,
    ushort* __restrict__ aB, int step)
{
  __shared__ uint32_t hTp[8192];       // full h, quads [q4][32 r][4 e]
  __shared__ uint32_t Wsp[4096];       // 16-col W slab, quads [k4p][16 c][4 e]
  __shared__ float zx[16 * 33];
  __shared__ float zbuf[32 * 17];
  __shared__ float hl[4 * 32];
  const int t = threadIdx.x;
  const int dir = blockIdx.x >> 7;
  const int blk = blockIdx.x & 127;
  const int u0 = blk * 4;
  const float* XF = dir ? Xb : Xf;
  const uint32_t* hin = dir ? hbi : hfi;
  uint32_t* hout = dir ? hbo : hfo;
  float* cst = dir ? cb : cf;
  const int ta = dir ? (63 - step) : step;
  const uint32_t* wsrc = Wencp + ((size_t)dir * 128 + blk) * 4096;

  for (int i = 0; i < 8; ++i) {
    int b4 = (t >> 6) * 64 + 256 * i;
    GLOAD_LDS16(hin + (size_t)(t + 256 * i) * 4, hTp + (size_t)b4 * 4);
  }
  for (int i = 0; i < 4; ++i) {
    int b4 = (t >> 6) * 64 + 256 * i;
    GLOAD_LDS16(wsrc + (size_t)(t + 256 * i) * 4, Wsp + (size_t)b4 * 4);
  }
  for (int i = 0; i < 2; ++i) {
    int p = t + 256 * i;
    int c = p >> 5, r = p & 31;
    int col = (c >> 2) * 512 + u0 + (c & 3);
    zx[c * 33 + r] = XF[((size_t)ta * 2048 + col) * 32 + r];
  }
  __syncthreads();
  const int r = t & 31, slot = t >> 5;         // slot 0..7
  float acc0 = zx[slot * 33 + r];
  float acc1 = zx[(slot + 8) * 33 + r];
  const uint4* hT4 = (const uint4*)hTp;
  const uint4* Ws4 = (const uint4*)Wsp;
#pragma unroll 8
  for (int k4p = 0; k4p < 64; ++k4p) {
    uint4 ua = hT4[k4p * 32 + r];
    uint4 w0 = Ws4[k4p * 16 + slot];
    uint4 w1 = Ws4[k4p * 16 + slot + 8];
    acc0 = dot2bf(ua.x, w0.x, acc0);
    acc0 = dot2bf(ua.y, w0.y, acc0);
    acc0 = dot2bf(ua.z, w0.z, acc0);
    acc0 = dot2bf(ua.w, w0.w, acc0);
    acc1 = dot2bf(ua.x, w1.x, acc1);
    acc1 = dot2bf(ua.y, w1.y, acc1);
    acc1 = dot2bf(ua.z, w1.z, acc1);
    acc1 = dot2bf(ua.w, w1.w, acc1);
  }
  zbuf[r * 17 + slot] = acc0;
  zbuf[r * 17 + slot + 8] = acc1;
  __syncthreads();
  if (t < 128) {
    int rr = t & 31, j = t >> 5;               // unit-local j 0..3
    float zi = zbuf[rr * 17 + j];
    float zf = zbuf[rr * 17 + 4 + j];
    float zg = zbuf[rr * 17 + 8 + j];
    float zo = zbuf[rr * 17 + 12 + j];
    int u = u0 + j;
    float cold = cst[u * 32 + rr];
    float cn = sigm(zf) * cold + sigm(zi) * tanhf_fast(zg);
    float h = sigm(zo) * tanhf_fast(cn);
    cst[u * 32 + rr] = cn;
    aB[((size_t)rr * 64 + ta) * 1024 + dir * 512 + u] = (ushort)bf1(h);
    hl[j * 32 + rr] = h;
  }
  __syncthreads();
  if (t < 64) {
    int j = t >> 5, rr = t & 31;               // pair j 0..1
    int pair = blk * 2 + j;
    hout[(pair >> 2) * 128 + rr * 4 + (pair & 3)] =
        bpack(hl[(2 * j) * 32 + rr], hl[(2 * j + 1) * 32 + rr]);
  }
}

// =====================================================================
// K5: aw1[m][j] = aB[m]@W1[:1024,j] + b1[j] via dot2, padded to 16 cols.
// =====================================================================
__global__ __launch_bounds__(256) void k5_aw1(
    const ushort* __restrict__ aB, const uint32_t* __restrict__ W1pbAll,
    const float* __restrict__ b1, float* __restrict__ aw1)
{
  __shared__ uint32_t ar[512];
  __shared__ float ps[16 * 17];
  const int t = threadIdx.x;
  const uint32_t* aBu = (const uint32_t*)aB;
  for (int m = blockIdx.x; m < 2048; m += gridDim.x) {
    __syncthreads();
    *(uint2*)(&ar[t * 2]) = *(const uint2*)(aBu + (size_t)m * 512 + t * 2);
    __syncthreads();
    int j = t & 15, part = t >> 4;
    int jj = j < 10 ? j : 0;
    float s = 0.f;
#pragma unroll 8
    for (int q = part * 32; q < part * 32 + 32; ++q)
      s = dot2bf(ar[q], W1pbAll[q * 12 + jj], s);
    ps[part * 17 + j] = s;
    __syncthreads();
    if (t < 16) {
      float sum = 0.f;
      if (t < 10) {
        for (int p = 0; p < 16; ++p) sum += ps[p * 17 + t];
        sum += b1[t];
      }
      aw1[m * 16 + t] = sum;
    }
  }
}

// =====================================================================
// K_wxdT: Wxd[1024][2048] fp32 -> WxdT[2048][1024] bf16 (LDS transpose)
// =====================================================================
__global__ __launch_bounds__(256) void k_wxdT(
    const float* __restrict__ Wxd, ushort* __restrict__ WxdT)
{
  __shared__ float tile[64 * 65];
  const int t = threadIdx.x;
  const int n0 = blockIdx.x * 64, k0 = blockIdx.y * 64;
  for (int i = 0; i < 16; ++i) {
    int p = t + 256 * i;
    int kk = p >> 6, nn = p & 63;
    tile[kk * 65 + nn] = Wxd[(size_t)(k0 + kk) * 2048 + n0 + nn];
  }
  __syncthreads();
  for (int i = 0; i < 4; ++i) {
    int p = t + 256 * i;
    int nn = p >> 4, k4 = (p & 15) * 4;
    ushort4 o;
    o.x = (ushort)bf1(tile[(k4 + 0) * 65 + nn]);
    o.y = (ushort)bf1(tile[(k4 + 1) * 65 + nn]);
    o.z = (ushort)bf1(tile[(k4 + 2) * 65 + nn]);
    o.w = (ushort)bf1(tile[(k4 + 3) * 65 + nn]);
    *(ushort4*)(WxdT + (size_t)(n0 + nn) * 1024 + k0 + k4) = o;
  }
}

// =====================================================================
// KA: A'T = (a @ Wxd)^T via MFMA bf16, output PACKED bf16 pairs.
// =====================================================================
__global__ __launch_bounds__(256) void kA_aprime(
    const ushort* __restrict__ WxdT, const ushort* __restrict__ aB,
    uint32_t* __restrict__ ApTb)
{
  __shared__ ushort As[128 * 64];
  __shared__ ushort Bs[128 * 64];
  const int t = threadIdx.x;
  const int lane = t & 63, w = t >> 6;
  const int wr = w >> 1, wc = w & 1;
  const int m0 = blockIdx.y * 128, n0 = blockIdx.x * 128;
  const int lrow = lane >> 3, s = lane & 7;
  const int quad = lane >> 4, l15 = lane & 15;
  f32x4 acc[4][4] = {};
  for (int kc = 0; kc < 16; ++kc) {
    const int k0 = kc * 64;
    __syncthreads();
    for (int i = 0; i < 4; ++i) {
      int row = w * 32 + i * 8 + lrow;
      int k8 = s ^ (row & 7);
      GLOAD_LDS16(WxdT + (size_t)(m0 + row) * 1024 + k0 + k8 * 8,
                  As + (w * 32 + i * 8) * 64);
      GLOAD_LDS16(aB + (size_t)(n0 + row) * 1024 + k0 + k8 * 8,
                  Bs + (w * 32 + i * 8) * 64);
    }
    __syncthreads();
#pragma unroll
    for (int ks = 0; ks < 2; ++ks) {
      bf16x8 af[4], bfr[4];
      int kq = ks * 4 + quad;
#pragma unroll
      for (int mi = 0; mi < 4; ++mi) {
        int row = wr * 64 + mi * 16 + l15;
        int slot = kq ^ (row & 7);
        af[mi] = *(const bf16x8*)(As + row * 64 + slot * 8);
      }
#pragma unroll
      for (int ni = 0; ni < 4; ++ni) {
        int row = wc * 64 + ni * 16 + l15;
        int slot = kq ^ (row & 7);
        bfr[ni] = *(const bf16x8*)(Bs + row * 64 + slot * 8);
      }
#pragma unroll
      for (int mi = 0; mi < 4; ++mi)
#pragma unroll
        for (int ni = 0; ni < 4; ++ni)
          acc[mi][ni] = __builtin_amdgcn_mfma_f32_16x16x32_bf16(
              af[mi], bfr[ni], acc[mi][ni], 0, 0, 0);
    }
  }
#pragma unroll
  for (int mi = 0; mi < 4; ++mi) {
    int mbase = m0 + wr * 64 + mi * 16 + quad * 4;
#pragma unroll
    for (int reg = 0; reg < 4; ++reg) {
      int m = mbase + reg;
#pragma unroll
      for (int ni = 0; ni < 4; ++ni) {
        int n = n0 + wc * 64 + ni * 16 + l15;
        float v = acc[mi][ni][reg];
        float v2 = __shfl_xor(v, 1);
        if (!(l15 & 1))
          ApTb[(size_t)m * 1024 + (n >> 1)] = bpack(v, v2);
      }
    }
  }
}

// =====================================================================
// K4: FUSED decoder step, 256 blocks = 64 unit-groups x 4 row-groups.
// Wsp staging issued after first barrier (overlaps hw1 phase).
// =====================================================================
__global__ __launch_bounds__(256) void k4_dec_step(
    const uint32_t* __restrict__ ApTb, const float* __restrict__ aw1,
    const uint32_t* __restrict__ W1pb, const float* __restrict__ W2,
    const float* __restrict__ b2, const uint32_t* __restrict__ hdp_in,
    const uint32_t* __restrict__ Wdp, const float* __restrict__ bd,
    uint32_t* __restrict__ hdp_out, float* __restrict__ cd,
    ushort* __restrict__ HsB, int step)
{
  __shared__ uint32_t W1s[256 * 12];   // bf16-paired W1 rows (decoder half)
  __shared__ uint32_t hdT[4096];       // hd quads, 8-row slice [q4][8 r][4]
  __shared__ uint32_t Wsp[8192];       // Whd slab quads [q4][32 cc][4]
  __shared__ float ph[32 * 8 * 12];
  __shared__ float hw1[8 * 12];
  __shared__ float esc[8 * 65];
  __shared__ uint32_t escp[8 * 33];
  __shared__ float pm[8 * 9];
  __shared__ float mrow[8], srow[8];
  __shared__ float w2s[12];
  __shared__ float zbuf[8 * 33];
  __shared__ float hl[64];
  const int t = threadIdx.x;
  const int ug = blockIdx.x >> 2;      // unit group: units u0..u0+7
  const int rg = blockIdx.x & 3;       // row group: rows r0..r0+7
  const int u0 = ug * 8, r0 = rg * 8;
  for (int i = 0; i < 3; ++i) {
    int b4 = (t >> 6) * 64 + 256 * i;
    GLOAD_LDS16(W1pb + (size_t)(t + 256 * i) * 4, W1s + (size_t)b4 * 4);
  }
  for (int i = 0; i < 4; ++i) {
    int idx4 = t + 256 * i;
    int q4 = idx4 >> 3, rl0 = idx4 & 7;
    int b4 = (t >> 6) * 64 + 256 * i;
    GLOAD_LDS16(hdp_in + (size_t)(q4 * 32 + r0 + rl0) * 4, hdT + (size_t)b4 * 4);
  }
  if (t < 12) w2s[t] = (t < 10) ? W2[t] : 0.f;
  __syncthreads();
  // Wsp staging issued here — drains at the barrier after the ph phase.
  {
    const uint32_t* wsrc = Wdp + (size_t)ug * 8192;
    for (int i = 0; i < 8; ++i) {
      int b4 = (t >> 6) * 64 + 256 * i;
      GLOAD_LDS16(wsrc + (size_t)(t + 256 * i) * 4, Wsp + (size_t)b4 * 4);
    }
  }
  // ---- hw1 = hd @ W1[1024:1536, :10] for 8 rows; 32 k-parts ----
  {
    const int rl = t & 7, kp = t >> 3;      // kp 0..31, 2 quads each
    const uint4* hd4 = (const uint4*)hdT;
    float acc[10] = {};
    for (int q4 = kp * 2; q4 < kp * 2 + 2; ++q4) {
      uint4 u4 = hd4[q4 * 8 + rl];
      const uint32_t* w0 = &W1s[(4 * q4) * 12];
      const uint32_t* w1 = &W1s[(4 * q4 + 1) * 12];
      const uint32_t* w2p = &W1s[(4 * q4 + 2) * 12];
      const uint32_t* w3 = &W1s[(4 * q4 + 3) * 12];
#pragma unroll
      for (int j = 0; j < 10; ++j) {
        acc[j] = dot2bf(u4.x, w0[j], acc[j]);
        acc[j] = dot2bf(u4.y, w1[j], acc[j]);
        acc[j] = dot2bf(u4.z, w2p[j], acc[j]);
        acc[j] = dot2bf(u4.w, w3[j], acc[j]);
      }
    }
#pragma unroll
    for (int j = 0; j < 10; ++j) ph[(kp * 8 + rl) * 12 + j] = acc[j];
  }
  __syncthreads();
  if (t < 96) {
    int rl = t / 12, j = t % 12;
    float s = 0.f;
#pragma unroll
    for (int p = 0; p < 32; ++p) s += ph[(p * 8 + rl) * 12 + j];
    hw1[rl * 12 + j] = s;
  }
  __syncthreads();
  // ---- scores (fast tanh), 8 rows x 64 tt = 2 per thread ----
  const float b2v = b2[0];
  for (int p = 0; p < 2; ++p) {
    int idx = t + 256 * p;               // 0..511
    int rl = idx >> 6, tt = idx & 63;
    size_t m = (size_t)(r0 + rl) * 64 + tt;
    const float4* aw = (const float4*)(aw1 + m * 16);
    float4 q0 = aw[0], q1 = aw[1], q2 = aw[2];
    const float* hw = &hw1[rl * 12];
    float e = b2v;
    e += tanhf_fast(q0.x + hw[0]) * w2s[0];
    e += tanhf_fast(q0.y + hw[1]) * w2s[1];
    e += tanhf_fast(q0.z + hw[2]) * w2s[2];
    e += tanhf_fast(q0.w + hw[3]) * w2s[3];
    e += tanhf_fast(q1.x + hw[4]) * w2s[4];
    e += tanhf_fast(q1.y + hw[5]) * w2s[5];
    e += tanhf_fast(q1.z + hw[6]) * w2s[6];
    e += tanhf_fast(q1.w + hw[7]) * w2s[7];
    e += tanhf_fast(q2.x + hw[8]) * w2s[8];
    e += tanhf_fast(q2.y + hw[9]) * w2s[9];
    esc[rl * 65 + tt] = fmaxf(e, 0.f);
  }
  __syncthreads();
  // ---- softmax stats over tt (8 rows) ----
  if (t < 64) {
    int rl = t >> 3, part = t & 7;
    float m = -1e30f;
    for (int i = 0; i < 8; ++i) m = fmaxf(m, esc[rl * 65 + part * 8 + i]);
    pm[rl * 9 + part] = m;
  }
  __syncthreads();
  if (t < 8) {
    float m = pm[t * 9];
    for (int p = 1; p < 8; ++p) m = fmaxf(m, pm[t * 9 + p]);
    mrow[t] = m;
  }
  __syncthreads();
  if (t < 64) {
    int rl = t >> 3, part = t & 7;
    float m = mrow[rl];
    float s = 0.f;
    for (int i = 0; i < 8; ++i) s += __expf(esc[rl * 65 + part * 8 + i] - m);
    pm[rl * 9 + part] = s;
  }
  __syncthreads();
  if (t < 8) {
    float s = 0.f;
    for (int p = 0; p < 8; ++p) s += pm[t * 9 + p];
    srow[t] = __fdividef(1.f, s);
  }
  __syncthreads();
  // ---- fused normalize + bf16 pair pack (8 rows x 32 pairs) ----
  {
    int rl = t >> 5, q = t & 31;
    float m = mrow[rl], s = srow[rl];
    float v0 = __expf(esc[rl * 65 + 2 * q] - m) * s;
    float v1 = __expf(esc[rl * 65 + 2 * q + 1] - m) * s;
    escp[rl * 33 + q] = bpack(v0, v1);
  }
  __syncthreads();
  // ---- z = score@A'Tb + hd@Whd + bd (32 cols x 8 rows) ----
  const int ccB = t >> 3, rl = t & 7;
  const int colg = (ccB >> 3) * 512 + u0 + (ccB & 7);
  float acc = 0.f;
  {
    const uint4* hd4 = (const uint4*)hdT;
    const uint4* wd4 = (const uint4*)Wsp;
#pragma unroll 8
    for (int q4 = 0; q4 < 64; ++q4) {
      uint4 ua = hd4[q4 * 8 + rl];
      uint4 ub = wd4[q4 * 32 + ccB];
      acc = dot2bf(ua.x, ub.x, acc);
      acc = dot2bf(ua.y, ub.y, acc);
      acc = dot2bf(ua.z, ub.z, acc);
      acc = dot2bf(ua.w, ub.w, acc);
    }
  }
  {
    const uint32_t* ap = ApTb + (size_t)colg * 1024 + (r0 + rl) * 32;
    const uint32_t* ep = &escp[rl * 33];
#pragma unroll
    for (int i8 = 0; i8 < 8; ++i8) {
      uint4 v = *(const uint4*)(ap + i8 * 4);
      acc = dot2bf(v.x, ep[4 * i8 + 0], acc);
      acc = dot2bf(v.y, ep[4 * i8 + 1], acc);
      acc = dot2bf(v.z, ep[4 * i8 + 2], acc);
      acc = dot2bf(v.w, ep[4 * i8 + 3], acc);
    }
  }
  zbuf[rl * 33 + ccB] = acc + bd[colg];
  __syncthreads();
  if (t < 64) {
    int j = t >> 3, rr = t & 7;          // unit j, local row rr
    int u = u0 + j, rgl = r0 + rr;
    float zi = zbuf[rr * 33 + j];
    float zf = zbuf[rr * 33 + 8 + j];
    float zg = zbuf[rr * 33 + 16 + j];
    float zo = zbuf[rr * 33 + 24 + j];
    float cold = cd[u * 32 + rgl];
    float cn = sigm(zf) * cold + sigm(zi) * tanhf_fast(zg);
    float h = sigm(zo) * tanhf_fast(cn);
    cd[u * 32 + rgl] = cn;
    HsB[(size_t)(step * 32 + rgl) * 512 + u] = (ushort)bf1(h);
    hl[j * 8 + rr] = h;
  }
  __syncthreads();
  if (t < 32) {
    int p = t >> 3, rr = t & 7;          // pair p (0..3), local row rr
    hdp_out[ug * 128 + (r0 + rr) * 4 + p] =
        bpack(hl[(2 * p) * 8 + rr], hl[(2 * p + 1) * 8 + rr]);
  }
}

// =====================================================================
// K_woT: Wo[512][32000] fp32 -> WoT[32000][512] bf16 (LDS transpose)
// =====================================================================
__global__ __launch_bounds__(256) void k_woT(
    const float* __restrict__ Wo, ushort* __restrict__ WoT)
{
  __shared__ float tile[64 * 65];
  const int t = threadIdx.x;
  const int n0 = blockIdx.x * 64, k0 = blockIdx.y * 64;
  for (int i = 0; i < 16; ++i) {
    int p = t + 256 * i;
    int kk = p >> 6, nn = p & 63;
    tile[kk * 65 + nn] = Wo[(size_t)(k0 + kk) * 32000 + n0 + nn];
  }
  __syncthreads();
  for (int i = 0; i < 4; ++i) {
    int p = t + 256 * i;
    int nn = p >> 4, k4 = (p & 15) * 4;
    ushort4 o;
    o.x = (ushort)bf1(tile[(k4 + 0) * 65 + nn]);
    o.y = (ushort)bf1(tile[(k4 + 1) * 65 + nn]);
    o.z = (ushort)bf1(tile[(k4 + 2) * 65 + nn]);
    o.w = (ushort)bf1(tile[(k4 + 3) * 65 + nn]);
    *(ushort4*)(WoT + (size_t)(n0 + nn) * 512 + k0 + k4) = o;
  }
}

// =====================================================================
// K6: logits = HsB[2048,512] @ WoT^T + bo via MFMA bf16.
// m-tile offset moff lets the launch run in row-halves (L3 reuse).
// Epilogue emits per-(outrow, ntile) softmax partials (max, sumexp).
// =====================================================================
__global__ __launch_bounds__(256) void k6_logits_mfma(
    const ushort* __restrict__ HsB, const ushort* __restrict__ WoT,
    const float* __restrict__ bo, float* __restrict__ out,
    float2* __restrict__ pstats, int moff)
{
  __shared__ ushort As[128 * 64];
  __shared__ ushort Bs[128 * 64];
  const int t = threadIdx.x;
  const int lane = t & 63, w = t >> 6;
  const int wr = w >> 1, wc = w & 1;
  const int m0 = (blockIdx.y + moff) * 128, n0 = blockIdx.x * 128;
  const int lrow = lane >> 3, s = lane & 7;
  const int quad = lane >> 4, l15 = lane & 15;
  f32x4 acc[4][4] = {};
  for (int kc = 0; kc < 8; ++kc) {
    const int k0 = kc * 64;
    __syncthreads();
    for (int i = 0; i < 4; ++i) {
      int row = w * 32 + i * 8 + lrow;
      int k8 = s ^ (row & 7);
      GLOAD_LDS16(HsB + (size_t)(m0 + row) * 512 + k0 + k8 * 8,
                  As + (w * 32 + i * 8) * 64);
      GLOAD_LDS16(WoT + (size_t)(n0 + row) * 512 + k0 + k8 * 8,
                  Bs + (w * 32 + i * 8) * 64);
    }
    __syncthreads();
#pragma unroll
    for (int ks = 0; ks < 2; ++ks) {
      bf16x8 af[4], bfr[4];
      int kq = ks * 4 + quad;
#pragma unroll
      for (int mi = 0; mi < 4; ++mi) {
        int row = wr * 64 + mi * 16 + l15;
        int slot = kq ^ (row & 7);
        af[mi] = *(const bf16x8*)(As + row * 64 + slot * 8);
      }
#pragma unroll
      for (int ni = 0; ni < 4; ++ni) {
        int row = wc * 64 + ni * 16 + l15;
        int slot = kq ^ (row & 7);
        bfr[ni] = *(const bf16x8*)(Bs + row * 64 + slot * 8);
      }
#pragma unroll
      for (int mi = 0; mi < 4; ++mi)
#pragma unroll
        for (int ni = 0; ni < 4; ++ni)
          acc[mi][ni] = __builtin_amdgcn_mfma_f32_16x16x32_bf16(
              af[mi], bfr[ni], acc[mi][ni], 0, 0, 0);
    }
  }
  __syncthreads();                    // As/Bs dead; reuse as partial arrays
  float* pmx = (float*)As;            // [128 rows][32 slots]
  float* psm = (float*)Bs;
#pragma unroll
  for (int mi = 0; mi < 4; ++mi) {
    int mbase = m0 + wr * 64 + mi * 16 + quad * 4;
#pragma unroll
    for (int reg = 0; reg < 4; ++reg) {
      int m = mbase + reg;
      int rowl = (m - m0);
      size_t rowbase = ((size_t)(m & 31) * 64 + (m >> 5)) * 32000;
      float vs[4];
      float mx = -1e30f;
#pragma unroll
      for (int ni = 0; ni < 4; ++ni) {
        int n = n0 + wc * 64 + ni * 16 + l15;
        float v = acc[mi][ni][reg] + bo[n];
        out[rowbase + n] = v;
        vs[ni] = v;
        mx = fmaxf(mx, v);
      }
      float sl = __expf(vs[0] - mx) + __expf(vs[1] - mx) +
                 __expf(vs[2] - mx) + __expf(vs[3] - mx);
      pmx[rowl * 32 + wc * 16 + l15] = mx;
      psm[rowl * 32 + wc * 16 + l15] = sl;
    }
  }
  __syncthreads();
  if (t < 128) {
    float m = pmx[t * 32], sacc = psm[t * 32];
    for (int i = 1; i < 32; ++i) {
      float m2 = pmx[t * 32 + i], s2 = psm[t * 32 + i];
      float mn = fmaxf(m, m2);
      sacc = sacc * __expf(m - mn) + s2 * __expf(m2 - mn);
      m = mn;
    }
    int mg = m0 + t;
    int outrow = (mg & 31) * 64 + (mg >> 5);
    pstats[(size_t)outrow * 256 + blockIdx.x] = make_float2(m, sacc);
  }
}

// =====================================================================
// K7: row softmax normalize for one m-half (1024 rows), using pstats.
// Rows derived from HsB m-index so each half matches its k6 launch
// (keeps the half's 131 MB of logits L3-resident between k6 and k7).
// =====================================================================
__global__ __launch_bounds__(256) void k7_softmax(
    float* __restrict__ out, const float2* __restrict__ pstats, int half)
{
  __shared__ float mred[256], sred[256];
  const int t = threadIdx.x;
  const int mg = half * 1024 + blockIdx.x;
  const int row = (mg & 31) * 64 + (mg >> 5);
  float m = -1e30f, s = 0.f;
  if (t < 250) {
    float2 p = pstats[(size_t)row * 256 + t];
    m = p.x;
    s = p.y;
  }
  mred[t] = m;
  sred[t] = s;
  __syncthreads();
  for (int st = 128; st > 0; st >>= 1) {
    if (t < st) {
      float m1 = mred[t], m2 = mred[t + st];
      float mn = fmaxf(m1, m2);
      sred[t] = sred[t] * __expf(m1 - mn) + sred[t + st] * __expf(m2 - mn);
      mred[t] = mn;
    }
    __syncthreads();
  }
  m = mred[0];
  const float inv = 1.f / sred[0];
  float* p = out + (size_t)row * 32000;
  for (int i = t; i < 8000; i += 256) {
    float4 v = *(const float4*)(p + i * 4);
    v.x = __expf(v.x - m) * inv;
    v.y = __expf(v.y - m) * inv;
    v.z = __expf(v.z - m) * inv;
    v.w = __expf(v.w - m) * inv;
    *(float4*)(p + i * 4) = v;
  }
}

// =====================================================================
extern "C" void kernel_launch(void* const* d_in, const int* in_sizes, int n_in,
                              void* d_out, int out_size, void* d_ws, size_t ws_size,
                              hipStream_t stream)
{
  const int* x = (const int*)d_in[0];
  const float* emb = (const float*)d_in[1];
  const float* Wxf = (const float*)d_in[2];
  const float* Whf = (const float*)d_in[3];
  const float* bfv = (const float*)d_in[4];
  const float* Wxb = (const float*)d_in[5];
  const float* Whb = (const float*)d_in[6];
  const float* bbv = (const float*)d_in[7];
  const float* W1 = (const float*)d_in[8];
  const float* b1 = (const float*)d_in[9];
  const float* W2 = (const float*)d_in[10];
  const float* b2 = (const float*)d_in[11];
  const float* Wxd = (const float*)d_in[12];
  const float* Whd = (const float*)d_in[13];
  const float* bd = (const float*)d_in[14];
  const float* Wo = (const float*)d_in[15];
  const float* bo = (const float*)d_in[16];

  float* ws = (float*)d_ws;
  // layout (float offsets)
  float* c_f = ws + 0;
  float* c_b = ws + 16384;
  float* c_d = ws + 32768;
  uint32_t* hfp0 = (uint32_t*)(ws + 49152);
  uint32_t* hfp1 = hfp0 + 8192;
  uint32_t* hbp0 = (uint32_t*)(ws + 65536);
  uint32_t* hbp1 = hbp0 + 8192;
  uint32_t* hdp0 = (uint32_t*)(ws + 81920);
  uint32_t* hdp1 = hdp0 + 8192;
  uint32_t* W1pbAll = (uint32_t*)(ws + 98304);     // 9216 u32 (paired full W1)
  uint32_t* Wencp = (uint32_t*)(ws + 114688);      // 1,048,576 u32 (4 MB)
  uint32_t* Wdp = (uint32_t*)(ws + 1163264);       // 524,288 u32 (Whd slabs)
  ushort* aB = (ushort*)(ws + 1687552);            // 2048x1024 bf16
  float* aw1 = ws + 2742272;                       // 32768
  float* Xf = ws + 2775040;                        // 4,194,304
  float* Xb = Xf + 4194304;                        // 4,194,304
  ushort* HsB = (ushort*)(ws + 13260800);          // 2048*512 bf16
  // post-encoder overlays:
  uint32_t* ApTb = (uint32_t*)Xf;                  // 2048x1024 u32 bf16-pairs
  ushort* WxdT = (ushort*)Xb;                      // 2048x1024 bf16
  ushort* WoT = (ushort*)Xf;                       // overlays after decoder
  float2* pstats = (float2*)Wencp;                 // 2048x256 float2 (dead Wencp)

  // zero recurrent states (c_f, c_b, c_d, packed h buffers)
  hipMemsetAsync(ws, 0, 98304 * sizeof(float), stream);

  k0_pack<<<6180, 256, 0, stream>>>(Whf, Whb, Wencp, Whd, Wdp, W1, W1pbAll);

  k1_embed_gemm<<<dim3(32, 64), 256, 0, stream>>>(x, emb, Wxf, Wxb, bfv, bbv, Xf, Xb);

  for (int s = 0; s < 64; ++s) {
    const uint32_t* hfi = (s & 1) ? hfp1 : hfp0;
    uint32_t* hfo = (s & 1) ? hfp0 : hfp1;
    const uint32_t* hbi = (s & 1) ? hbp1 : hbp0;
    uint32_t* hbo = (s & 1) ? hbp0 : hbp1;
    k2_enc_step<<<256, 256, 0, stream>>>(Xf, Xb, Wencp, hfi, hfo, hbi, hbo,
                                         c_f, c_b, aB, s);
  }

  k5_aw1<<<256, 256, 0, stream>>>(aB, W1pbAll, b1, aw1);
  k_wxdT<<<dim3(32, 16), 256, 0, stream>>>(Wxd, WxdT);
  kA_aprime<<<dim3(16, 16), 256, 0, stream>>>(WxdT, aB, ApTb);

  for (int s = 0; s < 64; ++s) {
    const uint32_t* hdi = (s & 1) ? hdp1 : hdp0;
    uint32_t* hdo = (s & 1) ? hdp0 : hdp1;
    k4_dec_step<<<256, 256, 0, stream>>>(ApTb, aw1, W1pbAll + 6144, W2, b2,
                                         hdi, Wdp, bd, hdo, c_d, HsB, s);
  }

  k_woT<<<dim3(500, 8), 256, 0, stream>>>(Wo, WoT);
  // row-half split: each half's 131 MB of logits stays L3-resident
  // between its k6 (producer) and k7 (normalize) launches.
  k6_logits_mfma<<<dim3(250, 8), 256, 0, stream>>>(HsB, WoT, bo,
                                                   (float*)d_out, pstats, 0);
  k7_softmax<<<1024, 256, 0, stream>>>((float*)d_out, pstats, 0);
  k6_logits_mfma<<<dim3(250, 8), 256, 0, stream>>>(HsB, WoT, bo,
                                                   (float*)d_out, pstats, 8);
  k7_softmax<<<1024, 256, 0, stream>>>((float*)d_out, pstats, 1);
}

// Round 10
// 1634.210 us; speedup vs baseline: 1.0139x; 1.0139x over previous
//
#include <hip/hip_runtime.h>
#include <hip/hip_bf16.h>
#include <cstdint>

typedef float f32x4 __attribute__((ext_vector_type(4)));
typedef __bf16 bf16x8 __attribute__((ext_vector_type(8)));

// ---------- bf16 pack helpers (RNE) ----------
__device__ __forceinline__ uint32_t bf1(float x) {
  uint32_t u = __float_as_uint(x);
  return (u + 0x7fffu + ((u >> 16) & 1u)) >> 16;
}
__device__ __forceinline__ uint32_t bpack(float lo, float hi) {
  return bf1(lo) | (bf1(hi) << 16);
}
__device__ __forceinline__ float blo(uint32_t u) { return __uint_as_float(u << 16); }
__device__ __forceinline__ float bhi(uint32_t u) { return __uint_as_float(u & 0xffff0000u); }
__device__ __forceinline__ float sigm(float x) {
  return __fdividef(1.f, 1.f + exp2f(x * -1.4426950408889634f));
}
__device__ __forceinline__ float tanhf_fast(float x) {
  float e2 = exp2f(x * 2.8853900817779268f);
  return 1.f - __fdividef(2.f, e2 + 1.f);
}

// packed-bf16 dot2: acc += a.lo*b.lo + a.hi*b.hi (fp32 accumulate)
__device__ __forceinline__ float dot2bf(uint32_t a, uint32_t b, float acc) {
  asm("v_dot2_f32_bf16 %0, %1, %2, %0" : "+v"(acc) : "v"(a), "v"(b));
  return acc;
}

#define GLOAD_LDS16(g, l)                                                     \
  __builtin_amdgcn_global_load_lds(                                           \
      (const __attribute__((address_space(1))) void*)(g),                     \
      (__attribute__((address_space(3))) void*)(l), 16, 0, 0)

// =====================================================================
// K0: all weight packing in one launch.
// bid<4096: Whf/Whb -> [dir][blk=256][64 k4p][8 c][4 e] (round-8 512-blk k2
//           layout), col=(c>>1)*512+blk*2+(c&1)
// bid<6144: Whd -> [ug=64][64 q4][32 cc][4 e], col=(cc>>3)*512+ug*8+(cc&7)
// else:     W1[0:1536,:10] bf16-paired -> [768 q][12 j]
// =====================================================================
__global__ __launch_bounds__(256) void k0_pack(
    const float* __restrict__ Whf, const float* __restrict__ Whb,
    uint32_t* __restrict__ Wencp, const float* __restrict__ Whd,
    uint32_t* __restrict__ Wdp, const float* __restrict__ W1,
    uint32_t* __restrict__ W1pbAll)
{
  int bid = blockIdx.x;
  if (bid < 4096) {
    int p = bid * 256 + threadIdx.x;             // 0..2^20-1
    int e = p & 3, c = (p >> 2) & 7, k4p = (p >> 5) & 63;
    int blk = (p >> 11) & 255, dir = p >> 19;
    int k2 = 4 * k4p + e;
    const float* W = dir ? Whb : Whf;
    int col = (c >> 1) * 512 + blk * 2 + (c & 1);
    Wencp[p] = bpack(W[(size_t)(2 * k2) * 2048 + col],
                     W[(size_t)(2 * k2 + 1) * 2048 + col]);
  } else if (bid < 6144) {
    int p = (bid - 4096) * 256 + threadIdx.x;    // 0..524287
    int e = p & 3, cc = (p >> 2) & 31, q4 = (p >> 7) & 63, ug = p >> 13;
    int k2 = 4 * q4 + e;
    int col = (cc >> 3) * 512 + ug * 8 + (cc & 7);
    int k = 2 * k2;
    Wdp[p] = bpack(Whd[(size_t)k * 2048 + col], Whd[(size_t)(k + 1) * 2048 + col]);
  } else {
    int p = (bid - 6144) * 256 + threadIdx.x;    // 0..9215
    if (p < 9216) {
      int q = p / 12, j = p % 12;
      float v0 = (j < 10) ? W1[(size_t)(2 * q) * 10 + j] : 0.f;
      float v1 = (j < 10) ? W1[(size_t)(2 * q + 1) * 10 + j] : 0.f;
      W1pbAll[p] = bpack(v0, v1);
    }
  }
}

// =====================================================================
// K1: embedding gather + Xf = xe@Wxf + bf, Xb = xe@Wxb + bb (fp32 VALU)
// =====================================================================
__global__ __launch_bounds__(256) void k1_embed_gemm(
    const int* __restrict__ x, const float* __restrict__ emb,
    const float* __restrict__ Wxf, const float* __restrict__ Wxb,
    const float* __restrict__ bfv, const float* __restrict__ bbv,
    float* __restrict__ Xf, float* __restrict__ Xb)
{
  __shared__ float As[32 * 260];
  __shared__ float Bs[32 * 128];
  __shared__ int xid[32];
  const int t = threadIdx.x;
  const int ty = blockIdx.y;
  const int c0 = blockIdx.x * 128;
  if (t < 32) xid[t] = x[t * 64 + ty];
  __syncthreads();
  for (int i = 0; i < 8; ++i) {
    int f4 = t + 256 * i;
    int r = f4 >> 6, k4 = (f4 & 63) << 2;
    float4 v = *(const float4*)(emb + (size_t)xid[r] * 256 + k4);
    *(float4*)(&As[r * 260 + k4]) = v;
  }
  const int isB = (c0 >= 2048);
  const float* Wsrc = isB ? Wxb : Wxf;
  const float* bias = isB ? bbv : bfv;
  const int cbase = c0 & 2047;
  float acc[4][4] = {};
  const int rq = t >> 5;
  const int cq = t & 31;
  for (int kc = 0; kc < 8; ++kc) {
    int k0 = kc * 32;
    __syncthreads();
    for (int i = 0; i < 4; ++i) {
      int f4 = t + 256 * i;
      int k = f4 >> 5, c4 = (f4 & 31) << 2;
      *(float4*)(&Bs[k * 128 + c4]) =
          *(const float4*)(Wsrc + (size_t)(k0 + k) * 2048 + cbase + c4);
    }
    __syncthreads();
#pragma unroll
    for (int kk = 0; kk < 32; ++kk) {
      float a0 = As[(4 * rq + 0) * 260 + k0 + kk];
      float a1 = As[(4 * rq + 1) * 260 + k0 + kk];
      float a2 = As[(4 * rq + 2) * 260 + k0 + kk];
      float a3 = As[(4 * rq + 3) * 260 + k0 + kk];
      float4 b = *(const float4*)(&Bs[kk * 128 + 4 * cq]);
      acc[0][0] += a0 * b.x; acc[0][1] += a0 * b.y; acc[0][2] += a0 * b.z; acc[0][3] += a0 * b.w;
      acc[1][0] += a1 * b.x; acc[1][1] += a1 * b.y; acc[1][2] += a1 * b.z; acc[1][3] += a1 * b.w;
      acc[2][0] += a2 * b.x; acc[2][1] += a2 * b.y; acc[2][2] += a2 * b.z; acc[2][3] += a2 * b.w;
      acc[3][0] += a3 * b.x; acc[3][1] += a3 * b.y; acc[3][2] += a3 * b.z; acc[3][3] += a3 * b.w;
    }
  }
  float* Xout = isB ? Xb : Xf;
  for (int i = 0; i < 4; ++i) {
    int c = cbase + 4 * cq + i;
    float bi = bias[c];
    for (int j = 0; j < 4; ++j) {
      int b_ = 4 * rq + j;
      Xout[((size_t)ty * 2048 + c) * 32 + b_] = acc[j][i] + bi;
    }
  }
}

// =====================================================================
// K2: one encoder step both dirs; 512 blocks (2 units each, 2 blk/CU).
// QUAD-b128 LDS reads + v_dot2_f32_bf16, global_load_lds staging.
// (round-8 version — k2 is latency-floor-bound; 2 blk/CU needed)
// =====================================================================
__global__ __launch_bounds__(256) void k2_enc_step(
    const float* __restrict__ Xf, const float* __restrict__ Xb,
    const uint32_t* __restrict__ Wencp,
    const uint32_t* __restrict__ hfi, uint32_t* __restrict__ hfo,
    const uint32_t* __restrict__ hbi, uint32_t* __restrict__ hbo,
    float* __restrict__ cf, float* __restrict__ cb,
    ushort* __restrict__ aB, int step)
{
  __shared__ uint32_t hTp[256 * 32];   // full h, quads
  __shared__ uint32_t Wsp[2048];       // 8-col W slab, quads
  __shared__ float zx[8 * 33];
  __shared__ float zbuf[32 * 9];
  __shared__ float hl[2 * 32];
  const int t = threadIdx.x;
  const int dir = blockIdx.x >> 8;
  const int blk = blockIdx.x & 255;
  const int u0 = blk * 2;
  const float* XF = dir ? Xb : Xf;
  const uint32_t* hin = dir ? hbi : hfi;
  uint32_t* hout = dir ? hbo : hfo;
  float* cst = dir ? cb : cf;
  const int ta = dir ? (63 - step) : step;
  const uint32_t* wsrc = Wencp + ((size_t)dir * 256 + blk) * 2048;

  for (int i = 0; i < 8; ++i) {
    int b4 = (t >> 6) * 64 + 256 * i;
    GLOAD_LDS16(hin + (size_t)(t + 256 * i) * 4, hTp + (size_t)b4 * 4);
  }
  for (int i = 0; i < 2; ++i) {
    int b4 = (t >> 6) * 64 + 256 * i;
    GLOAD_LDS16(wsrc + (size_t)(t + 256 * i) * 4, Wsp + (size_t)b4 * 4);
  }
  {
    int c = t >> 5, r = t & 31;
    int col = (c >> 1) * 512 + u0 + (c & 1);
    zx[c * 33 + r] = XF[((size_t)ta * 2048 + col) * 32 + r];
  }
  __syncthreads();
  const int r = t & 31, cc = t >> 5;
  float acc = zx[cc * 33 + r];
  const uint4* hT4 = (const uint4*)hTp;
  const uint4* Ws4 = (const uint4*)Wsp;
#pragma unroll 8
  for (int k4p = 0; k4p < 64; ++k4p) {
    uint4 ua = hT4[k4p * 32 + r];
    uint4 w = Ws4[k4p * 8 + cc];
    acc = dot2bf(ua.x, w.x, acc);
    acc = dot2bf(ua.y, w.y, acc);
    acc = dot2bf(ua.z, w.z, acc);
    acc = dot2bf(ua.w, w.w, acc);
  }
  zbuf[r * 9 + cc] = acc;
  __syncthreads();
  if (t < 64) {
    int rr = t & 31, j = t >> 5;
    float zi = zbuf[rr * 9 + j];
    float zf = zbuf[rr * 9 + 2 + j];
    float zg = zbuf[rr * 9 + 4 + j];
    float zo = zbuf[rr * 9 + 6 + j];
    int u = u0 + j;
    float cold = cst[u * 32 + rr];
    float cn = sigm(zf) * cold + sigm(zi) * tanhf_fast(zg);
    float h = sigm(zo) * tanhf_fast(cn);
    cst[u * 32 + rr] = cn;
    aB[((size_t)rr * 64 + ta) * 1024 + dir * 512 + u] = (ushort)bf1(h);
    hl[j * 32 + rr] = h;
  }
  __syncthreads();
  if (t < 32) {
    hout[(blk >> 2) * 128 + t * 4 + (blk & 3)] = bpack(hl[t], hl[32 + t]);
  }
}

// =====================================================================
// K5: aw1[m][j] = aB[m]@W1[:1024,j] + b1[j] via dot2, padded to 16 cols.
// =====================================================================
__global__ __launch_bounds__(256) void k5_aw1(
    const ushort* __restrict__ aB, const uint32_t* __restrict__ W1pbAll,
    const float* __restrict__ b1, float* __restrict__ aw1)
{
  __shared__ uint32_t ar[512];
  __shared__ float ps[16 * 17];
  const int t = threadIdx.x;
  const uint32_t* aBu = (const uint32_t*)aB;
  for (int m = blockIdx.x; m < 2048; m += gridDim.x) {
    __syncthreads();
    *(uint2*)(&ar[t * 2]) = *(const uint2*)(aBu + (size_t)m * 512 + t * 2);
    __syncthreads();
    int j = t & 15, part = t >> 4;
    int jj = j < 10 ? j : 0;
    float s = 0.f;
#pragma unroll 8
    for (int q = part * 32; q < part * 32 + 32; ++q)
      s = dot2bf(ar[q], W1pbAll[q * 12 + jj], s);
    ps[part * 17 + j] = s;
    __syncthreads();
    if (t < 16) {
      float sum = 0.f;
      if (t < 10) {
        for (int p = 0; p < 16; ++p) sum += ps[p * 17 + t];
        sum += b1[t];
      }
      aw1[m * 16 + t] = sum;
    }
  }
}

// =====================================================================
// K_wxdT: Wxd[1024][2048] fp32 -> WxdT[2048][1024] bf16 (LDS transpose)
// =====================================================================
__global__ __launch_bounds__(256) void k_wxdT(
    const float* __restrict__ Wxd, ushort* __restrict__ WxdT)
{
  __shared__ float tile[64 * 65];
  const int t = threadIdx.x;
  const int n0 = blockIdx.x * 64, k0 = blockIdx.y * 64;
  for (int i = 0; i < 16; ++i) {
    int p = t + 256 * i;
    int kk = p >> 6, nn = p & 63;
    tile[kk * 65 + nn] = Wxd[(size_t)(k0 + kk) * 2048 + n0 + nn];
  }
  __syncthreads();
  for (int i = 0; i < 4; ++i) {
    int p = t + 256 * i;
    int nn = p >> 4, k4 = (p & 15) * 4;
    ushort4 o;
    o.x = (ushort)bf1(tile[(k4 + 0) * 65 + nn]);
    o.y = (ushort)bf1(tile[(k4 + 1) * 65 + nn]);
    o.z = (ushort)bf1(tile[(k4 + 2) * 65 + nn]);
    o.w = (ushort)bf1(tile[(k4 + 3) * 65 + nn]);
    *(ushort4*)(WxdT + (size_t)(n0 + nn) * 1024 + k0 + k4) = o;
  }
}

// =====================================================================
// KA: A'T = (a @ Wxd)^T via MFMA bf16, output PACKED bf16 pairs.
// =====================================================================
__global__ __launch_bounds__(256) void kA_aprime(
    const ushort* __restrict__ WxdT, const ushort* __restrict__ aB,
    uint32_t* __restrict__ ApTb)
{
  __shared__ ushort As[128 * 64];
  __shared__ ushort Bs[128 * 64];
  const int t = threadIdx.x;
  const int lane = t & 63, w = t >> 6;
  const int wr = w >> 1, wc = w & 1;
  const int m0 = blockIdx.y * 128, n0 = blockIdx.x * 128;
  const int lrow = lane >> 3, s = lane & 7;
  const int quad = lane >> 4, l15 = lane & 15;
  f32x4 acc[4][4] = {};
  for (int kc = 0; kc < 16; ++kc) {
    const int k0 = kc * 64;
    __syncthreads();
    for (int i = 0; i < 4; ++i) {
      int row = w * 32 + i * 8 + lrow;
      int k8 = s ^ (row & 7);
      GLOAD_LDS16(WxdT + (size_t)(m0 + row) * 1024 + k0 + k8 * 8,
                  As + (w * 32 + i * 8) * 64);
      GLOAD_LDS16(aB + (size_t)(n0 + row) * 1024 + k0 + k8 * 8,
                  Bs + (w * 32 + i * 8) * 64);
    }
    __syncthreads();
#pragma unroll
    for (int ks = 0; ks < 2; ++ks) {
      bf16x8 af[4], bfr[4];
      int kq = ks * 4 + quad;
#pragma unroll
      for (int mi = 0; mi < 4; ++mi) {
        int row = wr * 64 + mi * 16 + l15;
        int slot = kq ^ (row & 7);
        af[mi] = *(const bf16x8*)(As + row * 64 + slot * 8);
      }
#pragma unroll
      for (int ni = 0; ni < 4; ++ni) {
        int row = wc * 64 + ni * 16 + l15;
        int slot = kq ^ (row & 7);
        bfr[ni] = *(const bf16x8*)(Bs + row * 64 + slot * 8);
      }
#pragma unroll
      for (int mi = 0; mi < 4; ++mi)
#pragma unroll
        for (int ni = 0; ni < 4; ++ni)
          acc[mi][ni] = __builtin_amdgcn_mfma_f32_16x16x32_bf16(
              af[mi], bfr[ni], acc[mi][ni], 0, 0, 0);
    }
  }
#pragma unroll
  for (int mi = 0; mi < 4; ++mi) {
    int mbase = m0 + wr * 64 + mi * 16 + quad * 4;
#pragma unroll
    for (int reg = 0; reg < 4; ++reg) {
      int m = mbase + reg;
#pragma unroll
      for (int ni = 0; ni < 4; ++ni) {
        int n = n0 + wc * 64 + ni * 16 + l15;
        float v = acc[mi][ni][reg];
        float v2 = __shfl_xor(v, 1);
        if (!(l15 & 1))
          ApTb[(size_t)m * 1024 + (n >> 1)] = bpack(v, v2);
      }
    }
  }
}

// =====================================================================
// K4: FUSED decoder step, 256 blocks = 64 unit-groups x 4 row-groups.
// Wsp staging issued after first barrier (overlaps hw1 phase).
// =====================================================================
__global__ __launch_bounds__(256) void k4_dec_step(
    const uint32_t* __restrict__ ApTb, const float* __restrict__ aw1,
    const uint32_t* __restrict__ W1pb, const float* __restrict__ W2,
    const float* __restrict__ b2, const uint32_t* __restrict__ hdp_in,
    const uint32_t* __restrict__ Wdp, const float* __restrict__ bd,
    uint32_t* __restrict__ hdp_out, float* __restrict__ cd,
    ushort* __restrict__ HsB, int step)
{
  __shared__ uint32_t W1s[256 * 12];   // bf16-paired W1 rows (decoder half)
  __shared__ uint32_t hdT[4096];       // hd quads, 8-row slice [q4][8 r][4]
  __shared__ uint32_t Wsp[8192];       // Whd slab quads [q4][32 cc][4]
  __shared__ float ph[32 * 8 * 12];
  __shared__ float hw1[8 * 12];
  __shared__ float esc[8 * 65];
  __shared__ uint32_t escp[8 * 33];
  __shared__ float pm[8 * 9];
  __shared__ float mrow[8], srow[8];
  __shared__ float w2s[12];
  __shared__ float zbuf[8 * 33];
  __shared__ float hl[64];
  const int t = threadIdx.x;
  const int ug = blockIdx.x >> 2;      // unit group: units u0..u0+7
  const int rg = blockIdx.x & 3;       // row group: rows r0..r0+7
  const int u0 = ug * 8, r0 = rg * 8;
  for (int i = 0; i < 3; ++i) {
    int b4 = (t >> 6) * 64 + 256 * i;
    GLOAD_LDS16(W1pb + (size_t)(t + 256 * i) * 4, W1s + (size_t)b4 * 4);
  }
  for (int i = 0; i < 4; ++i) {
    int idx4 = t + 256 * i;
    int q4 = idx4 >> 3, rl0 = idx4 & 7;
    int b4 = (t >> 6) * 64 + 256 * i;
    GLOAD_LDS16(hdp_in + (size_t)(q4 * 32 + r0 + rl0) * 4, hdT + (size_t)b4 * 4);
  }
  if (t < 12) w2s[t] = (t < 10) ? W2[t] : 0.f;
  __syncthreads();
  // Wsp staging issued here — drains at the barrier after the ph phase.
  {
    const uint32_t* wsrc = Wdp + (size_t)ug * 8192;
    for (int i = 0; i < 8; ++i) {
      int b4 = (t >> 6) * 64 + 256 * i;
      GLOAD_LDS16(wsrc + (size_t)(t + 256 * i) * 4, Wsp + (size_t)b4 * 4);
    }
  }
  // ---- hw1 = hd @ W1[1024:1536, :10] for 8 rows; 32 k-parts ----
  {
    const int rl = t & 7, kp = t >> 3;      // kp 0..31, 2 quads each
    const uint4* hd4 = (const uint4*)hdT;
    float acc[10] = {};
    for (int q4 = kp * 2; q4 < kp * 2 + 2; ++q4) {
      uint4 u4 = hd4[q4 * 8 + rl];
      const uint32_t* w0 = &W1s[(4 * q4) * 12];
      const uint32_t* w1 = &W1s[(4 * q4 + 1) * 12];
      const uint32_t* w2p = &W1s[(4 * q4 + 2) * 12];
      const uint32_t* w3 = &W1s[(4 * q4 + 3) * 12];
#pragma unroll
      for (int j = 0; j < 10; ++j) {
        acc[j] = dot2bf(u4.x, w0[j], acc[j]);
        acc[j] = dot2bf(u4.y, w1[j], acc[j]);
        acc[j] = dot2bf(u4.z, w2p[j], acc[j]);
        acc[j] = dot2bf(u4.w, w3[j], acc[j]);
      }
    }
#pragma unroll
    for (int j = 0; j < 10; ++j) ph[(kp * 8 + rl) * 12 + j] = acc[j];
  }
  __syncthreads();
  if (t < 96) {
    int rl = t / 12, j = t % 12;
    float s = 0.f;
#pragma unroll
    for (int p = 0; p < 32; ++p) s += ph[(p * 8 + rl) * 12 + j];
    hw1[rl * 12 + j] = s;
  }
  __syncthreads();
  // ---- scores (fast tanh), 8 rows x 64 tt = 2 per thread ----
  const float b2v = b2[0];
  for (int p = 0; p < 2; ++p) {
    int idx = t + 256 * p;               // 0..511
    int rl = idx >> 6, tt = idx & 63;
    size_t m = (size_t)(r0 + rl) * 64 + tt;
    const float4* aw = (const float4*)(aw1 + m * 16);
    float4 q0 = aw[0], q1 = aw[1], q2 = aw[2];
    const float* hw = &hw1[rl * 12];
    float e = b2v;
    e += tanhf_fast(q0.x + hw[0]) * w2s[0];
    e += tanhf_fast(q0.y + hw[1]) * w2s[1];
    e += tanhf_fast(q0.z + hw[2]) * w2s[2];
    e += tanhf_fast(q0.w + hw[3]) * w2s[3];
    e += tanhf_fast(q1.x + hw[4]) * w2s[4];
    e += tanhf_fast(q1.y + hw[5]) * w2s[5];
    e += tanhf_fast(q1.z + hw[6]) * w2s[6];
    e += tanhf_fast(q1.w + hw[7]) * w2s[7];
    e += tanhf_fast(q2.x + hw[8]) * w2s[8];
    e += tanhf_fast(q2.y + hw[9]) * w2s[9];
    esc[rl * 65 + tt] = fmaxf(e, 0.f);
  }
  __syncthreads();
  // ---- softmax stats over tt (8 rows) ----
  if (t < 64) {
    int rl = t >> 3, part = t & 7;
    float m = -1e30f;
    for (int i = 0; i < 8; ++i) m = fmaxf(m, esc[rl * 65 + part * 8 + i]);
    pm[rl * 9 + part] = m;
  }
  __syncthreads();
  if (t < 8) {
    float m = pm[t * 9];
    for (int p = 1; p < 8; ++p) m = fmaxf(m, pm[t * 9 + p]);
    mrow[t] = m;
  }
  __syncthreads();
  if (t < 64) {
    int rl = t >> 3, part = t & 7;
    float m = mrow[rl];
    float s = 0.f;
    for (int i = 0; i < 8; ++i) s += __expf(esc[rl * 65 + part * 8 + i] - m);
    pm[rl * 9 + part] = s;
  }
  __syncthreads();
  if (t < 8) {
    float s = 0.f;
    for (int p = 0; p < 8; ++p) s += pm[t * 9 + p];
    srow[t] = __fdividef(1.f, s);
  }
  __syncthreads();
  // ---- fused normalize + bf16 pair pack (8 rows x 32 pairs) ----
  {
    int rl = t >> 5, q = t & 31;
    float m = mrow[rl], s = srow[rl];
    float v0 = __expf(esc[rl * 65 + 2 * q] - m) * s;
    float v1 = __expf(esc[rl * 65 + 2 * q + 1] - m) * s;
    escp[rl * 33 + q] = bpack(v0, v1);
  }
  __syncthreads();
  // ---- z = score@A'Tb + hd@Whd + bd (32 cols x 8 rows) ----
  const int ccB = t >> 3, rl = t & 7;
  const int colg = (ccB >> 3) * 512 + u0 + (ccB & 7);
  float acc = 0.f;
  {
    const uint4* hd4 = (const uint4*)hdT;
    const uint4* wd4 = (const uint4*)Wsp;
#pragma unroll 8
    for (int q4 = 0; q4 < 64; ++q4) {
      uint4 ua = hd4[q4 * 8 + rl];
      uint4 ub = wd4[q4 * 32 + ccB];
      acc = dot2bf(ua.x, ub.x, acc);
      acc = dot2bf(ua.y, ub.y, acc);
      acc = dot2bf(ua.z, ub.z, acc);
      acc = dot2bf(ua.w, ub.w, acc);
    }
  }
  {
    const uint32_t* ap = ApTb + (size_t)colg * 1024 + (r0 + rl) * 32;
    const uint32_t* ep = &escp[rl * 33];
#pragma unroll
    for (int i8 = 0; i8 < 8; ++i8) {
      uint4 v = *(const uint4*)(ap + i8 * 4);
      acc = dot2bf(v.x, ep[4 * i8 + 0], acc);
      acc = dot2bf(v.y, ep[4 * i8 + 1], acc);
      acc = dot2bf(v.z, ep[4 * i8 + 2], acc);
      acc = dot2bf(v.w, ep[4 * i8 + 3], acc);
    }
  }
  zbuf[rl * 33 + ccB] = acc + bd[colg];
  __syncthreads();
  if (t < 64) {
    int j = t >> 3, rr = t & 7;          // unit j, local row rr
    int u = u0 + j, rgl = r0 + rr;
    float zi = zbuf[rr * 33 + j];
    float zf = zbuf[rr * 33 + 8 + j];
    float zg = zbuf[rr * 33 + 16 + j];
    float zo = zbuf[rr * 33 + 24 + j];
    float cold = cd[u * 32 + rgl];
    float cn = sigm(zf) * cold + sigm(zi) * tanhf_fast(zg);
    float h = sigm(zo) * tanhf_fast(cn);
    cd[u * 32 + rgl] = cn;
    HsB[(size_t)(step * 32 + rgl) * 512 + u] = (ushort)bf1(h);
    hl[j * 8 + rr] = h;
  }
  __syncthreads();
  if (t < 32) {
    int p = t >> 3, rr = t & 7;          // pair p (0..3), local row rr
    hdp_out[ug * 128 + (r0 + rr) * 4 + p] =
        bpack(hl[(2 * p) * 8 + rr], hl[(2 * p + 1) * 8 + rr]);
  }
}

// =====================================================================
// K_woT: Wo[512][32000] fp32 -> WoT[32000][512] bf16 (LDS transpose)
// =====================================================================
__global__ __launch_bounds__(256) void k_woT(
    const float* __restrict__ Wo, ushort* __restrict__ WoT)
{
  __shared__ float tile[64 * 65];
  const int t = threadIdx.x;
  const int n0 = blockIdx.x * 64, k0 = blockIdx.y * 64;
  for (int i = 0; i < 16; ++i) {
    int p = t + 256 * i;
    int kk = p >> 6, nn = p & 63;
    tile[kk * 65 + nn] = Wo[(size_t)(k0 + kk) * 32000 + n0 + nn];
  }
  __syncthreads();
  for (int i = 0; i < 4; ++i) {
    int p = t + 256 * i;
    int nn = p >> 4, k4 = (p & 15) * 4;
    ushort4 o;
    o.x = (ushort)bf1(tile[(k4 + 0) * 65 + nn]);
    o.y = (ushort)bf1(tile[(k4 + 1) * 65 + nn]);
    o.z = (ushort)bf1(tile[(k4 + 2) * 65 + nn]);
    o.w = (ushort)bf1(tile[(k4 + 3) * 65 + nn]);
    *(ushort4*)(WoT + (size_t)(n0 + nn) * 512 + k0 + k4) = o;
  }
}

// =====================================================================
// K6: logits = HsB[2048,512] @ WoT^T + bo via MFMA bf16.
// m-tile offset moff lets the launch run in row-halves (L3 reuse).
// Epilogue emits per-(outrow, ntile) softmax partials (max, sumexp).
// =====================================================================
__global__ __launch_bounds__(256) void k6_logits_mfma(
    const ushort* __restrict__ HsB, const ushort* __restrict__ WoT,
    const float* __restrict__ bo, float* __restrict__ out,
    float2* __restrict__ pstats, int moff)
{
  __shared__ ushort As[128 * 64];
  __shared__ ushort Bs[128 * 64];
  const int t = threadIdx.x;
  const int lane = t & 63, w = t >> 6;
  const int wr = w >> 1, wc = w & 1;
  const int m0 = (blockIdx.y + moff) * 128, n0 = blockIdx.x * 128;
  const int lrow = lane >> 3, s = lane & 7;
  const int quad = lane >> 4, l15 = lane & 15;
  f32x4 acc[4][4] = {};
  for (int kc = 0; kc < 8; ++kc) {
    const int k0 = kc * 64;
    __syncthreads();
    for (int i = 0; i < 4; ++i) {
      int row = w * 32 + i * 8 + lrow;
      int k8 = s ^ (row & 7);
      GLOAD_LDS16(HsB + (size_t)(m0 + row) * 512 + k0 + k8 * 8,
                  As + (w * 32 + i * 8) * 64);
      GLOAD_LDS16(WoT + (size_t)(n0 + row) * 512 + k0 + k8 * 8,
                  Bs + (w * 32 + i * 8) * 64);
    }
    __syncthreads();
#pragma unroll
    for (int ks = 0; ks < 2; ++ks) {
      bf16x8 af[4], bfr[4];
      int kq = ks * 4 + quad;
#pragma unroll
      for (int mi = 0; mi < 4; ++mi) {
        int row = wr * 64 + mi * 16 + l15;
        int slot = kq ^ (row & 7);
        af[mi] = *(const bf16x8*)(As + row * 64 + slot * 8);
      }
#pragma unroll
      for (int ni = 0; ni < 4; ++ni) {
        int row = wc * 64 + ni * 16 + l15;
        int slot = kq ^ (row & 7);
        bfr[ni] = *(const bf16x8*)(Bs + row * 64 + slot * 8);
      }
#pragma unroll
      for (int mi = 0; mi < 4; ++mi)
#pragma unroll
        for (int ni = 0; ni < 4; ++ni)
          acc[mi][ni] = __builtin_amdgcn_mfma_f32_16x16x32_bf16(
              af[mi], bfr[ni], acc[mi][ni], 0, 0, 0);
    }
  }
  __syncthreads();                    // As/Bs dead; reuse as partial arrays
  float* pmx = (float*)As;            // [128 rows][32 slots]
  float* psm = (float*)Bs;
#pragma unroll
  for (int mi = 0; mi < 4; ++mi) {
    int mbase = m0 + wr * 64 + mi * 16 + quad * 4;
#pragma unroll
    for (int reg = 0; reg < 4; ++reg) {
      int m = mbase + reg;
      int rowl = (m - m0);
      size_t rowbase = ((size_t)(m & 31) * 64 + (m >> 5)) * 32000;
      float vs[4];
      float mx = -1e30f;
#pragma unroll
      for (int ni = 0; ni < 4; ++ni) {
        int n = n0 + wc * 64 + ni * 16 + l15;
        float v = acc[mi][ni][reg] + bo[n];
        out[rowbase + n] = v;
        vs[ni] = v;
        mx = fmaxf(mx, v);
      }
      float sl = __expf(vs[0] - mx) + __expf(vs[1] - mx) +
                 __expf(vs[2] - mx) + __expf(vs[3] - mx);
      pmx[rowl * 32 + wc * 16 + l15] = mx;
      psm[rowl * 32 + wc * 16 + l15] = sl;
    }
  }
  __syncthreads();
  if (t < 128) {
    float m = pmx[t * 32], sacc = psm[t * 32];
    for (int i = 1; i < 32; ++i) {
      float m2 = pmx[t * 32 + i], s2 = psm[t * 32 + i];
      float mn = fmaxf(m, m2);
      sacc = sacc * __expf(m - mn) + s2 * __expf(m2 - mn);
      m = mn;
    }
    int mg = m0 + t;
    int outrow = (mg & 31) * 64 + (mg >> 5);
    pstats[(size_t)outrow * 256 + blockIdx.x] = make_float2(m, sacc);
  }
}

// =====================================================================
// K7: row softmax normalize for one m-half (1024 rows), using pstats.
// =====================================================================
__global__ __launch_bounds__(256) void k7_softmax(
    float* __restrict__ out, const float2* __restrict__ pstats, int half)
{
  __shared__ float mred[256], sred[256];
  const int t = threadIdx.x;
  const int mg = half * 1024 + blockIdx.x;
  const int row = (mg & 31) * 64 + (mg >> 5);
  float m = -1e30f, s = 0.f;
  if (t < 250) {
    float2 p = pstats[(size_t)row * 256 + t];
    m = p.x;
    s = p.y;
  }
  mred[t] = m;
  sred[t] = s;
  __syncthreads();
  for (int st = 128; st > 0; st >>= 1) {
    if (t < st) {
      float m1 = mred[t], m2 = mred[t + st];
      float mn = fmaxf(m1, m2);
      sred[t] = sred[t] * __expf(m1 - mn) + sred[t + st] * __expf(m2 - mn);
      mred[t] = mn;
    }
    __syncthreads();
  }
  m = mred[0];
  const float inv = 1.f / sred[0];
  float* p = out + (size_t)row * 32000;
  for (int i = t; i < 8000; i += 256) {
    float4 v = *(const float4*)(p + i * 4);
    v.x = __expf(v.x - m) * inv;
    v.y = __expf(v.y - m) * inv;
    v.z = __expf(v.z - m) * inv;
    v.w = __expf(v.w - m) * inv;
    *(float4*)(p + i * 4) = v;
  }
}

// =====================================================================
extern "C" void kernel_launch(void* const* d_in, const int* in_sizes, int n_in,
                              void* d_out, int out_size, void* d_ws, size_t ws_size,
                              hipStream_t stream)
{
  const int* x = (const int*)d_in[0];
  const float* emb = (const float*)d_in[1];
  const float* Wxf = (const float*)d_in[2];
  const float* Whf = (const float*)d_in[3];
  const float* bfv = (const float*)d_in[4];
  const float* Wxb = (const float*)d_in[5];
  const float* Whb = (const float*)d_in[6];
  const float* bbv = (const float*)d_in[7];
  const float* W1 = (const float*)d_in[8];
  const float* b1 = (const float*)d_in[9];
  const float* W2 = (const float*)d_in[10];
  const float* b2 = (const float*)d_in[11];
  const float* Wxd = (const float*)d_in[12];
  const float* Whd = (const float*)d_in[13];
  const float* bd = (const float*)d_in[14];
  const float* Wo = (const float*)d_in[15];
  const float* bo = (const float*)d_in[16];

  float* ws = (float*)d_ws;
  // layout (float offsets)
  float* c_f = ws + 0;
  float* c_b = ws + 16384;
  float* c_d = ws + 32768;
  uint32_t* hfp0 = (uint32_t*)(ws + 49152);
  uint32_t* hfp1 = hfp0 + 8192;
  uint32_t* hbp0 = (uint32_t*)(ws + 65536);
  uint32_t* hbp1 = hbp0 + 8192;
  uint32_t* hdp0 = (uint32_t*)(ws + 81920);
  uint32_t* hdp1 = hdp0 + 8192;
  uint32_t* W1pbAll = (uint32_t*)(ws + 98304);     // 9216 u32 (paired full W1)
  uint32_t* Wencp = (uint32_t*)(ws + 114688);      // 1,048,576 u32 (4 MB)
  uint32_t* Wdp = (uint32_t*)(ws + 1163264);       // 524,288 u32 (Whd slabs)
  ushort* aB = (ushort*)(ws + 1687552);            // 2048x1024 bf16
  float* aw1 = ws + 2742272;                       // 32768
  float* Xf = ws + 2775040;                        // 4,194,304
  float* Xb = Xf + 4194304;                        // 4,194,304
  ushort* HsB = (ushort*)(ws + 13260800);          // 2048*512 bf16
  // post-encoder overlays:
  uint32_t* ApTb = (uint32_t*)Xf;                  // 2048x1024 u32 bf16-pairs
  ushort* WxdT = (ushort*)Xb;                      // 2048x1024 bf16
  ushort* WoT = (ushort*)Xf;                       // overlays after decoder
  float2* pstats = (float2*)Wencp;                 // 2048x256 float2 (dead Wencp)

  // zero recurrent states (c_f, c_b, c_d, packed h buffers)
  hipMemsetAsync(ws, 0, 98304 * sizeof(float), stream);

  k0_pack<<<6180, 256, 0, stream>>>(Whf, Whb, Wencp, Whd, Wdp, W1, W1pbAll);

  k1_embed_gemm<<<dim3(32, 64), 256, 0, stream>>>(x, emb, Wxf, Wxb, bfv, bbv, Xf, Xb);

  for (int s = 0; s < 64; ++s) {
    const uint32_t* hfi = (s & 1) ? hfp1 : hfp0;
    uint32_t* hfo = (s & 1) ? hfp0 : hfp1;
    const uint32_t* hbi = (s & 1) ? hbp1 : hbp0;
    uint32_t* hbo = (s & 1) ? hbp0 : hbp1;
    k2_enc_step<<<512, 256, 0, stream>>>(Xf, Xb, Wencp, hfi, hfo, hbi, hbo,
                                         c_f, c_b, aB, s);
  }

  k5_aw1<<<256, 256, 0, stream>>>(aB, W1pbAll, b1, aw1);
  k_wxdT<<<dim3(32, 16), 256, 0, stream>>>(Wxd, WxdT);
  kA_aprime<<<dim3(16, 16), 256, 0, stream>>>(WxdT, aB, ApTb);

  for (int s = 0; s < 64; ++s) {
    const uint32_t* hdi = (s & 1) ? hdp1 : hdp0;
    uint32_t* hdo = (s & 1) ? hdp0 : hdp1;
    k4_dec_step<<<256, 256, 0, stream>>>(ApTb, aw1, W1pbAll + 6144, W2, b2,
                                         hdi, Wdp, bd, hdo, c_d, HsB, s);
  }

  k_woT<<<dim3(500, 8), 256, 0, stream>>>(Wo, WoT);
  // row-half split: each half's 131 MB of logits stays L3-resident
  // between its k6 (producer) and k7 (normalize) launches.
  k6_logits_mfma<<<dim3(250, 8), 256, 0, stream>>>(HsB, WoT, bo,
                                                   (float*)d_out, pstats, 0);
  k7_softmax<<<1024, 256, 0, stream>>>((float*)d_out, pstats, 0);
  k6_logits_mfma<<<dim3(250, 8), 256, 0, stream>>>(HsB, WoT, bo,
                                                   (float*)d_out, pstats, 8);
  k7_softmax<<<1024, 256, 0, stream>>>((float*)d_out, pstats, 1);
}

// Round 11
// 1611.906 us; speedup vs baseline: 1.0279x; 1.0138x over previous
//
#include <hip/hip_runtime.h>
#include <hip/hip_bf16.h>
#include <cstdint>

typedef float f32x4 __attribute__((ext_vector_type(4)));
typedef __bf16 bf16x8 __attribute__((ext_vector_type(8)));

// ---------- bf16 pack helpers (RNE) ----------
__device__ __forceinline__ uint32_t bf1(float x) {
  uint32_t u = __float_as_uint(x);
  return (u + 0x7fffu + ((u >> 16) & 1u)) >> 16;
}
__device__ __forceinline__ uint32_t bpack(float lo, float hi) {
  return bf1(lo) | (bf1(hi) << 16);
}
__device__ __forceinline__ float blo(uint32_t u) { return __uint_as_float(u << 16); }
__device__ __forceinline__ float bhi(uint32_t u) { return __uint_as_float(u & 0xffff0000u); }
__device__ __forceinline__ float sigm(float x) {
  return __fdividef(1.f, 1.f + exp2f(x * -1.4426950408889634f));
}
__device__ __forceinline__ float tanhf_fast(float x) {
  float e2 = exp2f(x * 2.8853900817779268f);
  return 1.f - __fdividef(2.f, e2 + 1.f);
}

// packed-bf16 dot2: acc += a.lo*b.lo + a.hi*b.hi (fp32 accumulate)
__device__ __forceinline__ float dot2bf(uint32_t a, uint32_t b, float acc) {
  asm("v_dot2_f32_bf16 %0, %1, %2, %0" : "+v"(acc) : "v"(a), "v"(b));
  return acc;
}

#define GLOAD_LDS16(g, l)                                                     \
  __builtin_amdgcn_global_load_lds(                                           \
      (const __attribute__((address_space(1))) void*)(g),                     \
      (__attribute__((address_space(3))) void*)(l), 16, 0, 0)

// =====================================================================
// K0: all weight packing in one launch.
// bid<4096: Whf/Whb -> [dir][blk=256][64 k4p][8 c][4 e] (512-blk k2 layout)
// bid<6144: Whd -> [ug=64][64 q4][32 cc][4 e], col=(cc>>3)*512+ug*8+(cc&7)
// else:     W1[0:1536,:10] bf16-paired -> [768 q][12 j]
// =====================================================================
__global__ __launch_bounds__(256) void k0_pack(
    const float* __restrict__ Whf, const float* __restrict__ Whb,
    uint32_t* __restrict__ Wencp, const float* __restrict__ Whd,
    uint32_t* __restrict__ Wdp, const float* __restrict__ W1,
    uint32_t* __restrict__ W1pbAll)
{
  int bid = blockIdx.x;
  if (bid < 4096) {
    int p = bid * 256 + threadIdx.x;             // 0..2^20-1
    int e = p & 3, c = (p >> 2) & 7, k4p = (p >> 5) & 63;
    int blk = (p >> 11) & 255, dir = p >> 19;
    int k2 = 4 * k4p + e;
    const float* W = dir ? Whb : Whf;
    int col = (c >> 1) * 512 + blk * 2 + (c & 1);
    Wencp[p] = bpack(W[(size_t)(2 * k2) * 2048 + col],
                     W[(size_t)(2 * k2 + 1) * 2048 + col]);
  } else if (bid < 6144) {
    int p = (bid - 4096) * 256 + threadIdx.x;    // 0..524287
    int e = p & 3, cc = (p >> 2) & 31, q4 = (p >> 7) & 63, ug = p >> 13;
    int k2 = 4 * q4 + e;
    int col = (cc >> 3) * 512 + ug * 8 + (cc & 7);
    int k = 2 * k2;
    Wdp[p] = bpack(Whd[(size_t)k * 2048 + col], Whd[(size_t)(k + 1) * 2048 + col]);
  } else {
    int p = (bid - 6144) * 256 + threadIdx.x;    // 0..9215
    if (p < 9216) {
      int q = p / 12, j = p % 12;
      float v0 = (j < 10) ? W1[(size_t)(2 * q) * 10 + j] : 0.f;
      float v1 = (j < 10) ? W1[(size_t)(2 * q + 1) * 10 + j] : 0.f;
      W1pbAll[p] = bpack(v0, v1);
    }
  }
}

// =====================================================================
// K1: embedding gather + Xf = xe@Wxf + bf, Xb = xe@Wxb + bb (fp32 VALU)
// =====================================================================
__global__ __launch_bounds__(256) void k1_embed_gemm(
    const int* __restrict__ x, const float* __restrict__ emb,
    const float* __restrict__ Wxf, const float* __restrict__ Wxb,
    const float* __restrict__ bfv, const float* __restrict__ bbv,
    float* __restrict__ Xf, float* __restrict__ Xb)
{
  __shared__ float As[32 * 260];
  __shared__ float Bs[32 * 128];
  __shared__ int xid[32];
  const int t = threadIdx.x;
  const int ty = blockIdx.y;
  const int c0 = blockIdx.x * 128;
  if (t < 32) xid[t] = x[t * 64 + ty];
  __syncthreads();
  for (int i = 0; i < 8; ++i) {
    int f4 = t + 256 * i;
    int r = f4 >> 6, k4 = (f4 & 63) << 2;
    float4 v = *(const float4*)(emb + (size_t)xid[r] * 256 + k4);
    *(float4*)(&As[r * 260 + k4]) = v;
  }
  const int isB = (c0 >= 2048);
  const float* Wsrc = isB ? Wxb : Wxf;
  const float* bias = isB ? bbv : bfv;
  const int cbase = c0 & 2047;
  float acc[4][4] = {};
  const int rq = t >> 5;
  const int cq = t & 31;
  for (int kc = 0; kc < 8; ++kc) {
    int k0 = kc * 32;
    __syncthreads();
    for (int i = 0; i < 4; ++i) {
      int f4 = t + 256 * i;
      int k = f4 >> 5, c4 = (f4 & 31) << 2;
      *(float4*)(&Bs[k * 128 + c4]) =
          *(const float4*)(Wsrc + (size_t)(k0 + k) * 2048 + cbase + c4);
    }
    __syncthreads();
#pragma unroll
    for (int kk = 0; kk < 32; ++kk) {
      float a0 = As[(4 * rq + 0) * 260 + k0 + kk];
      float a1 = As[(4 * rq + 1) * 260 + k0 + kk];
      float a2 = As[(4 * rq + 2) * 260 + k0 + kk];
      float a3 = As[(4 * rq + 3) * 260 + k0 + kk];
      float4 b = *(const float4*)(&Bs[kk * 128 + 4 * cq]);
      acc[0][0] += a0 * b.x; acc[0][1] += a0 * b.y; acc[0][2] += a0 * b.z; acc[0][3] += a0 * b.w;
      acc[1][0] += a1 * b.x; acc[1][1] += a1 * b.y; acc[1][2] += a1 * b.z; acc[1][3] += a1 * b.w;
      acc[2][0] += a2 * b.x; acc[2][1] += a2 * b.y; acc[2][2] += a2 * b.z; acc[2][3] += a2 * b.w;
      acc[3][0] += a3 * b.x; acc[3][1] += a3 * b.y; acc[3][2] += a3 * b.z; acc[3][3] += a3 * b.w;
    }
  }
  float* Xout = isB ? Xb : Xf;
  for (int i = 0; i < 4; ++i) {
    int c = cbase + 4 * cq + i;
    float bi = bias[c];
    for (int j = 0; j < 4; ++j) {
      int b_ = 4 * rq + j;
      Xout[((size_t)ty * 2048 + c) * 32 + b_] = acc[j][i] + bi;
    }
  }
}

// =====================================================================
// K2: one encoder step both dirs; 512 blocks (2 units each, 2 blk/CU).
// QUAD-b128 LDS reads + v_dot2_f32_bf16, global_load_lds staging.
// =====================================================================
__global__ __launch_bounds__(256) void k2_enc_step(
    const float* __restrict__ Xf, const float* __restrict__ Xb,
    const uint32_t* __restrict__ Wencp,
    const uint32_t* __restrict__ hfi, uint32_t* __restrict__ hfo,
    const uint32_t* __restrict__ hbi, uint32_t* __restrict__ hbo,
    float* __restrict__ cf, float* __restrict__ cb,
    ushort* __restrict__ aB, int step)
{
  __shared__ uint32_t hTp[256 * 32];   // full h, quads
  __shared__ uint32_t Wsp[2048];       // 8-col W slab, quads
  __shared__ float zx[8 * 33];
  __shared__ float zbuf[32 * 9];
  __shared__ float hl[2 * 32];
  const int t = threadIdx.x;
  const int dir = blockIdx.x >> 8;
  const int blk = blockIdx.x & 255;
  const int u0 = blk * 2;
  const float* XF = dir ? Xb : Xf;
  const uint32_t* hin = dir ? hbi : hfi;
  uint32_t* hout = dir ? hbo : hfo;
  float* cst = dir ? cb : cf;
  const int ta = dir ? (63 - step) : step;
  const uint32_t* wsrc = Wencp + ((size_t)dir * 256 + blk) * 2048;

  for (int i = 0; i < 8; ++i) {
    int b4 = (t >> 6) * 64 + 256 * i;
    GLOAD_LDS16(hin + (size_t)(t + 256 * i) * 4, hTp + (size_t)b4 * 4);
  }
  for (int i = 0; i < 2; ++i) {
    int b4 = (t >> 6) * 64 + 256 * i;
    GLOAD_LDS16(wsrc + (size_t)(t + 256 * i) * 4, Wsp + (size_t)b4 * 4);
  }
  {
    int c = t >> 5, r = t & 31;
    int col = (c >> 1) * 512 + u0 + (c & 1);
    zx[c * 33 + r] = XF[((size_t)ta * 2048 + col) * 32 + r];
  }
  __syncthreads();
  const int r = t & 31, cc = t >> 5;
  float acc = zx[cc * 33 + r];
  const uint4* hT4 = (const uint4*)hTp;
  const uint4* Ws4 = (const uint4*)Wsp;
#pragma unroll 8
  for (int k4p = 0; k4p < 64; ++k4p) {
    uint4 ua = hT4[k4p * 32 + r];
    uint4 w = Ws4[k4p * 8 + cc];
    acc = dot2bf(ua.x, w.x, acc);
    acc = dot2bf(ua.y, w.y, acc);
    acc = dot2bf(ua.z, w.z, acc);
    acc = dot2bf(ua.w, w.w, acc);
  }
  zbuf[r * 9 + cc] = acc;
  __syncthreads();
  if (t < 64) {
    int rr = t & 31, j = t >> 5;
    float zi = zbuf[rr * 9 + j];
    float zf = zbuf[rr * 9 + 2 + j];
    float zg = zbuf[rr * 9 + 4 + j];
    float zo = zbuf[rr * 9 + 6 + j];
    int u = u0 + j;
    float cold = cst[u * 32 + rr];
    float cn = sigm(zf) * cold + sigm(zi) * tanhf_fast(zg);
    float h = sigm(zo) * tanhf_fast(cn);
    cst[u * 32 + rr] = cn;
    aB[((size_t)rr * 64 + ta) * 1024 + dir * 512 + u] = (ushort)bf1(h);
    hl[j * 32 + rr] = h;
  }
  __syncthreads();
  if (t < 32) {
    hout[(blk >> 2) * 128 + t * 4 + (blk & 3)] = bpack(hl[t], hl[32 + t]);
  }
}

// =====================================================================
// K5: aw1[m][j] = aB[m]@W1[:1024,j] + b1[j] via dot2, padded to 16 cols.
// =====================================================================
__global__ __launch_bounds__(256) void k5_aw1(
    const ushort* __restrict__ aB, const uint32_t* __restrict__ W1pbAll,
    const float* __restrict__ b1, float* __restrict__ aw1)
{
  __shared__ uint32_t ar[512];
  __shared__ float ps[16 * 17];
  const int t = threadIdx.x;
  const uint32_t* aBu = (const uint32_t*)aB;
  for (int m = blockIdx.x; m < 2048; m += gridDim.x) {
    __syncthreads();
    *(uint2*)(&ar[t * 2]) = *(const uint2*)(aBu + (size_t)m * 512 + t * 2);
    __syncthreads();
    int j = t & 15, part = t >> 4;
    int jj = j < 10 ? j : 0;
    float s = 0.f;
#pragma unroll 8
    for (int q = part * 32; q < part * 32 + 32; ++q)
      s = dot2bf(ar[q], W1pbAll[q * 12 + jj], s);
    ps[part * 17 + j] = s;
    __syncthreads();
    if (t < 16) {
      float sum = 0.f;
      if (t < 10) {
        for (int p = 0; p < 16; ++p) sum += ps[p * 17 + t];
        sum += b1[t];
      }
      aw1[m * 16 + t] = sum;
    }
  }
}

// =====================================================================
// K_wxdT: Wxd[1024][2048] fp32 -> WxdT[2048][1024] bf16 (LDS transpose)
// =====================================================================
__global__ __launch_bounds__(256) void k_wxdT(
    const float* __restrict__ Wxd, ushort* __restrict__ WxdT)
{
  __shared__ float tile[64 * 65];
  const int t = threadIdx.x;
  const int n0 = blockIdx.x * 64, k0 = blockIdx.y * 64;
  for (int i = 0; i < 16; ++i) {
    int p = t + 256 * i;
    int kk = p >> 6, nn = p & 63;
    tile[kk * 65 + nn] = Wxd[(size_t)(k0 + kk) * 2048 + n0 + nn];
  }
  __syncthreads();
  for (int i = 0; i < 4; ++i) {
    int p = t + 256 * i;
    int nn = p >> 4, k4 = (p & 15) * 4;
    ushort4 o;
    o.x = (ushort)bf1(tile[(k4 + 0) * 65 + nn]);
    o.y = (ushort)bf1(tile[(k4 + 1) * 65 + nn]);
    o.z = (ushort)bf1(tile[(k4 + 2) * 65 + nn]);
    o.w = (ushort)bf1(tile[(k4 + 3) * 65 + nn]);
    *(ushort4*)(WxdT + (size_t)(n0 + nn) * 1024 + k0 + k4) = o;
  }
}

// =====================================================================
// KA: A'T = (a @ Wxd)^T via MFMA bf16, output PACKED bf16 pairs.
// =====================================================================
__global__ __launch_bounds__(256) void kA_aprime(
    const ushort* __restrict__ WxdT, const ushort* __restrict__ aB,
    uint32_t* __restrict__ ApTb)
{
  __shared__ ushort As[128 * 64];
  __shared__ ushort Bs[128 * 64];
  const int t = threadIdx.x;
  const int lane = t & 63, w = t >> 6;
  const int wr = w >> 1, wc = w & 1;
  const int m0 = blockIdx.y * 128, n0 = blockIdx.x * 128;
  const int lrow = lane >> 3, s = lane & 7;
  const int quad = lane >> 4, l15 = lane & 15;
  f32x4 acc[4][4] = {};
  for (int kc = 0; kc < 16; ++kc) {
    const int k0 = kc * 64;
    __syncthreads();
    for (int i = 0; i < 4; ++i) {
      int row = w * 32 + i * 8 + lrow;
      int k8 = s ^ (row & 7);
      GLOAD_LDS16(WxdT + (size_t)(m0 + row) * 1024 + k0 + k8 * 8,
                  As + (w * 32 + i * 8) * 64);
      GLOAD_LDS16(aB + (size_t)(n0 + row) * 1024 + k0 + k8 * 8,
                  Bs + (w * 32 + i * 8) * 64);
    }
    __syncthreads();
#pragma unroll
    for (int ks = 0; ks < 2; ++ks) {
      bf16x8 af[4], bfr[4];
      int kq = ks * 4 + quad;
#pragma unroll
      for (int mi = 0; mi < 4; ++mi) {
        int row = wr * 64 + mi * 16 + l15;
        int slot = kq ^ (row & 7);
        af[mi] = *(const bf16x8*)(As + row * 64 + slot * 8);
      }
#pragma unroll
      for (int ni = 0; ni < 4; ++ni) {
        int row = wc * 64 + ni * 16 + l15;
        int slot = kq ^ (row & 7);
        bfr[ni] = *(const bf16x8*)(Bs + row * 64 + slot * 8);
      }
#pragma unroll
      for (int mi = 0; mi < 4; ++mi)
#pragma unroll
        for (int ni = 0; ni < 4; ++ni)
          acc[mi][ni] = __builtin_amdgcn_mfma_f32_16x16x32_bf16(
              af[mi], bfr[ni], acc[mi][ni], 0, 0, 0);
    }
  }
#pragma unroll
  for (int mi = 0; mi < 4; ++mi) {
    int mbase = m0 + wr * 64 + mi * 16 + quad * 4;
#pragma unroll
    for (int reg = 0; reg < 4; ++reg) {
      int m = mbase + reg;
#pragma unroll
      for (int ni = 0; ni < 4; ++ni) {
        int n = n0 + wc * 64 + ni * 16 + l15;
        float v = acc[mi][ni][reg];
        float v2 = __shfl_xor(v, 1);
        if (!(l15 & 1))
          ApTb[(size_t)m * 1024 + (n >> 1)] = bpack(v, v2);
      }
    }
  }
}

// =====================================================================
// K4: FUSED decoder step, 512 blocks = 64 unit-groups x 8 row-groups
// (4 rows each). ~63 KB LDS -> 2 blocks/CU co-resident (k2 lesson).
// z-phase K-split across thread halves; Wsp staging deferred.
// =====================================================================
__global__ __launch_bounds__(256) void k4_dec_step(
    const uint32_t* __restrict__ ApTb, const float* __restrict__ aw1,
    const uint32_t* __restrict__ W1pb, const float* __restrict__ W2,
    const float* __restrict__ b2, const uint32_t* __restrict__ hdp_in,
    const uint32_t* __restrict__ Wdp, const float* __restrict__ bd,
    uint32_t* __restrict__ hdp_out, float* __restrict__ cd,
    ushort* __restrict__ HsB, int step)
{
  __shared__ uint32_t W1s[256 * 12];   // bf16-paired W1 rows (decoder half)
  __shared__ uint32_t hdT[1024];       // hd quads, 4-row slice [q4][4 r][4]
  __shared__ uint32_t Wsp[8192];       // Whd slab quads [q4][32 cc][4]
  __shared__ float ph[64 * 4 * 12];
  __shared__ float hw1[4 * 12];
  __shared__ float esc[4 * 65];
  __shared__ uint32_t escp[4 * 33];
  __shared__ float pm[4 * 9];
  __shared__ float mrow[4], srow[4];
  __shared__ float w2s[12];
  __shared__ float zp[2][128];
  __shared__ float zbuf[4 * 33];
  __shared__ float hl[32];
  const int t = threadIdx.x;
  const int ug = blockIdx.x >> 3;      // unit group: units u0..u0+7
  const int rg = blockIdx.x & 7;       // row group: rows r0..r0+3
  const int u0 = ug * 8, r0 = rg * 4;
  for (int i = 0; i < 3; ++i) {
    int b4 = (t >> 6) * 64 + 256 * i;
    GLOAD_LDS16(W1pb + (size_t)(t + 256 * i) * 4, W1s + (size_t)b4 * 4);
  }
  {
    // hdT: LDS quad t <- hd quad (q4=t>>2, rl=t&3) of rows r0..r0+3
    int q4 = t >> 2, rl0 = t & 3;
    int b4 = (t >> 6) * 64;
    GLOAD_LDS16(hdp_in + (size_t)(q4 * 32 + r0 + rl0) * 4, hdT + (size_t)b4 * 4);
  }
  if (t < 12) w2s[t] = (t < 10) ? W2[t] : 0.f;
  __syncthreads();
  // Wsp staging issued here — drains at a later barrier (used in z-phase).
  {
    const uint32_t* wsrc = Wdp + (size_t)ug * 8192;
    for (int i = 0; i < 8; ++i) {
      int b4 = (t >> 6) * 64 + 256 * i;
      GLOAD_LDS16(wsrc + (size_t)(t + 256 * i) * 4, Wsp + (size_t)b4 * 4);
    }
  }
  // ---- hw1 = hd @ W1[1024:1536, :10] for 4 rows; 64 k-parts ----
  {
    const int rl = t & 3, kp = t >> 2;      // kp 0..63, 1 quad each
    const uint4* hd4 = (const uint4*)hdT;
    float acc[10] = {};
    {
      uint4 u4 = hd4[kp * 4 + rl];
      const uint32_t* w0 = &W1s[(4 * kp) * 12];
      const uint32_t* w1 = &W1s[(4 * kp + 1) * 12];
      const uint32_t* w2p = &W1s[(4 * kp + 2) * 12];
      const uint32_t* w3 = &W1s[(4 * kp + 3) * 12];
#pragma unroll
      for (int j = 0; j < 10; ++j) {
        acc[j] = dot2bf(u4.x, w0[j], acc[j]);
        acc[j] = dot2bf(u4.y, w1[j], acc[j]);
        acc[j] = dot2bf(u4.z, w2p[j], acc[j]);
        acc[j] = dot2bf(u4.w, w3[j], acc[j]);
      }
    }
#pragma unroll
    for (int j = 0; j < 10; ++j) ph[(kp * 4 + rl) * 12 + j] = acc[j];
  }
  __syncthreads();
  if (t < 40) {
    int rl = t / 10, j = t % 10;
    float s = 0.f;
#pragma unroll
    for (int p = 0; p < 64; ++p) s += ph[(p * 4 + rl) * 12 + j];
    hw1[rl * 12 + j] = s;
  }
  __syncthreads();
  // ---- scores (fast tanh), 4 rows x 64 tt = 1 per thread ----
  const float b2v = b2[0];
  {
    int rl = t >> 6, tt = t & 63;
    size_t m = (size_t)(r0 + rl) * 64 + tt;
    const float4* aw = (const float4*)(aw1 + m * 16);
    float4 q0 = aw[0], q1 = aw[1], q2 = aw[2];
    const float* hw = &hw1[rl * 12];
    float e = b2v;
    e += tanhf_fast(q0.x + hw[0]) * w2s[0];
    e += tanhf_fast(q0.y + hw[1]) * w2s[1];
    e += tanhf_fast(q0.z + hw[2]) * w2s[2];
    e += tanhf_fast(q0.w + hw[3]) * w2s[3];
    e += tanhf_fast(q1.x + hw[4]) * w2s[4];
    e += tanhf_fast(q1.y + hw[5]) * w2s[5];
    e += tanhf_fast(q1.z + hw[6]) * w2s[6];
    e += tanhf_fast(q1.w + hw[7]) * w2s[7];
    e += tanhf_fast(q2.x + hw[8]) * w2s[8];
    e += tanhf_fast(q2.y + hw[9]) * w2s[9];
    esc[rl * 65 + tt] = fmaxf(e, 0.f);
  }
  __syncthreads();
  // ---- softmax stats over tt (4 rows) ----
  if (t < 32) {
    int rl = t >> 3, part = t & 7;
    float m = -1e30f;
    for (int i = 0; i < 8; ++i) m = fmaxf(m, esc[rl * 65 + part * 8 + i]);
    pm[rl * 9 + part] = m;
  }
  __syncthreads();
  if (t < 4) {
    float m = pm[t * 9];
    for (int p = 1; p < 8; ++p) m = fmaxf(m, pm[t * 9 + p]);
    mrow[t] = m;
  }
  __syncthreads();
  if (t < 32) {
    int rl = t >> 3, part = t & 7;
    float m = mrow[rl];
    float s = 0.f;
    for (int i = 0; i < 8; ++i) s += __expf(esc[rl * 65 + part * 8 + i] - m);
    pm[rl * 9 + part] = s;
  }
  __syncthreads();
  if (t < 4) {
    float s = 0.f;
    for (int p = 0; p < 8; ++p) s += pm[t * 9 + p];
    srow[t] = __fdividef(1.f, s);
  }
  __syncthreads();
  // ---- fused normalize + bf16 pair pack (4 rows x 32 pairs) ----
  if (t < 128) {
    int rl = t >> 5, q = t & 31;
    float m = mrow[rl], s = srow[rl];
    float v0 = __expf(esc[rl * 65 + 2 * q] - m) * s;
    float v1 = __expf(esc[rl * 65 + 2 * q + 1] - m) * s;
    escp[rl * 33 + q] = bpack(v0, v1);
  }
  __syncthreads();
  // ---- z = score@A'Tb + hd@Whd + bd (32 cols x 4 rows, K-split) ----
  {
    const int out = t & 127;
    const int ccB = out >> 2, rl = out & 3;
    const int kh = t >> 7;               // K-half 0/1
    const int colg = (ccB >> 3) * 512 + u0 + (ccB & 7);
    float acc = 0.f;
    {
      const uint4* hd4 = (const uint4*)hdT;
      const uint4* wd4 = (const uint4*)Wsp;
#pragma unroll 8
      for (int q4 = kh * 32; q4 < kh * 32 + 32; ++q4) {
        uint4 ua = hd4[q4 * 4 + rl];
        uint4 ub = wd4[q4 * 32 + ccB];
        acc = dot2bf(ua.x, ub.x, acc);
        acc = dot2bf(ua.y, ub.y, acc);
        acc = dot2bf(ua.z, ub.z, acc);
        acc = dot2bf(ua.w, ub.w, acc);
      }
    }
    {
      const uint32_t* ap = ApTb + (size_t)colg * 1024 + (r0 + rl) * 32;
      const uint32_t* ep = &escp[rl * 33];
#pragma unroll
      for (int i8 = kh * 4; i8 < kh * 4 + 4; ++i8) {
        uint4 v = *(const uint4*)(ap + i8 * 4);
        acc = dot2bf(v.x, ep[4 * i8 + 0], acc);
        acc = dot2bf(v.y, ep[4 * i8 + 1], acc);
        acc = dot2bf(v.z, ep[4 * i8 + 2], acc);
        acc = dot2bf(v.w, ep[4 * i8 + 3], acc);
      }
    }
    zp[kh][out] = acc;
  }
  __syncthreads();
  if (t < 128) {
    int ccB = t >> 2, rl = t & 3;
    int colg = (ccB >> 3) * 512 + u0 + (ccB & 7);
    zbuf[rl * 33 + ccB] = zp[0][t] + zp[1][t] + bd[colg];
  }
  __syncthreads();
  if (t < 32) {
    int j = t >> 2, rr = t & 3;          // unit j, local row rr
    int u = u0 + j, rgl = r0 + rr;
    float zi = zbuf[rr * 33 + j];
    float zf = zbuf[rr * 33 + 8 + j];
    float zg = zbuf[rr * 33 + 16 + j];
    float zo = zbuf[rr * 33 + 24 + j];
    float cold = cd[u * 32 + rgl];
    float cn = sigm(zf) * cold + sigm(zi) * tanhf_fast(zg);
    float h = sigm(zo) * tanhf_fast(cn);
    cd[u * 32 + rgl] = cn;
    HsB[(size_t)(step * 32 + rgl) * 512 + u] = (ushort)bf1(h);
    hl[j * 4 + rr] = h;
  }
  __syncthreads();
  if (t < 16) {
    int p = t >> 2, rr = t & 3;          // pair p (0..3), local row rr
    hdp_out[ug * 128 + (r0 + rr) * 4 + p] =
        bpack(hl[(2 * p) * 4 + rr], hl[(2 * p + 1) * 4 + rr]);
  }
}

// =====================================================================
// K_woT: Wo[512][32000] fp32 -> WoT[32000][512] bf16 (LDS transpose)
// =====================================================================
__global__ __launch_bounds__(256) void k_woT(
    const float* __restrict__ Wo, ushort* __restrict__ WoT)
{
  __shared__ float tile[64 * 65];
  const int t = threadIdx.x;
  const int n0 = blockIdx.x * 64, k0 = blockIdx.y * 64;
  for (int i = 0; i < 16; ++i) {
    int p = t + 256 * i;
    int kk = p >> 6, nn = p & 63;
    tile[kk * 65 + nn] = Wo[(size_t)(k0 + kk) * 32000 + n0 + nn];
  }
  __syncthreads();
  for (int i = 0; i < 4; ++i) {
    int p = t + 256 * i;
    int nn = p >> 4, k4 = (p & 15) * 4;
    ushort4 o;
    o.x = (ushort)bf1(tile[(k4 + 0) * 65 + nn]);
    o.y = (ushort)bf1(tile[(k4 + 1) * 65 + nn]);
    o.z = (ushort)bf1(tile[(k4 + 2) * 65 + nn]);
    o.w = (ushort)bf1(tile[(k4 + 3) * 65 + nn]);
    *(ushort4*)(WoT + (size_t)(n0 + nn) * 512 + k0 + k4) = o;
  }
}

// =====================================================================
// K6: logits = HsB[2048,512] @ WoT^T + bo via MFMA bf16.
// m-tile offset moff lets the launch run in row-halves (L3 reuse).
// Epilogue emits per-(outrow, ntile) softmax partials (max, sumexp).
// =====================================================================
__global__ __launch_bounds__(256) void k6_logits_mfma(
    const ushort* __restrict__ HsB, const ushort* __restrict__ WoT,
    const float* __restrict__ bo, float* __restrict__ out,
    float2* __restrict__ pstats, int moff)
{
  __shared__ ushort As[128 * 64];
  __shared__ ushort Bs[128 * 64];
  const int t = threadIdx.x;
  const int lane = t & 63, w = t >> 6;
  const int wr = w >> 1, wc = w & 1;
  const int m0 = (blockIdx.y + moff) * 128, n0 = blockIdx.x * 128;
  const int lrow = lane >> 3, s = lane & 7;
  const int quad = lane >> 4, l15 = lane & 15;
  f32x4 acc[4][4] = {};
  for (int kc = 0; kc < 8; ++kc) {
    const int k0 = kc * 64;
    __syncthreads();
    for (int i = 0; i < 4; ++i) {
      int row = w * 32 + i * 8 + lrow;
      int k8 = s ^ (row & 7);
      GLOAD_LDS16(HsB + (size_t)(m0 + row) * 512 + k0 + k8 * 8,
                  As + (w * 32 + i * 8) * 64);
      GLOAD_LDS16(WoT + (size_t)(n0 + row) * 512 + k0 + k8 * 8,
                  Bs + (w * 32 + i * 8) * 64);
    }
    __syncthreads();
#pragma unroll
    for (int ks = 0; ks < 2; ++ks) {
      bf16x8 af[4], bfr[4];
      int kq = ks * 4 + quad;
#pragma unroll
      for (int mi = 0; mi < 4; ++mi) {
        int row = wr * 64 + mi * 16 + l15;
        int slot = kq ^ (row & 7);
        af[mi] = *(const bf16x8*)(As + row * 64 + slot * 8);
      }
#pragma unroll
      for (int ni = 0; ni < 4; ++ni) {
        int row = wc * 64 + ni * 16 + l15;
        int slot = kq ^ (row & 7);
        bfr[ni] = *(const bf16x8*)(Bs + row * 64 + slot * 8);
      }
#pragma unroll
      for (int mi = 0; mi < 4; ++mi)
#pragma unroll
        for (int ni = 0; ni < 4; ++ni)
          acc[mi][ni] = __builtin_amdgcn_mfma_f32_16x16x32_bf16(
              af[mi], bfr[ni], acc[mi][ni], 0, 0, 0);
    }
  }
  __syncthreads();                    // As/Bs dead; reuse as partial arrays
  float* pmx = (float*)As;            // [128 rows][32 slots]
  float* psm = (float*)Bs;
#pragma unroll
  for (int mi = 0; mi < 4; ++mi) {
    int mbase = m0 + wr * 64 + mi * 16 + quad * 4;
#pragma unroll
    for (int reg = 0; reg < 4; ++reg) {
      int m = mbase + reg;
      int rowl = (m - m0);
      size_t rowbase = ((size_t)(m & 31) * 64 + (m >> 5)) * 32000;
      float vs[4];
      float mx = -1e30f;
#pragma unroll
      for (int ni = 0; ni < 4; ++ni) {
        int n = n0 + wc * 64 + ni * 16 + l15;
        float v = acc[mi][ni][reg] + bo[n];
        out[rowbase + n] = v;
        vs[ni] = v;
        mx = fmaxf(mx, v);
      }
      float sl = __expf(vs[0] - mx) + __expf(vs[1] - mx) +
                 __expf(vs[2] - mx) + __expf(vs[3] - mx);
      pmx[rowl * 32 + wc * 16 + l15] = mx;
      psm[rowl * 32 + wc * 16 + l15] = sl;
    }
  }
  __syncthreads();
  if (t < 128) {
    float m = pmx[t * 32], sacc = psm[t * 32];
    for (int i = 1; i < 32; ++i) {
      float m2 = pmx[t * 32 + i], s2 = psm[t * 32 + i];
      float mn = fmaxf(m, m2);
      sacc = sacc * __expf(m - mn) + s2 * __expf(m2 - mn);
      m = mn;
    }
    int mg = m0 + t;
    int outrow = (mg & 31) * 64 + (mg >> 5);
    pstats[(size_t)outrow * 256 + blockIdx.x] = make_float2(m, sacc);
  }
}

// =====================================================================
// K7: row softmax normalize for one m-half (1024 rows), using pstats.
// =====================================================================
__global__ __launch_bounds__(256) void k7_softmax(
    float* __restrict__ out, const float2* __restrict__ pstats, int half)
{
  __shared__ float mred[256], sred[256];
  const int t = threadIdx.x;
  const int mg = half * 1024 + blockIdx.x;
  const int row = (mg & 31) * 64 + (mg >> 5);
  float m = -1e30f, s = 0.f;
  if (t < 250) {
    float2 p = pstats[(size_t)row * 256 + t];
    m = p.x;
    s = p.y;
  }
  mred[t] = m;
  sred[t] = s;
  __syncthreads();
  for (int st = 128; st > 0; st >>= 1) {
    if (t < st) {
      float m1 = mred[t], m2 = mred[t + st];
      float mn = fmaxf(m1, m2);
      sred[t] = sred[t] * __expf(m1 - mn) + sred[t + st] * __expf(m2 - mn);
      mred[t] = mn;
    }
    __syncthreads();
  }
  m = mred[0];
  const float inv = 1.f / sred[0];
  float* p = out + (size_t)row * 32000;
  for (int i = t; i < 8000; i += 256) {
    float4 v = *(const float4*)(p + i * 4);
    v.x = __expf(v.x - m) * inv;
    v.y = __expf(v.y - m) * inv;
    v.z = __expf(v.z - m) * inv;
    v.w = __expf(v.w - m) * inv;
    *(float4*)(p + i * 4) = v;
  }
}

// =====================================================================
extern "C" void kernel_launch(void* const* d_in, const int* in_sizes, int n_in,
                              void* d_out, int out_size, void* d_ws, size_t ws_size,
                              hipStream_t stream)
{
  const int* x = (const int*)d_in[0];
  const float* emb = (const float*)d_in[1];
  const float* Wxf = (const float*)d_in[2];
  const float* Whf = (const float*)d_in[3];
  const float* bfv = (const float*)d_in[4];
  const float* Wxb = (const float*)d_in[5];
  const float* Whb = (const float*)d_in[6];
  const float* bbv = (const float*)d_in[7];
  const float* W1 = (const float*)d_in[8];
  const float* b1 = (const float*)d_in[9];
  const float* W2 = (const float*)d_in[10];
  const float* b2 = (const float*)d_in[11];
  const float* Wxd = (const float*)d_in[12];
  const float* Whd = (const float*)d_in[13];
  const float* bd = (const float*)d_in[14];
  const float* Wo = (const float*)d_in[15];
  const float* bo = (const float*)d_in[16];

  float* ws = (float*)d_ws;
  // layout (float offsets)
  float* c_f = ws + 0;
  float* c_b = ws + 16384;
  float* c_d = ws + 32768;
  uint32_t* hfp0 = (uint32_t*)(ws + 49152);
  uint32_t* hfp1 = hfp0 + 8192;
  uint32_t* hbp0 = (uint32_t*)(ws + 65536);
  uint32_t* hbp1 = hbp0 + 8192;
  uint32_t* hdp0 = (uint32_t*)(ws + 81920);
  uint32_t* hdp1 = hdp0 + 8192;
  uint32_t* W1pbAll = (uint32_t*)(ws + 98304);     // 9216 u32 (paired full W1)
  uint32_t* Wencp = (uint32_t*)(ws + 114688);      // 1,048,576 u32 (4 MB)
  uint32_t* Wdp = (uint32_t*)(ws + 1163264);       // 524,288 u32 (Whd slabs)
  ushort* aB = (ushort*)(ws + 1687552);            // 2048x1024 bf16
  float* aw1 = ws + 2742272;                       // 32768
  float* Xf = ws + 2775040;                        // 4,194,304
  float* Xb = Xf + 4194304;                        // 4,194,304
  ushort* HsB = (ushort*)(ws + 13260800);          // 2048*512 bf16
  // post-encoder overlays:
  uint32_t* ApTb = (uint32_t*)Xf;                  // 2048x1024 u32 bf16-pairs
  ushort* WxdT = (ushort*)Xb;                      // 2048x1024 bf16
  ushort* WoT = (ushort*)Xf;                       // overlays after decoder
  float2* pstats = (float2*)Wencp;                 // 2048x256 float2 (dead Wencp)

  // zero recurrent states (c_f, c_b, c_d, packed h buffers)
  hipMemsetAsync(ws, 0, 98304 * sizeof(float), stream);

  k0_pack<<<6180, 256, 0, stream>>>(Whf, Whb, Wencp, Whd, Wdp, W1, W1pbAll);

  k1_embed_gemm<<<dim3(32, 64), 256, 0, stream>>>(x, emb, Wxf, Wxb, bfv, bbv, Xf, Xb);

  for (int s = 0; s < 64; ++s) {
    const uint32_t* hfi = (s & 1) ? hfp1 : hfp0;
    uint32_t* hfo = (s & 1) ? hfp0 : hfp1;
    const uint32_t* hbi = (s & 1) ? hbp1 : hbp0;
    uint32_t* hbo = (s & 1) ? hbp0 : hbp1;
    k2_enc_step<<<512, 256, 0, stream>>>(Xf, Xb, Wencp, hfi, hfo, hbi, hbo,
                                         c_f, c_b, aB, s);
  }

  k5_aw1<<<256, 256, 0, stream>>>(aB, W1pbAll, b1, aw1);
  k_wxdT<<<dim3(32, 16), 256, 0, stream>>>(Wxd, WxdT);
  kA_aprime<<<dim3(16, 16), 256, 0, stream>>>(WxdT, aB, ApTb);

  for (int s = 0; s < 64; ++s) {
    const uint32_t* hdi = (s & 1) ? hdp1 : hdp0;
    uint32_t* hdo = (s & 1) ? hdp0 : hdp1;
    k4_dec_step<<<512, 256, 0, stream>>>(ApTb, aw1, W1pbAll + 6144, W2, b2,
                                         hdi, Wdp, bd, hdo, c_d, HsB, s);
  }

  k_woT<<<dim3(500, 8), 256, 0, stream>>>(Wo, WoT);
  // row-half split: each half's 131 MB of logits stays L3-resident
  // between its k6 (producer) and k7 (normalize) launches.
  k6_logits_mfma<<<dim3(250, 8), 256, 0, stream>>>(HsB, WoT, bo,
                                                   (float*)d_out, pstats, 0);
  k7_softmax<<<1024, 256, 0, stream>>>((float*)d_out, pstats, 0);
  k6_logits_mfma<<<dim3(250, 8), 256, 0, stream>>>(HsB, WoT, bo,
                                                   (float*)d_out, pstats, 8);
  k7_softmax<<<1024, 256, 0, stream>>>((float*)d_out, pstats, 1);
}

// Round 12
// 1527.353 us; speedup vs baseline: 1.0848x; 1.0554x over previous
//
#include <hip/hip_runtime.h>
#include <hip/hip_bf16.h>
#include <cstdint>

typedef float f32x4 __attribute__((ext_vector_type(4)));
typedef __bf16 bf16x8 __attribute__((ext_vector_type(8)));

// ---------- bf16 pack helpers (RNE) ----------
__device__ __forceinline__ uint32_t bf1(float x) {
  uint32_t u = __float_as_uint(x);
  return (u + 0x7fffu + ((u >> 16) & 1u)) >> 16;
}
__device__ __forceinline__ uint32_t bpack(float lo, float hi) {
  return bf1(lo) | (bf1(hi) << 16);
}
__device__ __forceinline__ float blo(uint32_t u) { return __uint_as_float(u << 16); }
__device__ __forceinline__ float bhi(uint32_t u) { return __uint_as_float(u & 0xffff0000u); }
__device__ __forceinline__ float sigm(float x) {
  return __fdividef(1.f, 1.f + exp2f(x * -1.4426950408889634f));
}
__device__ __forceinline__ float tanhf_fast(float x) {
  float e2 = exp2f(x * 2.8853900817779268f);
  return 1.f - __fdividef(2.f, e2 + 1.f);
}

// packed-bf16 dot2: acc += a.lo*b.lo + a.hi*b.hi (fp32 accumulate)
__device__ __forceinline__ float dot2bf(uint32_t a, uint32_t b, float acc) {
  asm("v_dot2_f32_bf16 %0, %1, %2, %0" : "+v"(acc) : "v"(a), "v"(b));
  return acc;
}

#define GLOAD_LDS16(g, l)                                                     \
  __builtin_amdgcn_global_load_lds(                                           \
      (const __attribute__((address_space(1))) void*)(g),                     \
      (__attribute__((address_space(3))) void*)(l), 16, 0, 0)

// =====================================================================
// K0: all weight packing in one launch.
// bid<4096: Whf/Whb -> MFMA-k2 layout: [dir][cg=128][c=16][512 k] bf16
//   (u32 view; slot XOR-swizzled: pos = p ^ ((c&7)<<2))
//   colg = (c>>2)*512 + cg*4 + (c&3)
// bid<6144: Whd -> [ug=64][64 q4][32 cc][4 e], col=(cc>>3)*512+ug*8+(cc&7)
// else:     W1[0:1536,:10] bf16-paired -> [768 q][12 j]
// =====================================================================
__global__ __launch_bounds__(256) void k0_pack(
    const float* __restrict__ Whf, const float* __restrict__ Whb,
    uint32_t* __restrict__ Wencp, const float* __restrict__ Whd,
    uint32_t* __restrict__ Wdp, const float* __restrict__ W1,
    uint32_t* __restrict__ W1pbAll)
{
  int bid = blockIdx.x;
  if (bid < 4096) {
    int p = bid * 256 + threadIdx.x;             // 0..2^20-1
    int j2 = p & 3, slot = (p >> 2) & 63, c = (p >> 8) & 15;
    int cg = (p >> 12) & 127, dir = p >> 19;
    int k = slot * 8 + j2 * 2;
    const float* W = dir ? Whb : Whf;
    int colg = (c >> 2) * 512 + cg * 4 + (c & 3);
    Wencp[p ^ ((c & 7) << 2)] =
        bpack(W[(size_t)k * 2048 + colg], W[(size_t)(k + 1) * 2048 + colg]);
  } else if (bid < 6144) {
    int p = (bid - 4096) * 256 + threadIdx.x;    // 0..524287
    int e = p & 3, cc = (p >> 2) & 31, q4 = (p >> 7) & 63, ug = p >> 13;
    int k2 = 4 * q4 + e;
    int col = (cc >> 3) * 512 + ug * 8 + (cc & 7);
    int k = 2 * k2;
    Wdp[p] = bpack(Whd[(size_t)k * 2048 + col], Whd[(size_t)(k + 1) * 2048 + col]);
  } else {
    int p = (bid - 6144) * 256 + threadIdx.x;    // 0..9215
    if (p < 9216) {
      int q = p / 12, j = p % 12;
      float v0 = (j < 10) ? W1[(size_t)(2 * q) * 10 + j] : 0.f;
      float v1 = (j < 10) ? W1[(size_t)(2 * q + 1) * 10 + j] : 0.f;
      W1pbAll[p] = bpack(v0, v1);
    }
  }
}

// =====================================================================
// K1: embedding gather + Xf = xe@Wxf + bf, Xb = xe@Wxb + bb (fp32 VALU)
// =====================================================================
__global__ __launch_bounds__(256) void k1_embed_gemm(
    const int* __restrict__ x, const float* __restrict__ emb,
    const float* __restrict__ Wxf, const float* __restrict__ Wxb,
    const float* __restrict__ bfv, const float* __restrict__ bbv,
    float* __restrict__ Xf, float* __restrict__ Xb)
{
  __shared__ float As[32 * 260];
  __shared__ float Bs[32 * 128];
  __shared__ int xid[32];
  const int t = threadIdx.x;
  const int ty = blockIdx.y;
  const int c0 = blockIdx.x * 128;
  if (t < 32) xid[t] = x[t * 64 + ty];
  __syncthreads();
  for (int i = 0; i < 8; ++i) {
    int f4 = t + 256 * i;
    int r = f4 >> 6, k4 = (f4 & 63) << 2;
    float4 v = *(const float4*)(emb + (size_t)xid[r] * 256 + k4);
    *(float4*)(&As[r * 260 + k4]) = v;
  }
  const int isB = (c0 >= 2048);
  const float* Wsrc = isB ? Wxb : Wxf;
  const float* bias = isB ? bbv : bfv;
  const int cbase = c0 & 2047;
  float acc[4][4] = {};
  const int rq = t >> 5;
  const int cq = t & 31;
  for (int kc = 0; kc < 8; ++kc) {
    int k0 = kc * 32;
    __syncthreads();
    for (int i = 0; i < 4; ++i) {
      int f4 = t + 256 * i;
      int k = f4 >> 5, c4 = (f4 & 31) << 2;
      *(float4*)(&Bs[k * 128 + c4]) =
          *(const float4*)(Wsrc + (size_t)(k0 + k) * 2048 + cbase + c4);
    }
    __syncthreads();
#pragma unroll
    for (int kk = 0; kk < 32; ++kk) {
      float a0 = As[(4 * rq + 0) * 260 + k0 + kk];
      float a1 = As[(4 * rq + 1) * 260 + k0 + kk];
      float a2 = As[(4 * rq + 2) * 260 + k0 + kk];
      float a3 = As[(4 * rq + 3) * 260 + k0 + kk];
      float4 b = *(const float4*)(&Bs[kk * 128 + 4 * cq]);
      acc[0][0] += a0 * b.x; acc[0][1] += a0 * b.y; acc[0][2] += a0 * b.z; acc[0][3] += a0 * b.w;
      acc[1][0] += a1 * b.x; acc[1][1] += a1 * b.y; acc[1][2] += a1 * b.z; acc[1][3] += a1 * b.w;
      acc[2][0] += a2 * b.x; acc[2][1] += a2 * b.y; acc[2][2] += a2 * b.z; acc[2][3] += a2 * b.w;
      acc[3][0] += a3 * b.x; acc[3][1] += a3 * b.y; acc[3][2] += a3 * b.z; acc[3][3] += a3 * b.w;
    }
  }
  float* Xout = isB ? Xb : Xf;
  for (int i = 0; i < 4; ++i) {
    int c = cbase + 4 * cq + i;
    float bi = bias[c];
    for (int j = 0; j < 4; ++j) {
      int b_ = 4 * rq + j;
      Xout[((size_t)ty * 2048 + c) * 32 + b_] = acc[j][i] + bi;
    }
  }
}

// =====================================================================
// K2: one encoder step both dirs via MFMA bf16.
// 512 blocks = 2 dir x 2 row-halves x 128 col-groups (16 gate-cols each).
// h global: [row 32][unit 512] bf16, slot XOR-swizzle (slot^(row&7)).
// Per block: one 16x16 C tile, K=512 split 4-ways across waves (4 MFMA
// each), LDS fp32 partial reduce, + X, gates, h/aB/c writes.
// =====================================================================
__global__ __launch_bounds__(256) void k2_enc_step(
    const float* __restrict__ Xf, const float* __restrict__ Xb,
    const uint32_t* __restrict__ Wencp,
    const uint32_t* __restrict__ hfi, uint32_t* __restrict__ hfo,
    const uint32_t* __restrict__ hbi, uint32_t* __restrict__ hbo,
    float* __restrict__ cf, float* __restrict__ cb,
    ushort* __restrict__ aB, int step)
{
  __shared__ ushort Hs[16 * 512];      // 16 KB, rows r0..r0+15 (swizzled)
  __shared__ ushort Ws[16 * 512];      // 16 KB, 16 cols (swizzled)
  __shared__ float zp[4 * 256];        // wave partials
  __shared__ float zx[256];
  __shared__ float zbuf[256];
  __shared__ float hl[64];
  const int t = threadIdx.x;
  const int dir = blockIdx.x >> 8;
  const int rh = (blockIdx.x >> 7) & 1;
  const int cg = blockIdx.x & 127;
  const int r0 = rh * 16, u0 = cg * 4;
  const float* XF = dir ? Xb : Xf;
  const uint32_t* hin = dir ? hbi : hfi;
  uint32_t* hout = dir ? hbo : hfo;
  float* cst = dir ? cb : cf;
  const int ta = dir ? (63 - step) : step;

  {
    const uint32_t* hinu = hin + r0 * 256;       // 256 u32 per row
    for (int i = 0; i < 4; ++i) {
      int b4 = (t >> 6) * 64 + 256 * i;
      GLOAD_LDS16(hinu + (size_t)(t + 256 * i) * 4, (uint32_t*)Hs + b4 * 4);
    }
    const uint32_t* wsrc = Wencp + ((size_t)dir * 128 + cg) * 4096;
    for (int i = 0; i < 4; ++i) {
      int b4 = (t >> 6) * 64 + 256 * i;
      GLOAD_LDS16(wsrc + (size_t)(t + 256 * i) * 4, (uint32_t*)Ws + b4 * 4);
    }
  }
  {
    int cl = t & 15, rl = t >> 4;
    int colg = (cl >> 2) * 512 + u0 + (cl & 3);
    zx[t] = XF[((size_t)ta * 2048 + colg) * 32 + r0 + rl];
  }
  __syncthreads();
  const int lane = t & 63, w = t >> 6;
  const int quad = lane >> 4, l15 = lane & 15;
  f32x4 acc = {};
#pragma unroll
  for (int mm = 0; mm < 4; ++mm) {
    int m = w * 4 + mm;                          // K-chunk m*32..m*32+31
    int slot = m * 4 + quad;
    bf16x8 a = *(const bf16x8*)(Hs + l15 * 512 + (slot ^ (l15 & 7)) * 8);
    bf16x8 b = *(const bf16x8*)(Ws + l15 * 512 + (slot ^ (l15 & 7)) * 8);
    acc = __builtin_amdgcn_mfma_f32_16x16x32_bf16(a, b, acc, 0, 0, 0);
  }
#pragma unroll
  for (int reg = 0; reg < 4; ++reg)
    zp[w * 256 + (quad * 4 + reg) * 16 + l15] = acc[reg];
  __syncthreads();
  zbuf[t] = zp[t] + zp[256 + t] + zp[512 + t] + zp[768 + t] + zx[t];
  __syncthreads();
  if (t < 64) {
    int rl = t & 15, ui = t >> 4;
    int u = u0 + ui, r = r0 + rl;
    float zi = zbuf[rl * 16 + ui];
    float zf = zbuf[rl * 16 + 4 + ui];
    float zg = zbuf[rl * 16 + 8 + ui];
    float zo = zbuf[rl * 16 + 12 + ui];
    float cold = cst[u * 32 + r];
    float cn = sigm(zf) * cold + sigm(zi) * tanhf_fast(zg);
    float h = sigm(zo) * tanhf_fast(cn);
    cst[u * 32 + r] = cn;
    aB[((size_t)r * 64 + ta) * 1024 + dir * 512 + u] = (ushort)bf1(h);
    hl[rl * 4 + ui] = h;
  }
  __syncthreads();
  if (t < 16) {
    int r = r0 + t;
    uint32_t lo = bpack(hl[t * 4 + 0], hl[t * 4 + 1]);
    uint32_t hi = bpack(hl[t * 4 + 2], hl[t * 4 + 3]);
    // ushort pos = r*512 + ((u0>>3)^(r&7))*8 + (u0&7); u32 pos = /2
    uint32_t* dst = hout + r * 256 + (((cg >> 1) ^ (r & 7)) * 4) + (cg & 1) * 2;
    *(uint2*)dst = make_uint2(lo, hi);
  }
}

// =====================================================================
// K5: aw1[m][j] = aB[m]@W1[:1024,j] + b1[j] via dot2, padded to 16 cols.
// =====================================================================
__global__ __launch_bounds__(256) void k5_aw1(
    const ushort* __restrict__ aB, const uint32_t* __restrict__ W1pbAll,
    const float* __restrict__ b1, float* __restrict__ aw1)
{
  __shared__ uint32_t ar[512];
  __shared__ float ps[16 * 17];
  const int t = threadIdx.x;
  const uint32_t* aBu = (const uint32_t*)aB;
  for (int m = blockIdx.x; m < 2048; m += gridDim.x) {
    __syncthreads();
    *(uint2*)(&ar[t * 2]) = *(const uint2*)(aBu + (size_t)m * 512 + t * 2);
    __syncthreads();
    int j = t & 15, part = t >> 4;
    int jj = j < 10 ? j : 0;
    float s = 0.f;
#pragma unroll 8
    for (int q = part * 32; q < part * 32 + 32; ++q)
      s = dot2bf(ar[q], W1pbAll[q * 12 + jj], s);
    ps[part * 17 + j] = s;
    __syncthreads();
    if (t < 16) {
      float sum = 0.f;
      if (t < 10) {
        for (int p = 0; p < 16; ++p) sum += ps[p * 17 + t];
        sum += b1[t];
      }
      aw1[m * 16 + t] = sum;
    }
  }
}

// =====================================================================
// K_wxdT: Wxd[1024][2048] fp32 -> WxdT[2048][1024] bf16 (LDS transpose)
// =====================================================================
__global__ __launch_bounds__(256) void k_wxdT(
    const float* __restrict__ Wxd, ushort* __restrict__ WxdT)
{
  __shared__ float tile[64 * 65];
  const int t = threadIdx.x;
  const int n0 = blockIdx.x * 64, k0 = blockIdx.y * 64;
  for (int i = 0; i < 16; ++i) {
    int p = t + 256 * i;
    int kk = p >> 6, nn = p & 63;
    tile[kk * 65 + nn] = Wxd[(size_t)(k0 + kk) * 2048 + n0 + nn];
  }
  __syncthreads();
  for (int i = 0; i < 4; ++i) {
    int p = t + 256 * i;
    int nn = p >> 4, k4 = (p & 15) * 4;
    ushort4 o;
    o.x = (ushort)bf1(tile[(k4 + 0) * 65 + nn]);
    o.y = (ushort)bf1(tile[(k4 + 1) * 65 + nn]);
    o.z = (ushort)bf1(tile[(k4 + 2) * 65 + nn]);
    o.w = (ushort)bf1(tile[(k4 + 3) * 65 + nn]);
    *(ushort4*)(WxdT + (size_t)(n0 + nn) * 1024 + k0 + k4) = o;
  }
}

// =====================================================================
// KA: A'T = (a @ Wxd)^T via MFMA bf16, output PACKED bf16 pairs.
// =====================================================================
__global__ __launch_bounds__(256) void kA_aprime(
    const ushort* __restrict__ WxdT, const ushort* __restrict__ aB,
    uint32_t* __restrict__ ApTb)
{
  __shared__ ushort As[128 * 64];
  __shared__ ushort Bs[128 * 64];
  const int t = threadIdx.x;
  const int lane = t & 63, w = t >> 6;
  const int wr = w >> 1, wc = w & 1;
  const int m0 = blockIdx.y * 128, n0 = blockIdx.x * 128;
  const int lrow = lane >> 3, s = lane & 7;
  const int quad = lane >> 4, l15 = lane & 15;
  f32x4 acc[4][4] = {};
  for (int kc = 0; kc < 16; ++kc) {
    const int k0 = kc * 64;
    __syncthreads();
    for (int i = 0; i < 4; ++i) {
      int row = w * 32 + i * 8 + lrow;
      int k8 = s ^ (row & 7);
      GLOAD_LDS16(WxdT + (size_t)(m0 + row) * 1024 + k0 + k8 * 8,
                  As + (w * 32 + i * 8) * 64);
      GLOAD_LDS16(aB + (size_t)(n0 + row) * 1024 + k0 + k8 * 8,
                  Bs + (w * 32 + i * 8) * 64);
    }
    __syncthreads();
#pragma unroll
    for (int ks = 0; ks < 2; ++ks) {
      bf16x8 af[4], bfr[4];
      int kq = ks * 4 + quad;
#pragma unroll
      for (int mi = 0; mi < 4; ++mi) {
        int row = wr * 64 + mi * 16 + l15;
        int slot = kq ^ (row & 7);
        af[mi] = *(const bf16x8*)(As + row * 64 + slot * 8);
      }
#pragma unroll
      for (int ni = 0; ni < 4; ++ni) {
        int row = wc * 64 + ni * 16 + l15;
        int slot = kq ^ (row & 7);
        bfr[ni] = *(const bf16x8*)(Bs + row * 64 + slot * 8);
      }
#pragma unroll
      for (int mi = 0; mi < 4; ++mi)
#pragma unroll
        for (int ni = 0; ni < 4; ++ni)
          acc[mi][ni] = __builtin_amdgcn_mfma_f32_16x16x32_bf16(
              af[mi], bfr[ni], acc[mi][ni], 0, 0, 0);
    }
  }
#pragma unroll
  for (int mi = 0; mi < 4; ++mi) {
    int mbase = m0 + wr * 64 + mi * 16 + quad * 4;
#pragma unroll
    for (int reg = 0; reg < 4; ++reg) {
      int m = mbase + reg;
#pragma unroll
      for (int ni = 0; ni < 4; ++ni) {
        int n = n0 + wc * 64 + ni * 16 + l15;
        float v = acc[mi][ni][reg];
        float v2 = __shfl_xor(v, 1);
        if (!(l15 & 1))
          ApTb[(size_t)m * 1024 + (n >> 1)] = bpack(v, v2);
      }
    }
  }
}

// =====================================================================
// K4: FUSED decoder step, 512 blocks = 64 unit-groups x 8 row-groups
// (4 rows each). ~63 KB LDS -> 2 blocks/CU co-resident.
// z-phase K-split across thread halves; Wsp staging deferred.
// =====================================================================
__global__ __launch_bounds__(256) void k4_dec_step(
    const uint32_t* __restrict__ ApTb, const float* __restrict__ aw1,
    const uint32_t* __restrict__ W1pb, const float* __restrict__ W2,
    const float* __restrict__ b2, const uint32_t* __restrict__ hdp_in,
    const uint32_t* __restrict__ Wdp, const float* __restrict__ bd,
    uint32_t* __restrict__ hdp_out, float* __restrict__ cd,
    ushort* __restrict__ HsB, int step)
{
  __shared__ uint32_t W1s[256 * 12];   // bf16-paired W1 rows (decoder half)
  __shared__ uint32_t hdT[1024];       // hd quads, 4-row slice [q4][4 r][4]
  __shared__ uint32_t Wsp[8192];       // Whd slab quads [q4][32 cc][4]
  __shared__ float ph[64 * 4 * 12];
  __shared__ float hw1[4 * 12];
  __shared__ float esc[4 * 65];
  __shared__ uint32_t escp[4 * 33];
  __shared__ float pm[4 * 9];
  __shared__ float mrow[4], srow[4];
  __shared__ float w2s[12];
  __shared__ float zp[2][128];
  __shared__ float zbuf[4 * 33];
  __shared__ float hl[32];
  const int t = threadIdx.x;
  const int ug = blockIdx.x >> 3;      // unit group: units u0..u0+7
  const int rg = blockIdx.x & 7;       // row group: rows r0..r0+3
  const int u0 = ug * 8, r0 = rg * 4;
  for (int i = 0; i < 3; ++i) {
    int b4 = (t >> 6) * 64 + 256 * i;
    GLOAD_LDS16(W1pb + (size_t)(t + 256 * i) * 4, W1s + (size_t)b4 * 4);
  }
  {
    int q4 = t >> 2, rl0 = t & 3;
    int b4 = (t >> 6) * 64;
    GLOAD_LDS16(hdp_in + (size_t)(q4 * 32 + r0 + rl0) * 4, hdT + (size_t)b4 * 4);
  }
  if (t < 12) w2s[t] = (t < 10) ? W2[t] : 0.f;
  __syncthreads();
  {
    const uint32_t* wsrc = Wdp + (size_t)ug * 8192;
    for (int i = 0; i < 8; ++i) {
      int b4 = (t >> 6) * 64 + 256 * i;
      GLOAD_LDS16(wsrc + (size_t)(t + 256 * i) * 4, Wsp + (size_t)b4 * 4);
    }
  }
  // ---- hw1 = hd @ W1[1024:1536, :10] for 4 rows; 64 k-parts ----
  {
    const int rl = t & 3, kp = t >> 2;
    const uint4* hd4 = (const uint4*)hdT;
    float acc[10] = {};
    {
      uint4 u4 = hd4[kp * 4 + rl];
      const uint32_t* w0 = &W1s[(4 * kp) * 12];
      const uint32_t* w1 = &W1s[(4 * kp + 1) * 12];
      const uint32_t* w2p = &W1s[(4 * kp + 2) * 12];
      const uint32_t* w3 = &W1s[(4 * kp + 3) * 12];
#pragma unroll
      for (int j = 0; j < 10; ++j) {
        acc[j] = dot2bf(u4.x, w0[j], acc[j]);
        acc[j] = dot2bf(u4.y, w1[j], acc[j]);
        acc[j] = dot2bf(u4.z, w2p[j], acc[j]);
        acc[j] = dot2bf(u4.w, w3[j], acc[j]);
      }
    }
#pragma unroll
    for (int j = 0; j < 10; ++j) ph[(kp * 4 + rl) * 12 + j] = acc[j];
  }
  __syncthreads();
  if (t < 40) {
    int rl = t / 10, j = t % 10;
    float s = 0.f;
#pragma unroll
    for (int p = 0; p < 64; ++p) s += ph[(p * 4 + rl) * 12 + j];
    hw1[rl * 12 + j] = s;
  }
  __syncthreads();
  // ---- scores (fast tanh), 4 rows x 64 tt = 1 per thread ----
  const float b2v = b2[0];
  {
    int rl = t >> 6, tt = t & 63;
    size_t m = (size_t)(r0 + rl) * 64 + tt;
    const float4* aw = (const float4*)(aw1 + m * 16);
    float4 q0 = aw[0], q1 = aw[1], q2 = aw[2];
    const float* hw = &hw1[rl * 12];
    float e = b2v;
    e += tanhf_fast(q0.x + hw[0]) * w2s[0];
    e += tanhf_fast(q0.y + hw[1]) * w2s[1];
    e += tanhf_fast(q0.z + hw[2]) * w2s[2];
    e += tanhf_fast(q0.w + hw[3]) * w2s[3];
    e += tanhf_fast(q1.x + hw[4]) * w2s[4];
    e += tanhf_fast(q1.y + hw[5]) * w2s[5];
    e += tanhf_fast(q1.z + hw[6]) * w2s[6];
    e += tanhf_fast(q1.w + hw[7]) * w2s[7];
    e += tanhf_fast(q2.x + hw[8]) * w2s[8];
    e += tanhf_fast(q2.y + hw[9]) * w2s[9];
    esc[rl * 65 + tt] = fmaxf(e, 0.f);
  }
  __syncthreads();
  if (t < 32) {
    int rl = t >> 3, part = t & 7;
    float m = -1e30f;
    for (int i = 0; i < 8; ++i) m = fmaxf(m, esc[rl * 65 + part * 8 + i]);
    pm[rl * 9 + part] = m;
  }
  __syncthreads();
  if (t < 4) {
    float m = pm[t * 9];
    for (int p = 1; p < 8; ++p) m = fmaxf(m, pm[t * 9 + p]);
    mrow[t] = m;
  }
  __syncthreads();
  if (t < 32) {
    int rl = t >> 3, part = t & 7;
    float m = mrow[rl];
    float s = 0.f;
    for (int i = 0; i < 8; ++i) s += __expf(esc[rl * 65 + part * 8 + i] - m);
    pm[rl * 9 + part] = s;
  }
  __syncthreads();
  if (t < 4) {
    float s = 0.f;
    for (int p = 0; p < 8; ++p) s += pm[t * 9 + p];
    srow[t] = __fdividef(1.f, s);
  }
  __syncthreads();
  if (t < 128) {
    int rl = t >> 5, q = t & 31;
    float m = mrow[rl], s = srow[rl];
    float v0 = __expf(esc[rl * 65 + 2 * q] - m) * s;
    float v1 = __expf(esc[rl * 65 + 2 * q + 1] - m) * s;
    escp[rl * 33 + q] = bpack(v0, v1);
  }
  __syncthreads();
  // ---- z = score@A'Tb + hd@Whd + bd (32 cols x 4 rows, K-split) ----
  {
    const int out = t & 127;
    const int ccB = out >> 2, rl = out & 3;
    const int kh = t >> 7;
    const int colg = (ccB >> 3) * 512 + u0 + (ccB & 7);
    float acc = 0.f;
    {
      const uint4* hd4 = (const uint4*)hdT;
      const uint4* wd4 = (const uint4*)Wsp;
#pragma unroll 8
      for (int q4 = kh * 32; q4 < kh * 32 + 32; ++q4) {
        uint4 ua = hd4[q4 * 4 + rl];
        uint4 ub = wd4[q4 * 32 + ccB];
        acc = dot2bf(ua.x, ub.x, acc);
        acc = dot2bf(ua.y, ub.y, acc);
        acc = dot2bf(ua.z, ub.z, acc);
        acc = dot2bf(ua.w, ub.w, acc);
      }
    }
    {
      const uint32_t* ap = ApTb + (size_t)colg * 1024 + (r0 + rl) * 32;
      const uint32_t* ep = &escp[rl * 33];
#pragma unroll
      for (int i8 = kh * 4; i8 < kh * 4 + 4; ++i8) {
        uint4 v = *(const uint4*)(ap + i8 * 4);
        acc = dot2bf(v.x, ep[4 * i8 + 0], acc);
        acc = dot2bf(v.y, ep[4 * i8 + 1], acc);
        acc = dot2bf(v.z, ep[4 * i8 + 2], acc);
        acc = dot2bf(v.w, ep[4 * i8 + 3], acc);
      }
    }
    zp[kh][out] = acc;
  }
  __syncthreads();
  if (t < 128) {
    int ccB = t >> 2, rl = t & 3;
    int colg = (ccB >> 3) * 512 + u0 + (ccB & 7);
    zbuf[rl * 33 + ccB] = zp[0][t] + zp[1][t] + bd[colg];
  }
  __syncthreads();
  if (t < 32) {
    int j = t >> 2, rr = t & 3;
    int u = u0 + j, rgl = r0 + rr;
    float zi = zbuf[rr * 33 + j];
    float zf = zbuf[rr * 33 + 8 + j];
    float zg = zbuf[rr * 33 + 16 + j];
    float zo = zbuf[rr * 33 + 24 + j];
    float cold = cd[u * 32 + rgl];
    float cn = sigm(zf) * cold + sigm(zi) * tanhf_fast(zg);
    float h = sigm(zo) * tanhf_fast(cn);
    cd[u * 32 + rgl] = cn;
    HsB[(size_t)(step * 32 + rgl) * 512 + u] = (ushort)bf1(h);
    hl[j * 4 + rr] = h;
  }
  __syncthreads();
  if (t < 16) {
    int p = t >> 2, rr = t & 3;
    hdp_out[ug * 128 + (r0 + rr) * 4 + p] =
        bpack(hl[(2 * p) * 4 + rr], hl[(2 * p + 1) * 4 + rr]);
  }
}

// =====================================================================
// K_woT: Wo[512][32000] fp32 -> WoT[32000][512] bf16 (LDS transpose)
// =====================================================================
__global__ __launch_bounds__(256) void k_woT(
    const float* __restrict__ Wo, ushort* __restrict__ WoT)
{
  __shared__ float tile[64 * 65];
  const int t = threadIdx.x;
  const int n0 = blockIdx.x * 64, k0 = blockIdx.y * 64;
  for (int i = 0; i < 16; ++i) {
    int p = t + 256 * i;
    int kk = p >> 6, nn = p & 63;
    tile[kk * 65 + nn] = Wo[(size_t)(k0 + kk) * 32000 + n0 + nn];
  }
  __syncthreads();
  for (int i = 0; i < 4; ++i) {
    int p = t + 256 * i;
    int nn = p >> 4, k4 = (p & 15) * 4;
    ushort4 o;
    o.x = (ushort)bf1(tile[(k4 + 0) * 65 + nn]);
    o.y = (ushort)bf1(tile[(k4 + 1) * 65 + nn]);
    o.z = (ushort)bf1(tile[(k4 + 2) * 65 + nn]);
    o.w = (ushort)bf1(tile[(k4 + 3) * 65 + nn]);
    *(ushort4*)(WoT + (size_t)(n0 + nn) * 512 + k0 + k4) = o;
  }
}

// =====================================================================
// K6: logits = HsB[2048,512] @ WoT^T + bo via MFMA bf16.
// m-tile offset moff lets the launch run in row-halves (L3 reuse).
// Epilogue emits per-(outrow, ntile) softmax partials (max, sumexp).
// =====================================================================
__global__ __launch_bounds__(256) void k6_logits_mfma(
    const ushort* __restrict__ HsB, const ushort* __restrict__ WoT,
    const float* __restrict__ bo, float* __restrict__ out,
    float2* __restrict__ pstats, int moff)
{
  __shared__ ushort As[128 * 64];
  __shared__ ushort Bs[128 * 64];
  const int t = threadIdx.x;
  const int lane = t & 63, w = t >> 6;
  const int wr = w >> 1, wc = w & 1;
  const int m0 = (blockIdx.y + moff) * 128, n0 = blockIdx.x * 128;
  const int lrow = lane >> 3, s = lane & 7;
  const int quad = lane >> 4, l15 = lane & 15;
  f32x4 acc[4][4] = {};
  for (int kc = 0; kc < 8; ++kc) {
    const int k0 = kc * 64;
    __syncthreads();
    for (int i = 0; i < 4; ++i) {
      int row = w * 32 + i * 8 + lrow;
      int k8 = s ^ (row & 7);
      GLOAD_LDS16(HsB + (size_t)(m0 + row) * 512 + k0 + k8 * 8,
                  As + (w * 32 + i * 8) * 64);
      GLOAD_LDS16(WoT + (size_t)(n0 + row) * 512 + k0 + k8 * 8,
                  Bs + (w * 32 + i * 8) * 64);
    }
    __syncthreads();
#pragma unroll
    for (int ks = 0; ks < 2; ++ks) {
      bf16x8 af[4], bfr[4];
      int kq = ks * 4 + quad;
#pragma unroll
      for (int mi = 0; mi < 4; ++mi) {
        int row = wr * 64 + mi * 16 + l15;
        int slot = kq ^ (row & 7);
        af[mi] = *(const bf16x8*)(As + row * 64 + slot * 8);
      }
#pragma unroll
      for (int ni = 0; ni < 4; ++ni) {
        int row = wc * 64 + ni * 16 + l15;
        int slot = kq ^ (row & 7);
        bfr[ni] = *(const bf16x8*)(Bs + row * 64 + slot * 8);
      }
#pragma unroll
      for (int mi = 0; mi < 4; ++mi)
#pragma unroll
        for (int ni = 0; ni < 4; ++ni)
          acc[mi][ni] = __builtin_amdgcn_mfma_f32_16x16x32_bf16(
              af[mi], bfr[ni], acc[mi][ni], 0, 0, 0);
    }
  }
  __syncthreads();                    // As/Bs dead; reuse as partial arrays
  float* pmx = (float*)As;            // [128 rows][32 slots]
  float* psm = (float*)Bs;
#pragma unroll
  for (int mi = 0; mi < 4; ++mi) {
    int mbase = m0 + wr * 64 + mi * 16 + quad * 4;
#pragma unroll
    for (int reg = 0; reg < 4; ++reg) {
      int m = mbase + reg;
      int rowl = (m - m0);
      size_t rowbase = ((size_t)(m & 31) * 64 + (m >> 5)) * 32000;
      float vs[4];
      float mx = -1e30f;
#pragma unroll
      for (int ni = 0; ni < 4; ++ni) {
        int n = n0 + wc * 64 + ni * 16 + l15;
        float v = acc[mi][ni][reg] + bo[n];
        out[rowbase + n] = v;
        vs[ni] = v;
        mx = fmaxf(mx, v);
      }
      float sl = __expf(vs[0] - mx) + __expf(vs[1] - mx) +
                 __expf(vs[2] - mx) + __expf(vs[3] - mx);
      pmx[rowl * 32 + wc * 16 + l15] = mx;
      psm[rowl * 32 + wc * 16 + l15] = sl;
    }
  }
  __syncthreads();
  if (t < 128) {
    float m = pmx[t * 32], sacc = psm[t * 32];
    for (int i = 1; i < 32; ++i) {
      float m2 = pmx[t * 32 + i], s2 = psm[t * 32 + i];
      float mn = fmaxf(m, m2);
      sacc = sacc * __expf(m - mn) + s2 * __expf(m2 - mn);
      m = mn;
    }
    int mg = m0 + t;
    int outrow = (mg & 31) * 64 + (mg >> 5);
    pstats[(size_t)outrow * 256 + blockIdx.x] = make_float2(m, sacc);
  }
}

// =====================================================================
// K7: row softmax normalize for one m-half (1024 rows), using pstats.
// =====================================================================
__global__ __launch_bounds__(256) void k7_softmax(
    float* __restrict__ out, const float2* __restrict__ pstats, int half)
{
  __shared__ float mred[256], sred[256];
  const int t = threadIdx.x;
  const int mg = half * 1024 + blockIdx.x;
  const int row = (mg & 31) * 64 + (mg >> 5);
  float m = -1e30f, s = 0.f;
  if (t < 250) {
    float2 p = pstats[(size_t)row * 256 + t];
    m = p.x;
    s = p.y;
  }
  mred[t] = m;
  sred[t] = s;
  __syncthreads();
  for (int st = 128; st > 0; st >>= 1) {
    if (t < st) {
      float m1 = mred[t], m2 = mred[t + st];
      float mn = fmaxf(m1, m2);
      sred[t] = sred[t] * __expf(m1 - mn) + sred[t + st] * __expf(m2 - mn);
      mred[t] = mn;
    }
    __syncthreads();
  }
  m = mred[0];
  const float inv = 1.f / sred[0];
  float* p = out + (size_t)row * 32000;
  for (int i = t; i < 8000; i += 256) {
    float4 v = *(const float4*)(p + i * 4);
    v.x = __expf(v.x - m) * inv;
    v.y = __expf(v.y - m) * inv;
    v.z = __expf(v.z - m) * inv;
    v.w = __expf(v.w - m) * inv;
    *(float4*)(p + i * 4) = v;
  }
}

// =====================================================================
extern "C" void kernel_launch(void* const* d_in, const int* in_sizes, int n_in,
                              void* d_out, int out_size, void* d_ws, size_t ws_size,
                              hipStream_t stream)
{
  const int* x = (const int*)d_in[0];
  const float* emb = (const float*)d_in[1];
  const float* Wxf = (const float*)d_in[2];
  const float* Whf = (const float*)d_in[3];
  const float* bfv = (const float*)d_in[4];
  const float* Wxb = (const float*)d_in[5];
  const float* Whb = (const float*)d_in[6];
  const float* bbv = (const float*)d_in[7];
  const float* W1 = (const float*)d_in[8];
  const float* b1 = (const float*)d_in[9];
  const float* W2 = (const float*)d_in[10];
  const float* b2 = (const float*)d_in[11];
  const float* Wxd = (const float*)d_in[12];
  const float* Whd = (const float*)d_in[13];
  const float* bd = (const float*)d_in[14];
  const float* Wo = (const float*)d_in[15];
  const float* bo = (const float*)d_in[16];

  float* ws = (float*)d_ws;
  // layout (float offsets)
  float* c_f = ws + 0;
  float* c_b = ws + 16384;
  float* c_d = ws + 32768;
  uint32_t* hfp0 = (uint32_t*)(ws + 49152);   // 32KB: [32 r][512 u] bf16 swz
  uint32_t* hfp1 = hfp0 + 8192;
  uint32_t* hbp0 = (uint32_t*)(ws + 65536);
  uint32_t* hbp1 = hbp0 + 8192;
  uint32_t* hdp0 = (uint32_t*)(ws + 81920);
  uint32_t* hdp1 = hdp0 + 8192;
  uint32_t* W1pbAll = (uint32_t*)(ws + 98304);     // 9216 u32 (paired full W1)
  uint32_t* Wencp = (uint32_t*)(ws + 114688);      // 1,048,576 u32 (4 MB)
  uint32_t* Wdp = (uint32_t*)(ws + 1163264);       // 524,288 u32 (Whd slabs)
  ushort* aB = (ushort*)(ws + 1687552);            // 2048x1024 bf16
  float* aw1 = ws + 2742272;                       // 32768
  float* Xf = ws + 2775040;                        // 4,194,304
  float* Xb = Xf + 4194304;                        // 4,194,304
  ushort* HsB = (ushort*)(ws + 13260800);          // 2048*512 bf16
  // post-encoder overlays:
  uint32_t* ApTb = (uint32_t*)Xf;                  // 2048x1024 u32 bf16-pairs
  ushort* WxdT = (ushort*)Xb;                      // 2048x1024 bf16
  ushort* WoT = (ushort*)Xf;                       // overlays after decoder
  float2* pstats = (float2*)Wencp;                 // 2048x256 float2 (dead Wencp)

  // zero recurrent states (c_f, c_b, c_d, packed h buffers)
  hipMemsetAsync(ws, 0, 98304 * sizeof(float), stream);

  k0_pack<<<6180, 256, 0, stream>>>(Whf, Whb, Wencp, Whd, Wdp, W1, W1pbAll);

  k1_embed_gemm<<<dim3(32, 64), 256, 0, stream>>>(x, emb, Wxf, Wxb, bfv, bbv, Xf, Xb);

  for (int s = 0; s < 64; ++s) {
    const uint32_t* hfi = (s & 1) ? hfp1 : hfp0;
    uint32_t* hfo = (s & 1) ? hfp0 : hfp1;
    const uint32_t* hbi = (s & 1) ? hbp1 : hbp0;
    uint32_t* hbo = (s & 1) ? hbp0 : hbp1;
    k2_enc_step<<<512, 256, 0, stream>>>(Xf, Xb, Wencp, hfi, hfo, hbi, hbo,
                                         c_f, c_b, aB, s);
  }

  k5_aw1<<<256, 256, 0, stream>>>(aB, W1pbAll, b1, aw1);
  k_wxdT<<<dim3(32, 16), 256, 0, stream>>>(Wxd, WxdT);
  kA_aprime<<<dim3(16, 16), 256, 0, stream>>>(WxdT, aB, ApTb);

  for (int s = 0; s < 64; ++s) {
    const uint32_t* hdi = (s & 1) ? hdp1 : hdp0;
    uint32_t* hdo = (s & 1) ? hdp0 : hdp1;
    k4_dec_step<<<512, 256, 0, stream>>>(ApTb, aw1, W1pbAll + 6144, W2, b2,
                                         hdi, Wdp, bd, hdo, c_d, HsB, s);
  }

  k_woT<<<dim3(500, 8), 256, 0, stream>>>(Wo, WoT);
  // row-half split: each half's 131 MB of logits stays L3-resident
  // between its k6 (producer) and k7 (normalize) launches.
  k6_logits_mfma<<<dim3(250, 8), 256, 0, stream>>>(HsB, WoT, bo,
                                                   (float*)d_out, pstats, 0);
  k7_softmax<<<1024, 256, 0, stream>>>((float*)d_out, pstats, 0);
  k6_logits_mfma<<<dim3(250, 8), 256, 0, stream>>>(HsB, WoT, bo,
                                                   (float*)d_out, pstats, 8);
  k7_softmax<<<1024, 256, 0, stream>>>((float*)d_out, pstats, 1);
}

// Round 13
// 1479.151 us; speedup vs baseline: 1.1202x; 1.0326x over previous
//
#include <hip/hip_runtime.h>
#include <hip/hip_bf16.h>
#include <cstdint>

typedef float f32x4 __attribute__((ext_vector_type(4)));
typedef __bf16 bf16x8 __attribute__((ext_vector_type(8)));

// ---------- bf16 pack helpers (RNE) ----------
__device__ __forceinline__ uint32_t bf1(float x) {
  uint32_t u = __float_as_uint(x);
  return (u + 0x7fffu + ((u >> 16) & 1u)) >> 16;
}
__device__ __forceinline__ uint32_t bpack(float lo, float hi) {
  return bf1(lo) | (bf1(hi) << 16);
}
__device__ __forceinline__ float blo(uint32_t u) { return __uint_as_float(u << 16); }
__device__ __forceinline__ float bhi(uint32_t u) { return __uint_as_float(u & 0xffff0000u); }
__device__ __forceinline__ float sigm(float x) {
  return __fdividef(1.f, 1.f + exp2f(x * -1.4426950408889634f));
}
__device__ __forceinline__ float tanhf_fast(float x) {
  float e2 = exp2f(x * 2.8853900817779268f);
  return 1.f - __fdividef(2.f, e2 + 1.f);
}

// packed-bf16 dot2: acc += a.lo*b.lo + a.hi*b.hi (fp32 accumulate)
__device__ __forceinline__ float dot2bf(uint32_t a, uint32_t b, float acc) {
  asm("v_dot2_f32_bf16 %0, %1, %2, %0" : "+v"(acc) : "v"(a), "v"(b));
  return acc;
}

#define GLOAD_LDS16(g, l)                                                     \
  __builtin_amdgcn_global_load_lds(                                           \
      (const __attribute__((address_space(1))) void*)(g),                     \
      (__attribute__((address_space(3))) void*)(l), 16, 0, 0)

// =====================================================================
// K0: all weight packing in one launch.
// bid<4096: Whf/Whb -> MFMA-k2 layout: [dir][cg=128][c=16][512 k] bf16
//   (u32 view; slot XOR-swizzled: pos = p ^ ((c&7)<<2))
// bid<6144: Whd -> [ug=64][64 q4][32 cc][4 e], col=(cc>>3)*512+ug*8+(cc&7)
// else:     W1[0:1536,:10] bf16-paired -> [768 q][12 j]
// =====================================================================
__global__ __launch_bounds__(256) void k0_pack(
    const float* __restrict__ Whf, const float* __restrict__ Whb,
    uint32_t* __restrict__ Wencp, const float* __restrict__ Whd,
    uint32_t* __restrict__ Wdp, const float* __restrict__ W1,
    uint32_t* __restrict__ W1pbAll)
{
  int bid = blockIdx.x;
  if (bid < 4096) {
    int p = bid * 256 + threadIdx.x;             // 0..2^20-1
    int j2 = p & 3, slot = (p >> 2) & 63, c = (p >> 8) & 15;
    int cg = (p >> 12) & 127, dir = p >> 19;
    int k = slot * 8 + j2 * 2;
    const float* W = dir ? Whb : Whf;
    int colg = (c >> 2) * 512 + cg * 4 + (c & 3);
    Wencp[p ^ ((c & 7) << 2)] =
        bpack(W[(size_t)k * 2048 + colg], W[(size_t)(k + 1) * 2048 + colg]);
  } else if (bid < 6144) {
    int p = (bid - 4096) * 256 + threadIdx.x;    // 0..524287
    int e = p & 3, cc = (p >> 2) & 31, q4 = (p >> 7) & 63, ug = p >> 13;
    int k2 = 4 * q4 + e;
    int col = (cc >> 3) * 512 + ug * 8 + (cc & 7);
    int k = 2 * k2;
    Wdp[p] = bpack(Whd[(size_t)k * 2048 + col], Whd[(size_t)(k + 1) * 2048 + col]);
  } else {
    int p = (bid - 6144) * 256 + threadIdx.x;    // 0..9215
    if (p < 9216) {
      int q = p / 12, j = p % 12;
      float v0 = (j < 10) ? W1[(size_t)(2 * q) * 10 + j] : 0.f;
      float v1 = (j < 10) ? W1[(size_t)(2 * q + 1) * 10 + j] : 0.f;
      W1pbAll[p] = bpack(v0, v1);
    }
  }
}

// =====================================================================
// K_wT: generic transpose-pack: src[K][N] fp32 -> dst[N][K] bf16.
// grid (N/64, K/64). Replaces k_wxdT / k_woT; also packs Wxf/Wxb.
// =====================================================================
__global__ __launch_bounds__(256) void k_wT(
    const float* __restrict__ src, ushort* __restrict__ dst, int K, int N)
{
  __shared__ float tile[64 * 65];
  const int t = threadIdx.x;
  const int n0 = blockIdx.x * 64, k0 = blockIdx.y * 64;
  for (int i = 0; i < 16; ++i) {
    int p = t + 256 * i;
    int kk = p >> 6, nn = p & 63;
    tile[kk * 65 + nn] = src[(size_t)(k0 + kk) * N + n0 + nn];
  }
  __syncthreads();
  for (int i = 0; i < 4; ++i) {
    int p = t + 256 * i;
    int nn = p >> 4, k4 = (p & 15) * 4;
    ushort4 o;
    o.x = (ushort)bf1(tile[(k4 + 0) * 65 + nn]);
    o.y = (ushort)bf1(tile[(k4 + 1) * 65 + nn]);
    o.z = (ushort)bf1(tile[(k4 + 2) * 65 + nn]);
    o.w = (ushort)bf1(tile[(k4 + 3) * 65 + nn]);
    *(ushort4*)(dst + (size_t)(n0 + nn) * K + k0 + k4) = o;
  }
}

// =====================================================================
// K1: X = gather(emb,x) @ Wx + b via MFMA bf16.
// grid (32 n-tiles, 16 m-tiles), 4 waves each own 32 C-rows x 128 cols.
// A staged fp32 (gathered, granule-swizzled source, linear dest),
// converted to bf16 once per element in-register. B = WxT bf16 (k6-style).
// Output X[token][col] fp32 (+bias), token = b*64+ta.
// =====================================================================
__global__ __launch_bounds__(256) void k1_embed_mfma(
    const int* __restrict__ x, const float* __restrict__ emb,
    const ushort* __restrict__ WxfT, const ushort* __restrict__ WxbT,
    const float* __restrict__ bfv, const float* __restrict__ bbv,
    float* __restrict__ Xf, float* __restrict__ Xb)
{
  __shared__ float Afp[128 * 64];      // 32 KB
  __shared__ ushort Bs[128 * 64];      // 16 KB
  __shared__ int xid[128];
  const int t = threadIdx.x;
  const int n0g = blockIdx.x * 128;
  const int m0 = blockIdx.y * 128;
  const int isB = (n0g >= 2048);
  const int n0 = n0g & 2047;
  const ushort* WT = isB ? WxbT : WxfT;
  const float* bias = isB ? bbv : bfv;
  if (t < 128) xid[t] = x[m0 + t];
  __syncthreads();
  int xr[8];
#pragma unroll
  for (int i = 0; i < 8; ++i) xr[i] = xid[(t >> 4) + 16 * i];
  const int lane = t & 63, w = t >> 6;
  const int quad = lane >> 4, l15 = lane & 15;
  f32x4 acc[2][8] = {};
  for (int kc = 0; kc < 4; ++kc) {
    const int k0 = kc * 64;
    __syncthreads();
    // stage A: 128 rows x 64 fp32; dest linear 16B chunks, src swizzled
    for (int i = 0; i < 8; ++i) {
      int idx = t + 256 * i;            // 16B-chunk index, 0..2047
      int row = (t >> 4) + 16 * i, ch = idx & 15;
      int gr = (ch >> 1) ^ (row & 7), w16 = ch & 1;
      GLOAD_LDS16(emb + (size_t)xr[i] * 256 + k0 + gr * 8 + w16 * 4,
                  Afp + idx * 4);
    }
    // stage B: 128 rows x 64 bf16
    for (int i = 0; i < 4; ++i) {
      int idx = t + 256 * i;            // 16B-chunk (8 ushort), 0..1023
      int row = idx >> 3, s8 = (idx & 7) ^ (row & 7);
      GLOAD_LDS16(WT + (size_t)(n0 + row) * 256 + k0 + s8 * 8,
                  Bs + idx * 8);
    }
    __syncthreads();
#pragma unroll
    for (int ks = 0; ks < 2; ++ks) {
      int kq = ks * 4 + quad;
      bf16x8 af[2];
#pragma unroll
      for (int mi = 0; mi < 2; ++mi) {
        int row = w * 32 + mi * 16 + l15;
        int slot = kq ^ (row & 7);
        const float* ap = Afp + row * 64 + slot * 8;
        float4 a0 = *(const float4*)ap;
        float4 a1 = *(const float4*)(ap + 4);
        union { ushort u[8]; bf16x8 v; } cv;
        cv.u[0] = (ushort)bf1(a0.x); cv.u[1] = (ushort)bf1(a0.y);
        cv.u[2] = (ushort)bf1(a0.z); cv.u[3] = (ushort)bf1(a0.w);
        cv.u[4] = (ushort)bf1(a1.x); cv.u[5] = (ushort)bf1(a1.y);
        cv.u[6] = (ushort)bf1(a1.z); cv.u[7] = (ushort)bf1(a1.w);
        af[mi] = cv.v;
      }
#pragma unroll
      for (int ni = 0; ni < 8; ++ni) {
        int rowB = ni * 16 + l15;
        int slotB = kq ^ (rowB & 7);
        bf16x8 bfr = *(const bf16x8*)(Bs + rowB * 64 + slotB * 8);
#pragma unroll
        for (int mi = 0; mi < 2; ++mi)
          acc[mi][ni] = __builtin_amdgcn_mfma_f32_16x16x32_bf16(
              af[mi], bfr, acc[mi][ni], 0, 0, 0);
      }
    }
  }
  float* Xout = isB ? Xb : Xf;
  float bcol[8];
#pragma unroll
  for (int ni = 0; ni < 8; ++ni) bcol[ni] = bias[n0 + ni * 16 + l15];
#pragma unroll
  for (int mi = 0; mi < 2; ++mi) {
#pragma unroll
    for (int reg = 0; reg < 4; ++reg) {
      int token = m0 + w * 32 + mi * 16 + quad * 4 + reg;
#pragma unroll
      for (int ni = 0; ni < 8; ++ni) {
        int col = n0 + ni * 16 + l15;
        Xout[(size_t)token * 2048 + col] = acc[mi][ni][reg] + bcol[ni];
      }
    }
  }
}

// =====================================================================
// K2: one encoder step both dirs via MFMA bf16.
// 512 blocks = 2 dir x 2 row-halves x 128 col-groups (16 gate-cols each).
// X layout now [token][col] (token = r*64+ta).
// =====================================================================
__global__ __launch_bounds__(256) void k2_enc_step(
    const float* __restrict__ Xf, const float* __restrict__ Xb,
    const uint32_t* __restrict__ Wencp,
    const uint32_t* __restrict__ hfi, uint32_t* __restrict__ hfo,
    const uint32_t* __restrict__ hbi, uint32_t* __restrict__ hbo,
    float* __restrict__ cf, float* __restrict__ cb,
    ushort* __restrict__ aB, int step)
{
  __shared__ ushort Hs[16 * 512];      // 16 KB, rows r0..r0+15 (swizzled)
  __shared__ ushort Ws[16 * 512];      // 16 KB, 16 cols (swizzled)
  __shared__ float zp[4 * 256];        // wave partials
  __shared__ float zx[256];
  __shared__ float zbuf[256];
  __shared__ float hl[64];
  const int t = threadIdx.x;
  const int dir = blockIdx.x >> 8;
  const int rh = (blockIdx.x >> 7) & 1;
  const int cg = blockIdx.x & 127;
  const int r0 = rh * 16, u0 = cg * 4;
  const float* XF = dir ? Xb : Xf;
  const uint32_t* hin = dir ? hbi : hfi;
  uint32_t* hout = dir ? hbo : hfo;
  float* cst = dir ? cb : cf;
  const int ta = dir ? (63 - step) : step;

  {
    const uint32_t* hinu = hin + r0 * 256;       // 256 u32 per row
    for (int i = 0; i < 4; ++i) {
      int b4 = (t >> 6) * 64 + 256 * i;
      GLOAD_LDS16(hinu + (size_t)(t + 256 * i) * 4, (uint32_t*)Hs + b4 * 4);
    }
    const uint32_t* wsrc = Wencp + ((size_t)dir * 128 + cg) * 4096;
    for (int i = 0; i < 4; ++i) {
      int b4 = (t >> 6) * 64 + 256 * i;
      GLOAD_LDS16(wsrc + (size_t)(t + 256 * i) * 4, (uint32_t*)Ws + b4 * 4);
    }
  }
  {
    int cl = t & 15, rl = t >> 4;
    int colg = (cl >> 2) * 512 + u0 + (cl & 3);
    zx[t] = XF[(size_t)((r0 + rl) * 64 + ta) * 2048 + colg];
  }
  __syncthreads();
  const int lane = t & 63, w = t >> 6;
  const int quad = lane >> 4, l15 = lane & 15;
  f32x4 acc = {};
#pragma unroll
  for (int mm = 0; mm < 4; ++mm) {
    int m = w * 4 + mm;                          // K-chunk m*32..m*32+31
    int slot = m * 4 + quad;
    bf16x8 a = *(const bf16x8*)(Hs + l15 * 512 + (slot ^ (l15 & 7)) * 8);
    bf16x8 b = *(const bf16x8*)(Ws + l15 * 512 + (slot ^ (l15 & 7)) * 8);
    acc = __builtin_amdgcn_mfma_f32_16x16x32_bf16(a, b, acc, 0, 0, 0);
  }
#pragma unroll
  for (int reg = 0; reg < 4; ++reg)
    zp[w * 256 + (quad * 4 + reg) * 16 + l15] = acc[reg];
  __syncthreads();
  zbuf[t] = zp[t] + zp[256 + t] + zp[512 + t] + zp[768 + t] + zx[t];
  __syncthreads();
  if (t < 64) {
    int rl = t & 15, ui = t >> 4;
    int u = u0 + ui, r = r0 + rl;
    float zi = zbuf[rl * 16 + ui];
    float zf = zbuf[rl * 16 + 4 + ui];
    float zg = zbuf[rl * 16 + 8 + ui];
    float zo = zbuf[rl * 16 + 12 + ui];
    float cold = cst[u * 32 + r];
    float cn = sigm(zf) * cold + sigm(zi) * tanhf_fast(zg);
    float h = sigm(zo) * tanhf_fast(cn);
    cst[u * 32 + r] = cn;
    aB[((size_t)r * 64 + ta) * 1024 + dir * 512 + u] = (ushort)bf1(h);
    hl[rl * 4 + ui] = h;
  }
  __syncthreads();
  if (t < 16) {
    int r = r0 + t;
    uint32_t lo = bpack(hl[t * 4 + 0], hl[t * 4 + 1]);
    uint32_t hi = bpack(hl[t * 4 + 2], hl[t * 4 + 3]);
    uint32_t* dst = hout + r * 256 + (((cg >> 1) ^ (r & 7)) * 4) + (cg & 1) * 2;
    *(uint2*)dst = make_uint2(lo, hi);
  }
}

// =====================================================================
// K5: aw1[m][j] = aB[m]@W1[:1024,j] + b1[j] via dot2, padded to 16 cols.
// =====================================================================
__global__ __launch_bounds__(256) void k5_aw1(
    const ushort* __restrict__ aB, const uint32_t* __restrict__ W1pbAll,
    const float* __restrict__ b1, float* __restrict__ aw1)
{
  __shared__ uint32_t ar[512];
  __shared__ float ps[16 * 17];
  const int t = threadIdx.x;
  const uint32_t* aBu = (const uint32_t*)aB;
  for (int m = blockIdx.x; m < 2048; m += gridDim.x) {
    __syncthreads();
    *(uint2*)(&ar[t * 2]) = *(const uint2*)(aBu + (size_t)m * 512 + t * 2);
    __syncthreads();
    int j = t & 15, part = t >> 4;
    int jj = j < 10 ? j : 0;
    float s = 0.f;
#pragma unroll 8
    for (int q = part * 32; q < part * 32 + 32; ++q)
      s = dot2bf(ar[q], W1pbAll[q * 12 + jj], s);
    ps[part * 17 + j] = s;
    __syncthreads();
    if (t < 16) {
      float sum = 0.f;
      if (t < 10) {
        for (int p = 0; p < 16; ++p) sum += ps[p * 17 + t];
        sum += b1[t];
      }
      aw1[m * 16 + t] = sum;
    }
  }
}

// =====================================================================
// KA: A'T = (a @ Wxd)^T via MFMA bf16, output PACKED bf16 pairs.
// =====================================================================
__global__ __launch_bounds__(256) void kA_aprime(
    const ushort* __restrict__ WxdT, const ushort* __restrict__ aB,
    uint32_t* __restrict__ ApTb)
{
  __shared__ ushort As[128 * 64];
  __shared__ ushort Bs[128 * 64];
  const int t = threadIdx.x;
  const int lane = t & 63, w = t >> 6;
  const int wr = w >> 1, wc = w & 1;
  const int m0 = blockIdx.y * 128, n0 = blockIdx.x * 128;
  const int lrow = lane >> 3, s = lane & 7;
  const int quad = lane >> 4, l15 = lane & 15;
  f32x4 acc[4][4] = {};
  for (int kc = 0; kc < 16; ++kc) {
    const int k0 = kc * 64;
    __syncthreads();
    for (int i = 0; i < 4; ++i) {
      int row = w * 32 + i * 8 + lrow;
      int k8 = s ^ (row & 7);
      GLOAD_LDS16(WxdT + (size_t)(m0 + row) * 1024 + k0 + k8 * 8,
                  As + (w * 32 + i * 8) * 64);
      GLOAD_LDS16(aB + (size_t)(n0 + row) * 1024 + k0 + k8 * 8,
                  Bs + (w * 32 + i * 8) * 64);
    }
    __syncthreads();
#pragma unroll
    for (int ks = 0; ks < 2; ++ks) {
      bf16x8 af[4], bfr[4];
      int kq = ks * 4 + quad;
#pragma unroll
      for (int mi = 0; mi < 4; ++mi) {
        int row = wr * 64 + mi * 16 + l15;
        int slot = kq ^ (row & 7);
        af[mi] = *(const bf16x8*)(As + row * 64 + slot * 8);
      }
#pragma unroll
      for (int ni = 0; ni < 4; ++ni) {
        int row = wc * 64 + ni * 16 + l15;
        int slot = kq ^ (row & 7);
        bfr[ni] = *(const bf16x8*)(Bs + row * 64 + slot * 8);
      }
#pragma unroll
      for (int mi = 0; mi < 4; ++mi)
#pragma unroll
        for (int ni = 0; ni < 4; ++ni)
          acc[mi][ni] = __builtin_amdgcn_mfma_f32_16x16x32_bf16(
              af[mi], bfr[ni], acc[mi][ni], 0, 0, 0);
    }
  }
#pragma unroll
  for (int mi = 0; mi < 4; ++mi) {
    int mbase = m0 + wr * 64 + mi * 16 + quad * 4;
#pragma unroll
    for (int reg = 0; reg < 4; ++reg) {
      int m = mbase + reg;
#pragma unroll
      for (int ni = 0; ni < 4; ++ni) {
        int n = n0 + wc * 64 + ni * 16 + l15;
        float v = acc[mi][ni][reg];
        float v2 = __shfl_xor(v, 1);
        if (!(l15 & 1))
          ApTb[(size_t)m * 1024 + (n >> 1)] = bpack(v, v2);
      }
    }
  }
}

// =====================================================================
// K4: FUSED decoder step, 512 blocks = 64 unit-groups x 8 row-groups
// (4 rows each). ~63 KB LDS -> 2 blocks/CU co-resident.
// =====================================================================
__global__ __launch_bounds__(256) void k4_dec_step(
    const uint32_t* __restrict__ ApTb, const float* __restrict__ aw1,
    const uint32_t* __restrict__ W1pb, const float* __restrict__ W2,
    const float* __restrict__ b2, const uint32_t* __restrict__ hdp_in,
    const uint32_t* __restrict__ Wdp, const float* __restrict__ bd,
    uint32_t* __restrict__ hdp_out, float* __restrict__ cd,
    ushort* __restrict__ HsB, int step)
{
  __shared__ uint32_t W1s[256 * 12];   // bf16-paired W1 rows (decoder half)
  __shared__ uint32_t hdT[1024];       // hd quads, 4-row slice [q4][4 r][4]
  __shared__ uint32_t Wsp[8192];       // Whd slab quads [q4][32 cc][4]
  __shared__ float ph[64 * 4 * 12];
  __shared__ float hw1[4 * 12];
  __shared__ float esc[4 * 65];
  __shared__ uint32_t escp[4 * 33];
  __shared__ float pm[4 * 9];
  __shared__ float mrow[4], srow[4];
  __shared__ float w2s[12];
  __shared__ float zp[2][128];
  __shared__ float zbuf[4 * 33];
  __shared__ float hl[32];
  const int t = threadIdx.x;
  const int ug = blockIdx.x >> 3;      // unit group: units u0..u0+7
  const int rg = blockIdx.x & 7;       // row group: rows r0..r0+3
  const int u0 = ug * 8, r0 = rg * 4;
  for (int i = 0; i < 3; ++i) {
    int b4 = (t >> 6) * 64 + 256 * i;
    GLOAD_LDS16(W1pb + (size_t)(t + 256 * i) * 4, W1s + (size_t)b4 * 4);
  }
  {
    int q4 = t >> 2, rl0 = t & 3;
    int b4 = (t >> 6) * 64;
    GLOAD_LDS16(hdp_in + (size_t)(q4 * 32 + r0 + rl0) * 4, hdT + (size_t)b4 * 4);
  }
  if (t < 12) w2s[t] = (t < 10) ? W2[t] : 0.f;
  __syncthreads();
  {
    const uint32_t* wsrc = Wdp + (size_t)ug * 8192;
    for (int i = 0; i < 8; ++i) {
      int b4 = (t >> 6) * 64 + 256 * i;
      GLOAD_LDS16(wsrc + (size_t)(t + 256 * i) * 4, Wsp + (size_t)b4 * 4);
    }
  }
  // ---- hw1 = hd @ W1[1024:1536, :10] for 4 rows; 64 k-parts ----
  {
    const int rl = t & 3, kp = t >> 2;
    const uint4* hd4 = (const uint4*)hdT;
    float acc[10] = {};
    {
      uint4 u4 = hd4[kp * 4 + rl];
      const uint32_t* w0 = &W1s[(4 * kp) * 12];
      const uint32_t* w1 = &W1s[(4 * kp + 1) * 12];
      const uint32_t* w2p = &W1s[(4 * kp + 2) * 12];
      const uint32_t* w3 = &W1s[(4 * kp + 3) * 12];
#pragma unroll
      for (int j = 0; j < 10; ++j) {
        acc[j] = dot2bf(u4.x, w0[j], acc[j]);
        acc[j] = dot2bf(u4.y, w1[j], acc[j]);
        acc[j] = dot2bf(u4.z, w2p[j], acc[j]);
        acc[j] = dot2bf(u4.w, w3[j], acc[j]);
      }
    }
#pragma unroll
    for (int j = 0; j < 10; ++j) ph[(kp * 4 + rl) * 12 + j] = acc[j];
  }
  __syncthreads();
  if (t < 40) {
    int rl = t / 10, j = t % 10;
    float s = 0.f;
#pragma unroll
    for (int p = 0; p < 64; ++p) s += ph[(p * 4 + rl) * 12 + j];
    hw1[rl * 12 + j] = s;
  }
  __syncthreads();
  // ---- scores (fast tanh), 4 rows x 64 tt = 1 per thread ----
  const float b2v = b2[0];
  {
    int rl = t >> 6, tt = t & 63;
    size_t m = (size_t)(r0 + rl) * 64 + tt;
    const float4* aw = (const float4*)(aw1 + m * 16);
    float4 q0 = aw[0], q1 = aw[1], q2 = aw[2];
    const float* hw = &hw1[rl * 12];
    float e = b2v;
    e += tanhf_fast(q0.x + hw[0]) * w2s[0];
    e += tanhf_fast(q0.y + hw[1]) * w2s[1];
    e += tanhf_fast(q0.z + hw[2]) * w2s[2];
    e += tanhf_fast(q0.w + hw[3]) * w2s[3];
    e += tanhf_fast(q1.x + hw[4]) * w2s[4];
    e += tanhf_fast(q1.y + hw[5]) * w2s[5];
    e += tanhf_fast(q1.z + hw[6]) * w2s[6];
    e += tanhf_fast(q1.w + hw[7]) * w2s[7];
    e += tanhf_fast(q2.x + hw[8]) * w2s[8];
    e += tanhf_fast(q2.y + hw[9]) * w2s[9];
    esc[rl * 65 + tt] = fmaxf(e, 0.f);
  }
  __syncthreads();
  if (t < 32) {
    int rl = t >> 3, part = t & 7;
    float m = -1e30f;
    for (int i = 0; i < 8; ++i) m = fmaxf(m, esc[rl * 65 + part * 8 + i]);
    pm[rl * 9 + part] = m;
  }
  __syncthreads();
  if (t < 4) {
    float m = pm[t * 9];
    for (int p = 1; p < 8; ++p) m = fmaxf(m, pm[t * 9 + p]);
    mrow[t] = m;
  }
  __syncthreads();
  if (t < 32) {
    int rl = t >> 3, part = t & 7;
    float m = mrow[rl];
    float s = 0.f;
    for (int i = 0; i < 8; ++i) s += __expf(esc[rl * 65 + part * 8 + i] - m);
    pm[rl * 9 + part] = s;
  }
  __syncthreads();
  if (t < 4) {
    float s = 0.f;
    for (int p = 0; p < 8; ++p) s += pm[t * 9 + p];
    srow[t] = __fdividef(1.f, s);
  }
  __syncthreads();
  if (t < 128) {
    int rl = t >> 5, q = t & 31;
    float m = mrow[rl], s = srow[rl];
    float v0 = __expf(esc[rl * 65 + 2 * q] - m) * s;
    float v1 = __expf(esc[rl * 65 + 2 * q + 1] - m) * s;
    escp[rl * 33 + q] = bpack(v0, v1);
  }
  __syncthreads();
  // ---- z = score@A'Tb + hd@Whd + bd (32 cols x 4 rows, K-split) ----
  {
    const int out = t & 127;
    const int ccB = out >> 2, rl = out & 3;
    const int kh = t >> 7;
    const int colg = (ccB >> 3) * 512 + u0 + (ccB & 7);
    float acc = 0.f;
    {
      const uint4* hd4 = (const uint4*)hdT;
      const uint4* wd4 = (const uint4*)Wsp;
#pragma unroll 8
      for (int q4 = kh * 32; q4 < kh * 32 + 32; ++q4) {
        uint4 ua = hd4[q4 * 4 + rl];
        uint4 ub = wd4[q4 * 32 + ccB];
        acc = dot2bf(ua.x, ub.x, acc);
        acc = dot2bf(ua.y, ub.y, acc);
        acc = dot2bf(ua.z, ub.z, acc);
        acc = dot2bf(ua.w, ub.w, acc);
      }
    }
    {
      const uint32_t* ap = ApTb + (size_t)colg * 1024 + (r0 + rl) * 32;
      const uint32_t* ep = &escp[rl * 33];
#pragma unroll
      for (int i8 = kh * 4; i8 < kh * 4 + 4; ++i8) {
        uint4 v = *(const uint4*)(ap + i8 * 4);
        acc = dot2bf(v.x, ep[4 * i8 + 0], acc);
        acc = dot2bf(v.y, ep[4 * i8 + 1], acc);
        acc = dot2bf(v.z, ep[4 * i8 + 2], acc);
        acc = dot2bf(v.w, ep[4 * i8 + 3], acc);
      }
    }
    zp[kh][out] = acc;
  }
  __syncthreads();
  if (t < 128) {
    int ccB = t >> 2, rl = t & 3;
    int colg = (ccB >> 3) * 512 + u0 + (ccB & 7);
    zbuf[rl * 33 + ccB] = zp[0][t] + zp[1][t] + bd[colg];
  }
  __syncthreads();
  if (t < 32) {
    int j = t >> 2, rr = t & 3;
    int u = u0 + j, rgl = r0 + rr;
    float zi = zbuf[rr * 33 + j];
    float zf = zbuf[rr * 33 + 8 + j];
    float zg = zbuf[rr * 33 + 16 + j];
    float zo = zbuf[rr * 33 + 24 + j];
    float cold = cd[u * 32 + rgl];
    float cn = sigm(zf) * cold + sigm(zi) * tanhf_fast(zg);
    float h = sigm(zo) * tanhf_fast(cn);
    cd[u * 32 + rgl] = cn;
    HsB[(size_t)(step * 32 + rgl) * 512 + u] = (ushort)bf1(h);
    hl[j * 4 + rr] = h;
  }
  __syncthreads();
  if (t < 16) {
    int p = t >> 2, rr = t & 3;
    hdp_out[ug * 128 + (r0 + rr) * 4 + p] =
        bpack(hl[(2 * p) * 4 + rr], hl[(2 * p + 1) * 4 + rr]);
  }
}

// =====================================================================
// K6: logits = HsB[2048,512] @ WoT^T + bo via MFMA bf16.
// m-tile offset moff lets the launch run in row-halves (L3 reuse).
// Epilogue emits per-(outrow, ntile) softmax partials (max, sumexp).
// =====================================================================
__global__ __launch_bounds__(256) void k6_logits_mfma(
    const ushort* __restrict__ HsB, const ushort* __restrict__ WoT,
    const float* __restrict__ bo, float* __restrict__ out,
    float2* __restrict__ pstats, int moff)
{
  __shared__ ushort As[128 * 64];
  __shared__ ushort Bs[128 * 64];
  const int t = threadIdx.x;
  const int lane = t & 63, w = t >> 6;
  const int wr = w >> 1, wc = w & 1;
  const int m0 = (blockIdx.y + moff) * 128, n0 = blockIdx.x * 128;
  const int lrow = lane >> 3, s = lane & 7;
  const int quad = lane >> 4, l15 = lane & 15;
  f32x4 acc[4][4] = {};
  for (int kc = 0; kc < 8; ++kc) {
    const int k0 = kc * 64;
    __syncthreads();
    for (int i = 0; i < 4; ++i) {
      int row = w * 32 + i * 8 + lrow;
      int k8 = s ^ (row & 7);
      GLOAD_LDS16(HsB + (size_t)(m0 + row) * 512 + k0 + k8 * 8,
                  As + (w * 32 + i * 8) * 64);
      GLOAD_LDS16(WoT + (size_t)(n0 + row) * 512 + k0 + k8 * 8,
                  Bs + (w * 32 + i * 8) * 64);
    }
    __syncthreads();
#pragma unroll
    for (int ks = 0; ks < 2; ++ks) {
      bf16x8 af[4], bfr[4];
      int kq = ks * 4 + quad;
#pragma unroll
      for (int mi = 0; mi < 4; ++mi) {
        int row = wr * 64 + mi * 16 + l15;
        int slot = kq ^ (row & 7);
        af[mi] = *(const bf16x8*)(As + row * 64 + slot * 8);
      }
#pragma unroll
      for (int ni = 0; ni < 4; ++ni) {
        int row = wc * 64 + ni * 16 + l15;
        int slot = kq ^ (row & 7);
        bfr[ni] = *(const bf16x8*)(Bs + row * 64 + slot * 8);
      }
#pragma unroll
      for (int mi = 0; mi < 4; ++mi)
#pragma unroll
        for (int ni = 0; ni < 4; ++ni)
          acc[mi][ni] = __builtin_amdgcn_mfma_f32_16x16x32_bf16(
              af[mi], bfr[ni], acc[mi][ni], 0, 0, 0);
    }
  }
  __syncthreads();                    // As/Bs dead; reuse as partial arrays
  float* pmx = (float*)As;            // [128 rows][32 slots]
  float* psm = (float*)Bs;
#pragma unroll
  for (int mi = 0; mi < 4; ++mi) {
    int mbase = m0 + wr * 64 + mi * 16 + quad * 4;
#pragma unroll
    for (int reg = 0; reg < 4; ++reg) {
      int m = mbase + reg;
      int rowl = (m - m0);
      size_t rowbase = ((size_t)(m & 31) * 64 + (m >> 5)) * 32000;
      float vs[4];
      float mx = -1e30f;
#pragma unroll
      for (int ni = 0; ni < 4; ++ni) {
        int n = n0 + wc * 64 + ni * 16 + l15;
        float v = acc[mi][ni][reg] + bo[n];
        out[rowbase + n] = v;
        vs[ni] = v;
        mx = fmaxf(mx, v);
      }
      float sl = __expf(vs[0] - mx) + __expf(vs[1] - mx) +
                 __expf(vs[2] - mx) + __expf(vs[3] - mx);
      pmx[rowl * 32 + wc * 16 + l15] = mx;
      psm[rowl * 32 + wc * 16 + l15] = sl;
    }
  }
  __syncthreads();
  if (t < 128) {
    float m = pmx[t * 32], sacc = psm[t * 32];
    for (int i = 1; i < 32; ++i) {
      float m2 = pmx[t * 32 + i], s2 = psm[t * 32 + i];
      float mn = fmaxf(m, m2);
      sacc = sacc * __expf(m - mn) + s2 * __expf(m2 - mn);
      m = mn;
    }
    int mg = m0 + t;
    int outrow = (mg & 31) * 64 + (mg >> 5);
    pstats[(size_t)outrow * 256 + blockIdx.x] = make_float2(m, sacc);
  }
}

// =====================================================================
// K7: row softmax normalize for one m-half (1024 rows), using pstats.
// =====================================================================
__global__ __launch_bounds__(256) void k7_softmax(
    float* __restrict__ out, const float2* __restrict__ pstats, int half)
{
  __shared__ float mred[256], sred[256];
  const int t = threadIdx.x;
  const int mg = half * 1024 + blockIdx.x;
  const int row = (mg & 31) * 64 + (mg >> 5);
  float m = -1e30f, s = 0.f;
  if (t < 250) {
    float2 p = pstats[(size_t)row * 256 + t];
    m = p.x;
    s = p.y;
  }
  mred[t] = m;
  sred[t] = s;
  __syncthreads();
  for (int st = 128; st > 0; st >>= 1) {
    if (t < st) {
      float m1 = mred[t], m2 = mred[t + st];
      float mn = fmaxf(m1, m2);
      sred[t] = sred[t] * __expf(m1 - mn) + sred[t + st] * __expf(m2 - mn);
      mred[t] = mn;
    }
    __syncthreads();
  }
  m = mred[0];
  const float inv = 1.f / sred[0];
  float* p = out + (size_t)row * 32000;
  for (int i = t; i < 8000; i += 256) {
    float4 v = *(const float4*)(p + i * 4);
    v.x = __expf(v.x - m) * inv;
    v.y = __expf(v.y - m) * inv;
    v.z = __expf(v.z - m) * inv;
    v.w = __expf(v.w - m) * inv;
    *(float4*)(p + i * 4) = v;
  }
}

// =====================================================================
extern "C" void kernel_launch(void* const* d_in, const int* in_sizes, int n_in,
                              void* d_out, int out_size, void* d_ws, size_t ws_size,
                              hipStream_t stream)
{
  const int* x = (const int*)d_in[0];
  const float* emb = (const float*)d_in[1];
  const float* Wxf = (const float*)d_in[2];
  const float* Whf = (const float*)d_in[3];
  const float* bfv = (const float*)d_in[4];
  const float* Wxb = (const float*)d_in[5];
  const float* Whb = (const float*)d_in[6];
  const float* bbv = (const float*)d_in[7];
  const float* W1 = (const float*)d_in[8];
  const float* b1 = (const float*)d_in[9];
  const float* W2 = (const float*)d_in[10];
  const float* b2 = (const float*)d_in[11];
  const float* Wxd = (const float*)d_in[12];
  const float* Whd = (const float*)d_in[13];
  const float* bd = (const float*)d_in[14];
  const float* Wo = (const float*)d_in[15];
  const float* bo = (const float*)d_in[16];

  float* ws = (float*)d_ws;
  // layout (float offsets)
  float* c_f = ws + 0;
  float* c_b = ws + 16384;
  float* c_d = ws + 32768;
  uint32_t* hfp0 = (uint32_t*)(ws + 49152);   // 32KB: [32 r][512 u] bf16 swz
  uint32_t* hfp1 = hfp0 + 8192;
  uint32_t* hbp0 = (uint32_t*)(ws + 65536);
  uint32_t* hbp1 = hbp0 + 8192;
  uint32_t* hdp0 = (uint32_t*)(ws + 81920);
  uint32_t* hdp1 = hdp0 + 8192;
  uint32_t* W1pbAll = (uint32_t*)(ws + 98304);     // 9216 u32 (paired full W1)
  uint32_t* Wencp = (uint32_t*)(ws + 114688);      // 1,048,576 u32 (4 MB)
  uint32_t* Wdp = (uint32_t*)(ws + 1163264);       // 524,288 u32 (Whd slabs)
  ushort* aB = (ushort*)(ws + 1687552);            // 2048x1024 bf16
  float* aw1 = ws + 2742272;                       // 32768
  float* Xf = ws + 2775040;                        // 2048x2048 fp32 [token][col]
  float* Xb = Xf + 4194304;                        // 2048x2048 fp32
  ushort* WxfT = (ushort*)(ws + 11163648);         // 2048x256 bf16 (old 'a' gap)
  ushort* WxbT = (ushort*)(ws + 11425792);         // 2048x256 bf16
  ushort* HsB = (ushort*)(ws + 13260800);          // 2048*512 bf16
  // post-encoder overlays:
  uint32_t* ApTb = (uint32_t*)Xf;                  // 2048x1024 u32 bf16-pairs
  ushort* WxdT = (ushort*)Xb;                      // 2048x1024 bf16
  ushort* WoT = (ushort*)Xf;                       // overlays after decoder
  float2* pstats = (float2*)Wencp;                 // 2048x256 float2 (dead Wencp)

  // zero recurrent states (c_f, c_b, c_d, packed h buffers)
  hipMemsetAsync(ws, 0, 98304 * sizeof(float), stream);

  k0_pack<<<6180, 256, 0, stream>>>(Whf, Whb, Wencp, Whd, Wdp, W1, W1pbAll);
  k_wT<<<dim3(32, 4), 256, 0, stream>>>(Wxf, WxfT, 256, 2048);
  k_wT<<<dim3(32, 4), 256, 0, stream>>>(Wxb, WxbT, 256, 2048);

  k1_embed_mfma<<<dim3(32, 16), 256, 0, stream>>>(x, emb, WxfT, WxbT,
                                                  bfv, bbv, Xf, Xb);

  for (int s = 0; s < 64; ++s) {
    const uint32_t* hfi = (s & 1) ? hfp1 : hfp0;
    uint32_t* hfo = (s & 1) ? hfp0 : hfp1;
    const uint32_t* hbi = (s & 1) ? hbp1 : hbp0;
    uint32_t* hbo = (s & 1) ? hbp0 : hbp1;
    k2_enc_step<<<512, 256, 0, stream>>>(Xf, Xb, Wencp, hfi, hfo, hbi, hbo,
                                         c_f, c_b, aB, s);
  }

  k5_aw1<<<256, 256, 0, stream>>>(aB, W1pbAll, b1, aw1);
  k_wT<<<dim3(32, 16), 256, 0, stream>>>(Wxd, WxdT, 1024, 2048);
  kA_aprime<<<dim3(16, 16), 256, 0, stream>>>(WxdT, aB, ApTb);

  for (int s = 0; s < 64; ++s) {
    const uint32_t* hdi = (s & 1) ? hdp1 : hdp0;
    uint32_t* hdo = (s & 1) ? hdp0 : hdp1;
    k4_dec_step<<<512, 256, 0, stream>>>(ApTb, aw1, W1pbAll + 6144, W2, b2,
                                         hdi, Wdp, bd, hdo, c_d, HsB, s);
  }

  k_wT<<<dim3(500, 8), 256, 0, stream>>>(Wo, WoT, 512, 32000);
  // row-half split: each half's 131 MB of logits stays L3-resident
  // between its k6 (producer) and k7 (normalize) launches.
  k6_logits_mfma<<<dim3(250, 8), 256, 0, stream>>>(HsB, WoT, bo,
                                                   (float*)d_out, pstats, 0);
  k7_softmax<<<1024, 256, 0, stream>>>((float*)d_out, pstats, 0);
  k6_logits_mfma<<<dim3(250, 8), 256, 0, stream>>>(HsB, WoT, bo,
                                                   (float*)d_out, pstats, 8);
  k7_softmax<<<1024, 256, 0, stream>>>((float*)d_out, pstats, 1);
}

// Round 14
// 1456.769 us; speedup vs baseline: 1.1374x; 1.0154x over previous
//
#include <hip/hip_runtime.h>
#include <hip/hip_bf16.h>
#include <cstdint>

typedef float f32x4 __attribute__((ext_vector_type(4)));
typedef __bf16 bf16x8 __attribute__((ext_vector_type(8)));

// ---------- bf16 pack helpers (RNE) ----------
__device__ __forceinline__ uint32_t bf1(float x) {
  uint32_t u = __float_as_uint(x);
  return (u + 0x7fffu + ((u >> 16) & 1u)) >> 16;
}
__device__ __forceinline__ uint32_t bpack(float lo, float hi) {
  return bf1(lo) | (bf1(hi) << 16);
}
__device__ __forceinline__ float blo(uint32_t u) { return __uint_as_float(u << 16); }
__device__ __forceinline__ float bhi(uint32_t u) { return __uint_as_float(u & 0xffff0000u); }
__device__ __forceinline__ float sigm(float x) {
  return __fdividef(1.f, 1.f + exp2f(x * -1.4426950408889634f));
}
__device__ __forceinline__ float tanhf_fast(float x) {
  float e2 = exp2f(x * 2.8853900817779268f);
  return 1.f - __fdividef(2.f, e2 + 1.f);
}

// packed-bf16 dot2: acc += a.lo*b.lo + a.hi*b.hi (fp32 accumulate)
__device__ __forceinline__ float dot2bf(uint32_t a, uint32_t b, float acc) {
  asm("v_dot2_f32_bf16 %0, %1, %2, %0" : "+v"(acc) : "v"(a), "v"(b));
  return acc;
}

#define GLOAD_LDS16(g, l)                                                     \
  __builtin_amdgcn_global_load_lds(                                           \
      (const __attribute__((address_space(1))) void*)(g),                     \
      (__attribute__((address_space(3))) void*)(l), 16, 0, 0)
#define GLOAD_LDS4(g, l)                                                      \
  __builtin_amdgcn_global_load_lds(                                           \
      (const __attribute__((address_space(1))) void*)(g),                     \
      (__attribute__((address_space(3))) void*)(l), 4, 0, 0)

// =====================================================================
// K0: all weight packing in one launch.
// bid<4096: Whf/Whb -> MFMA-k2 layout: [dir][cg=128][c=16][512 k] bf16
//   (u32 view; slot XOR-swizzled: pos = p ^ ((c&7)<<2))
// bid<6144: Whd -> [ug=64][64 q4][32 cc][4 e], col=(cc>>3)*512+ug*8+(cc&7)
// else:     W1[0:1536,:10] bf16-paired -> [768 q][12 j]
// =====================================================================
__global__ __launch_bounds__(256) void k0_pack(
    const float* __restrict__ Whf, const float* __restrict__ Whb,
    uint32_t* __restrict__ Wencp, const float* __restrict__ Whd,
    uint32_t* __restrict__ Wdp, const float* __restrict__ W1,
    uint32_t* __restrict__ W1pbAll)
{
  int bid = blockIdx.x;
  if (bid < 4096) {
    int p = bid * 256 + threadIdx.x;             // 0..2^20-1
    int j2 = p & 3, slot = (p >> 2) & 63, c = (p >> 8) & 15;
    int cg = (p >> 12) & 127, dir = p >> 19;
    int k = slot * 8 + j2 * 2;
    const float* W = dir ? Whb : Whf;
    int colg = (c >> 2) * 512 + cg * 4 + (c & 3);
    Wencp[p ^ ((c & 7) << 2)] =
        bpack(W[(size_t)k * 2048 + colg], W[(size_t)(k + 1) * 2048 + colg]);
  } else if (bid < 6144) {
    int p = (bid - 4096) * 256 + threadIdx.x;    // 0..524287
    int e = p & 3, cc = (p >> 2) & 31, q4 = (p >> 7) & 63, ug = p >> 13;
    int k2 = 4 * q4 + e;
    int col = (cc >> 3) * 512 + ug * 8 + (cc & 7);
    int k = 2 * k2;
    Wdp[p] = bpack(Whd[(size_t)k * 2048 + col], Whd[(size_t)(k + 1) * 2048 + col]);
  } else {
    int p = (bid - 6144) * 256 + threadIdx.x;    // 0..9215
    if (p < 9216) {
      int q = p / 12, j = p % 12;
      float v0 = (j < 10) ? W1[(size_t)(2 * q) * 10 + j] : 0.f;
      float v1 = (j < 10) ? W1[(size_t)(2 * q + 1) * 10 + j] : 0.f;
      W1pbAll[p] = bpack(v0, v1);
    }
  }
}

// =====================================================================
// K_wT: generic transpose-pack: src[K][N] fp32 -> dst[N][K] bf16.
// grid (N/64, K/64).
// =====================================================================
__global__ __launch_bounds__(256) void k_wT(
    const float* __restrict__ src, ushort* __restrict__ dst, int K, int N)
{
  __shared__ float tile[64 * 65];
  const int t = threadIdx.x;
  const int n0 = blockIdx.x * 64, k0 = blockIdx.y * 64;
  for (int i = 0; i < 16; ++i) {
    int p = t + 256 * i;
    int kk = p >> 6, nn = p & 63;
    tile[kk * 65 + nn] = src[(size_t)(k0 + kk) * N + n0 + nn];
  }
  __syncthreads();
  for (int i = 0; i < 4; ++i) {
    int p = t + 256 * i;
    int nn = p >> 4, k4 = (p & 15) * 4;
    ushort4 o;
    o.x = (ushort)bf1(tile[(k4 + 0) * 65 + nn]);
    o.y = (ushort)bf1(tile[(k4 + 1) * 65 + nn]);
    o.z = (ushort)bf1(tile[(k4 + 2) * 65 + nn]);
    o.w = (ushort)bf1(tile[(k4 + 3) * 65 + nn]);
    *(ushort4*)(dst + (size_t)(n0 + nn) * K + k0 + k4) = o;
  }
}

// =====================================================================
// K1: X = gather(emb,x) @ Wx + b via MFMA bf16.
// grid (32 n-tiles, 16 m-tiles), 4 waves each own 32 C-rows x 128 cols.
// =====================================================================
__global__ __launch_bounds__(256) void k1_embed_mfma(
    const int* __restrict__ x, const float* __restrict__ emb,
    const ushort* __restrict__ WxfT, const ushort* __restrict__ WxbT,
    const float* __restrict__ bfv, const float* __restrict__ bbv,
    float* __restrict__ Xf, float* __restrict__ Xb)
{
  __shared__ float Afp[128 * 64];      // 32 KB
  __shared__ ushort Bs[128 * 64];      // 16 KB
  __shared__ int xid[128];
  const int t = threadIdx.x;
  const int n0g = blockIdx.x * 128;
  const int m0 = blockIdx.y * 128;
  const int isB = (n0g >= 2048);
  const int n0 = n0g & 2047;
  const ushort* WT = isB ? WxbT : WxfT;
  const float* bias = isB ? bbv : bfv;
  if (t < 128) xid[t] = x[m0 + t];
  __syncthreads();
  int xr[8];
#pragma unroll
  for (int i = 0; i < 8; ++i) xr[i] = xid[(t >> 4) + 16 * i];
  const int lane = t & 63, w = t >> 6;
  const int quad = lane >> 4, l15 = lane & 15;
  f32x4 acc[2][8] = {};
  for (int kc = 0; kc < 4; ++kc) {
    const int k0 = kc * 64;
    __syncthreads();
    for (int i = 0; i < 8; ++i) {
      int idx = t + 256 * i;
      int row = (t >> 4) + 16 * i, ch = idx & 15;
      int gr = (ch >> 1) ^ (row & 7), w16 = ch & 1;
      GLOAD_LDS16(emb + (size_t)xr[i] * 256 + k0 + gr * 8 + w16 * 4,
                  Afp + idx * 4);
    }
    for (int i = 0; i < 4; ++i) {
      int idx = t + 256 * i;
      int row = idx >> 3, s8 = (idx & 7) ^ (row & 7);
      GLOAD_LDS16(WT + (size_t)(n0 + row) * 256 + k0 + s8 * 8,
                  Bs + idx * 8);
    }
    __syncthreads();
#pragma unroll
    for (int ks = 0; ks < 2; ++ks) {
      int kq = ks * 4 + quad;
      bf16x8 af[2];
#pragma unroll
      for (int mi = 0; mi < 2; ++mi) {
        int row = w * 32 + mi * 16 + l15;
        int slot = kq ^ (row & 7);
        const float* ap = Afp + row * 64 + slot * 8;
        float4 a0 = *(const float4*)ap;
        float4 a1 = *(const float4*)(ap + 4);
        union { ushort u[8]; bf16x8 v; } cv;
        cv.u[0] = (ushort)bf1(a0.x); cv.u[1] = (ushort)bf1(a0.y);
        cv.u[2] = (ushort)bf1(a0.z); cv.u[3] = (ushort)bf1(a0.w);
        cv.u[4] = (ushort)bf1(a1.x); cv.u[5] = (ushort)bf1(a1.y);
        cv.u[6] = (ushort)bf1(a1.z); cv.u[7] = (ushort)bf1(a1.w);
        af[mi] = cv.v;
      }
#pragma unroll
      for (int ni = 0; ni < 8; ++ni) {
        int rowB = ni * 16 + l15;
        int slotB = kq ^ (rowB & 7);
        bf16x8 bfr = *(const bf16x8*)(Bs + rowB * 64 + slotB * 8);
#pragma unroll
        for (int mi = 0; mi < 2; ++mi)
          acc[mi][ni] = __builtin_amdgcn_mfma_f32_16x16x32_bf16(
              af[mi], bfr, acc[mi][ni], 0, 0, 0);
      }
    }
  }
  float* Xout = isB ? Xb : Xf;
  float bcol[8];
#pragma unroll
  for (int ni = 0; ni < 8; ++ni) bcol[ni] = bias[n0 + ni * 16 + l15];
#pragma unroll
  for (int mi = 0; mi < 2; ++mi) {
#pragma unroll
    for (int reg = 0; reg < 4; ++reg) {
      int token = m0 + w * 32 + mi * 16 + quad * 4 + reg;
#pragma unroll
      for (int ni = 0; ni < 8; ++ni) {
        int col = n0 + ni * 16 + l15;
        Xout[(size_t)token * 2048 + col] = acc[mi][ni][reg] + bcol[ni];
      }
    }
  }
}

// =====================================================================
// K2: one encoder step both dirs via MFMA bf16.
// 512 blocks = 2 dir x 2 row-halves x 128 col-groups (16 gate-cols each).
// zx staged via global_load_lds(4) (per-lane src, wave-linear dest).
// =====================================================================
__global__ __launch_bounds__(256) void k2_enc_step(
    const float* __restrict__ Xf, const float* __restrict__ Xb,
    const uint32_t* __restrict__ Wencp,
    const uint32_t* __restrict__ hfi, uint32_t* __restrict__ hfo,
    const uint32_t* __restrict__ hbi, uint32_t* __restrict__ hbo,
    float* __restrict__ cf, float* __restrict__ cb,
    ushort* __restrict__ aB, int step)
{
  __shared__ ushort Hs[16 * 512];      // 16 KB, rows r0..r0+15 (swizzled)
  __shared__ ushort Ws[16 * 512];      // 16 KB, 16 cols (swizzled)
  __shared__ float zp[4 * 256];        // wave partials
  __shared__ float zx[256];
  __shared__ float zbuf[256];
  __shared__ float hl[64];
  const int t = threadIdx.x;
  const int dir = blockIdx.x >> 8;
  const int rh = (blockIdx.x >> 7) & 1;
  const int cg = blockIdx.x & 127;
  const int r0 = rh * 16, u0 = cg * 4;
  const float* XF = dir ? Xb : Xf;
  const uint32_t* hin = dir ? hbi : hfi;
  uint32_t* hout = dir ? hbo : hfo;
  float* cst = dir ? cb : cf;
  const int ta = dir ? (63 - step) : step;

  {
    const uint32_t* hinu = hin + r0 * 256;       // 256 u32 per row
    for (int i = 0; i < 4; ++i) {
      int b4 = (t >> 6) * 64 + 256 * i;
      GLOAD_LDS16(hinu + (size_t)(t + 256 * i) * 4, (uint32_t*)Hs + b4 * 4);
    }
    const uint32_t* wsrc = Wencp + ((size_t)dir * 128 + cg) * 4096;
    for (int i = 0; i < 4; ++i) {
      int b4 = (t >> 6) * 64 + 256 * i;
      GLOAD_LDS16(wsrc + (size_t)(t + 256 * i) * 4, (uint32_t*)Ws + b4 * 4);
    }
  }
  {
    int cl = t & 15, rl = t >> 4;
    int colg = (cl >> 2) * 512 + u0 + (cl & 3);
    GLOAD_LDS4(XF + (size_t)((r0 + rl) * 64 + ta) * 2048 + colg,
               zx + (t >> 6) * 64);
  }
  __syncthreads();
  const int lane = t & 63, w = t >> 6;
  const int quad = lane >> 4, l15 = lane & 15;
  f32x4 acc = {};
#pragma unroll
  for (int mm = 0; mm < 4; ++mm) {
    int m = w * 4 + mm;                          // K-chunk m*32..m*32+31
    int slot = m * 4 + quad;
    bf16x8 a = *(const bf16x8*)(Hs + l15 * 512 + (slot ^ (l15 & 7)) * 8);
    bf16x8 b = *(const bf16x8*)(Ws + l15 * 512 + (slot ^ (l15 & 7)) * 8);
    acc = __builtin_amdgcn_mfma_f32_16x16x32_bf16(a, b, acc, 0, 0, 0);
  }
#pragma unroll
  for (int reg = 0; reg < 4; ++reg)
    zp[w * 256 + (quad * 4 + reg) * 16 + l15] = acc[reg];
  __syncthreads();
  zbuf[t] = zp[t] + zp[256 + t] + zp[512 + t] + zp[768 + t] + zx[t];
  __syncthreads();
  if (t < 64) {
    int rl = t & 15, ui = t >> 4;
    int u = u0 + ui, r = r0 + rl;
    float zi = zbuf[rl * 16 + ui];
    float zf = zbuf[rl * 16 + 4 + ui];
    float zg = zbuf[rl * 16 + 8 + ui];
    float zo = zbuf[rl * 16 + 12 + ui];
    float cold = cst[u * 32 + r];
    float cn = sigm(zf) * cold + sigm(zi) * tanhf_fast(zg);
    float h = sigm(zo) * tanhf_fast(cn);
    cst[u * 32 + r] = cn;
    aB[((size_t)r * 64 + ta) * 1024 + dir * 512 + u] = (ushort)bf1(h);
    hl[rl * 4 + ui] = h;
  }
  __syncthreads();
  if (t < 16) {
    int r = r0 + t;
    uint32_t lo = bpack(hl[t * 4 + 0], hl[t * 4 + 1]);
    uint32_t hi = bpack(hl[t * 4 + 2], hl[t * 4 + 3]);
    uint32_t* dst = hout + r * 256 + (((cg >> 1) ^ (r & 7)) * 4) + (cg & 1) * 2;
    *(uint2*)dst = make_uint2(lo, hi);
  }
}

// =====================================================================
// K5: aw1[m][j] = aB[m]@W1[:1024,j] + b1[j] via dot2, padded to 16 cols.
// Launched with 2048 blocks (one row each; loop degenerates).
// =====================================================================
__global__ __launch_bounds__(256) void k5_aw1(
    const ushort* __restrict__ aB, const uint32_t* __restrict__ W1pbAll,
    const float* __restrict__ b1, float* __restrict__ aw1)
{
  __shared__ uint32_t ar[512];
  __shared__ float ps[16 * 17];
  const int t = threadIdx.x;
  const uint32_t* aBu = (const uint32_t*)aB;
  for (int m = blockIdx.x; m < 2048; m += gridDim.x) {
    __syncthreads();
    *(uint2*)(&ar[t * 2]) = *(const uint2*)(aBu + (size_t)m * 512 + t * 2);
    __syncthreads();
    int j = t & 15, part = t >> 4;
    int jj = j < 10 ? j : 0;
    float s = 0.f;
#pragma unroll 8
    for (int q = part * 32; q < part * 32 + 32; ++q)
      s = dot2bf(ar[q], W1pbAll[q * 12 + jj], s);
    ps[part * 17 + j] = s;
    __syncthreads();
    if (t < 16) {
      float sum = 0.f;
      if (t < 10) {
        for (int p = 0; p < 16; ++p) sum += ps[p * 17 + t];
        sum += b1[t];
      }
      aw1[m * 16 + t] = sum;
    }
  }
}

// =====================================================================
// KA: A'T = (a @ Wxd)^T via MFMA bf16, output PACKED bf16 pairs.
// =====================================================================
__global__ __launch_bounds__(256) void kA_aprime(
    const ushort* __restrict__ WxdT, const ushort* __restrict__ aB,
    uint32_t* __restrict__ ApTb)
{
  __shared__ ushort As[128 * 64];
  __shared__ ushort Bs[128 * 64];
  const int t = threadIdx.x;
  const int lane = t & 63, w = t >> 6;
  const int wr = w >> 1, wc = w & 1;
  const int m0 = blockIdx.y * 128, n0 = blockIdx.x * 128;
  const int lrow = lane >> 3, s = lane & 7;
  const int quad = lane >> 4, l15 = lane & 15;
  f32x4 acc[4][4] = {};
  for (int kc = 0; kc < 16; ++kc) {
    const int k0 = kc * 64;
    __syncthreads();
    for (int i = 0; i < 4; ++i) {
      int row = w * 32 + i * 8 + lrow;
      int k8 = s ^ (row & 7);
      GLOAD_LDS16(WxdT + (size_t)(m0 + row) * 1024 + k0 + k8 * 8,
                  As + (w * 32 + i * 8) * 64);
      GLOAD_LDS16(aB + (size_t)(n0 + row) * 1024 + k0 + k8 * 8,
                  Bs + (w * 32 + i * 8) * 64);
    }
    __syncthreads();
#pragma unroll
    for (int ks = 0; ks < 2; ++ks) {
      bf16x8 af[4], bfr[4];
      int kq = ks * 4 + quad;
#pragma unroll
      for (int mi = 0; mi < 4; ++mi) {
        int row = wr * 64 + mi * 16 + l15;
        int slot = kq ^ (row & 7);
        af[mi] = *(const bf16x8*)(As + row * 64 + slot * 8);
      }
#pragma unroll
      for (int ni = 0; ni < 4; ++ni) {
        int row = wc * 64 + ni * 16 + l15;
        int slot = kq ^ (row & 7);
        bfr[ni] = *(const bf16x8*)(Bs + row * 64 + slot * 8);
      }
#pragma unroll
      for (int mi = 0; mi < 4; ++mi)
#pragma unroll
        for (int ni = 0; ni < 4; ++ni)
          acc[mi][ni] = __builtin_amdgcn_mfma_f32_16x16x32_bf16(
              af[mi], bfr[ni], acc[mi][ni], 0, 0, 0);
    }
  }
#pragma unroll
  for (int mi = 0; mi < 4; ++mi) {
    int mbase = m0 + wr * 64 + mi * 16 + quad * 4;
#pragma unroll
    for (int reg = 0; reg < 4; ++reg) {
      int m = mbase + reg;
#pragma unroll
      for (int ni = 0; ni < 4; ++ni) {
        int n = n0 + wc * 64 + ni * 16 + l15;
        float v = acc[mi][ni][reg];
        float v2 = __shfl_xor(v, 1);
        if (!(l15 & 1))
          ApTb[(size_t)m * 1024 + (n >> 1)] = bpack(v, v2);
      }
    }
  }
}

// =====================================================================
// K4: FUSED decoder step, 512 blocks = 64 unit-groups x 8 row-groups
// (4 rows each). ~63 KB LDS -> 2 blocks/CU co-resident.
// =====================================================================
__global__ __launch_bounds__(256) void k4_dec_step(
    const uint32_t* __restrict__ ApTb, const float* __restrict__ aw1,
    const uint32_t* __restrict__ W1pb, const float* __restrict__ W2,
    const float* __restrict__ b2, const uint32_t* __restrict__ hdp_in,
    const uint32_t* __restrict__ Wdp, const float* __restrict__ bd,
    uint32_t* __restrict__ hdp_out, float* __restrict__ cd,
    ushort* __restrict__ HsB, int step)
{
  __shared__ uint32_t W1s[256 * 12];   // bf16-paired W1 rows (decoder half)
  __shared__ uint32_t hdT[1024];       // hd quads, 4-row slice [q4][4 r][4]
  __shared__ uint32_t Wsp[8192];       // Whd slab quads [q4][32 cc][4]
  __shared__ float ph[64 * 4 * 12];
  __shared__ float hw1[4 * 12];
  __shared__ float esc[4 * 65];
  __shared__ uint32_t escp[4 * 33];
  __shared__ float pm[4 * 9];
  __shared__ float mrow[4], srow[4];
  __shared__ float w2s[12];
  __shared__ float zp[2][128];
  __shared__ float zbuf[4 * 33];
  __shared__ float hl[32];
  const int t = threadIdx.x;
  const int ug = blockIdx.x >> 3;      // unit group: units u0..u0+7
  const int rg = blockIdx.x & 7;       // row group: rows r0..r0+3
  const int u0 = ug * 8, r0 = rg * 4;
  for (int i = 0; i < 3; ++i) {
    int b4 = (t >> 6) * 64 + 256 * i;
    GLOAD_LDS16(W1pb + (size_t)(t + 256 * i) * 4, W1s + (size_t)b4 * 4);
  }
  {
    int q4 = t >> 2, rl0 = t & 3;
    int b4 = (t >> 6) * 64;
    GLOAD_LDS16(hdp_in + (size_t)(q4 * 32 + r0 + rl0) * 4, hdT + (size_t)b4 * 4);
  }
  if (t < 12) w2s[t] = (t < 10) ? W2[t] : 0.f;
  __syncthreads();
  {
    const uint32_t* wsrc = Wdp + (size_t)ug * 8192;
    for (int i = 0; i < 8; ++i) {
      int b4 = (t >> 6) * 64 + 256 * i;
      GLOAD_LDS16(wsrc + (size_t)(t + 256 * i) * 4, Wsp + (size_t)b4 * 4);
    }
  }
  // ---- hw1 = hd @ W1[1024:1536, :10] for 4 rows; 64 k-parts ----
  {
    const int rl = t & 3, kp = t >> 2;
    const uint4* hd4 = (const uint4*)hdT;
    float acc[10] = {};
    {
      uint4 u4 = hd4[kp * 4 + rl];
      const uint32_t* w0 = &W1s[(4 * kp) * 12];
      const uint32_t* w1 = &W1s[(4 * kp + 1) * 12];
      const uint32_t* w2p = &W1s[(4 * kp + 2) * 12];
      const uint32_t* w3 = &W1s[(4 * kp + 3) * 12];
#pragma unroll
      for (int j = 0; j < 10; ++j) {
        acc[j] = dot2bf(u4.x, w0[j], acc[j]);
        acc[j] = dot2bf(u4.y, w1[j], acc[j]);
        acc[j] = dot2bf(u4.z, w2p[j], acc[j]);
        acc[j] = dot2bf(u4.w, w3[j], acc[j]);
      }
    }
#pragma unroll
    for (int j = 0; j < 10; ++j) ph[(kp * 4 + rl) * 12 + j] = acc[j];
  }
  __syncthreads();
  if (t < 40) {
    int rl = t / 10, j = t % 10;
    float s = 0.f;
#pragma unroll
    for (int p = 0; p < 64; ++p) s += ph[(p * 4 + rl) * 12 + j];
    hw1[rl * 12 + j] = s;
  }
  __syncthreads();
  // ---- scores (fast tanh), 4 rows x 64 tt = 1 per thread ----
  const float b2v = b2[0];
  {
    int rl = t >> 6, tt = t & 63;
    size_t m = (size_t)(r0 + rl) * 64 + tt;
    const float4* aw = (const float4*)(aw1 + m * 16);
    float4 q0 = aw[0], q1 = aw[1], q2 = aw[2];
    const float* hw = &hw1[rl * 12];
    float e = b2v;
    e += tanhf_fast(q0.x + hw[0]) * w2s[0];
    e += tanhf_fast(q0.y + hw[1]) * w2s[1];
    e += tanhf_fast(q0.z + hw[2]) * w2s[2];
    e += tanhf_fast(q0.w + hw[3]) * w2s[3];
    e += tanhf_fast(q1.x + hw[4]) * w2s[4];
    e += tanhf_fast(q1.y + hw[5]) * w2s[5];
    e += tanhf_fast(q1.z + hw[6]) * w2s[6];
    e += tanhf_fast(q1.w + hw[7]) * w2s[7];
    e += tanhf_fast(q2.x + hw[8]) * w2s[8];
    e += tanhf_fast(q2.y + hw[9]) * w2s[9];
    esc[rl * 65 + tt] = fmaxf(e, 0.f);
  }
  __syncthreads();
  if (t < 32) {
    int rl = t >> 3, part = t & 7;
    float m = -1e30f;
    for (int i = 0; i < 8; ++i) m = fmaxf(m, esc[rl * 65 + part * 8 + i]);
    pm[rl * 9 + part] = m;
  }
  __syncthreads();
  if (t < 4) {
    float m = pm[t * 9];
    for (int p = 1; p < 8; ++p) m = fmaxf(m, pm[t * 9 + p]);
    mrow[t] = m;
  }
  __syncthreads();
  if (t < 32) {
    int rl = t >> 3, part = t & 7;
    float m = mrow[rl];
    float s = 0.f;
    for (int i = 0; i < 8; ++i) s += __expf(esc[rl * 65 + part * 8 + i] - m);
    pm[rl * 9 + part] = s;
  }
  __syncthreads();
  if (t < 4) {
    float s = 0.f;
    for (int p = 0; p < 8; ++p) s += pm[t * 9 + p];
    srow[t] = __fdividef(1.f, s);
  }
  __syncthreads();
  if (t < 128) {
    int rl = t >> 5, q = t & 31;
    float m = mrow[rl], s = srow[rl];
    float v0 = __expf(esc[rl * 65 + 2 * q] - m) * s;
    float v1 = __expf(esc[rl * 65 + 2 * q + 1] - m) * s;
    escp[rl * 33 + q] = bpack(v0, v1);
  }
  __syncthreads();
  // ---- z = score@A'Tb + hd@Whd + bd (32 cols x 4 rows, K-split) ----
  {
    const int out = t & 127;
    const int ccB = out >> 2, rl = out & 3;
    const int kh = t >> 7;
    const int colg = (ccB >> 3) * 512 + u0 + (ccB & 7);
    float acc = 0.f;
    {
      const uint4* hd4 = (const uint4*)hdT;
      const uint4* wd4 = (const uint4*)Wsp;
#pragma unroll 8
      for (int q4 = kh * 32; q4 < kh * 32 + 32; ++q4) {
        uint4 ua = hd4[q4 * 4 + rl];
        uint4 ub = wd4[q4 * 32 + ccB];
        acc = dot2bf(ua.x, ub.x, acc);
        acc = dot2bf(ua.y, ub.y, acc);
        acc = dot2bf(ua.z, ub.z, acc);
        acc = dot2bf(ua.w, ub.w, acc);
      }
    }
    {
      const uint32_t* ap = ApTb + (size_t)colg * 1024 + (r0 + rl) * 32;
      const uint32_t* ep = &escp[rl * 33];
#pragma unroll
      for (int i8 = kh * 4; i8 < kh * 4 + 4; ++i8) {
        uint4 v = *(const uint4*)(ap + i8 * 4);
        acc = dot2bf(v.x, ep[4 * i8 + 0], acc);
        acc = dot2bf(v.y, ep[4 * i8 + 1], acc);
        acc = dot2bf(v.z, ep[4 * i8 + 2], acc);
        acc = dot2bf(v.w, ep[4 * i8 + 3], acc);
      }
    }
    zp[kh][out] = acc;
  }
  __syncthreads();
  if (t < 128) {
    int ccB = t >> 2, rl = t & 3;
    int colg = (ccB >> 3) * 512 + u0 + (ccB & 7);
    zbuf[rl * 33 + ccB] = zp[0][t] + zp[1][t] + bd[colg];
  }
  __syncthreads();
  if (t < 32) {
    int j = t >> 2, rr = t & 3;
    int u = u0 + j, rgl = r0 + rr;
    float zi = zbuf[rr * 33 + j];
    float zf = zbuf[rr * 33 + 8 + j];
    float zg = zbuf[rr * 33 + 16 + j];
    float zo = zbuf[rr * 33 + 24 + j];
    float cold = cd[u * 32 + rgl];
    float cn = sigm(zf) * cold + sigm(zi) * tanhf_fast(zg);
    float h = sigm(zo) * tanhf_fast(cn);
    cd[u * 32 + rgl] = cn;
    HsB[(size_t)(step * 32 + rgl) * 512 + u] = (ushort)bf1(h);
    hl[j * 4 + rr] = h;
  }
  __syncthreads();
  if (t < 16) {
    int p = t >> 2, rr = t & 3;
    hdp_out[ug * 128 + (r0 + rr) * 4 + p] =
        bpack(hl[(2 * p) * 4 + rr], hl[(2 * p + 1) * 4 + rr]);
  }
}

// =====================================================================
// K6: logits = HsB[2048,512] @ WoT^T + bo via MFMA bf16.
// m-tile offset moff lets the launch run in row-halves (L3 reuse).
// Epilogue emits per-(outrow, ntile) softmax partials (two-stage combine).
// =====================================================================
__global__ __launch_bounds__(256) void k6_logits_mfma(
    const ushort* __restrict__ HsB, const ushort* __restrict__ WoT,
    const float* __restrict__ bo, float* __restrict__ out,
    float2* __restrict__ pstats, int moff)
{
  __shared__ ushort As[128 * 64];
  __shared__ ushort Bs[128 * 64];
  __shared__ float pm2[256], sm2[256];
  const int t = threadIdx.x;
  const int lane = t & 63, w = t >> 6;
  const int wr = w >> 1, wc = w & 1;
  const int m0 = (blockIdx.y + moff) * 128, n0 = blockIdx.x * 128;
  const int lrow = lane >> 3, s = lane & 7;
  const int quad = lane >> 4, l15 = lane & 15;
  f32x4 acc[4][4] = {};
  for (int kc = 0; kc < 8; ++kc) {
    const int k0 = kc * 64;
    __syncthreads();
    for (int i = 0; i < 4; ++i) {
      int row = w * 32 + i * 8 + lrow;
      int k8 = s ^ (row & 7);
      GLOAD_LDS16(HsB + (size_t)(m0 + row) * 512 + k0 + k8 * 8,
                  As + (w * 32 + i * 8) * 64);
      GLOAD_LDS16(WoT + (size_t)(n0 + row) * 512 + k0 + k8 * 8,
                  Bs + (w * 32 + i * 8) * 64);
    }
    __syncthreads();
#pragma unroll
    for (int ks = 0; ks < 2; ++ks) {
      bf16x8 af[4], bfr[4];
      int kq = ks * 4 + quad;
#pragma unroll
      for (int mi = 0; mi < 4; ++mi) {
        int row = wr * 64 + mi * 16 + l15;
        int slot = kq ^ (row & 7);
        af[mi] = *(const bf16x8*)(As + row * 64 + slot * 8);
      }
#pragma unroll
      for (int ni = 0; ni < 4; ++ni) {
        int row = wc * 64 + ni * 16 + l15;
        int slot = kq ^ (row & 7);
        bfr[ni] = *(const bf16x8*)(Bs + row * 64 + slot * 8);
      }
#pragma unroll
      for (int mi = 0; mi < 4; ++mi)
#pragma unroll
        for (int ni = 0; ni < 4; ++ni)
          acc[mi][ni] = __builtin_amdgcn_mfma_f32_16x16x32_bf16(
              af[mi], bfr[ni], acc[mi][ni], 0, 0, 0);
    }
  }
  __syncthreads();                    // As/Bs dead; reuse as partial arrays
  float* pmx = (float*)As;            // [128 rows][32 slots]
  float* psm = (float*)Bs;
#pragma unroll
  for (int mi = 0; mi < 4; ++mi) {
    int mbase = m0 + wr * 64 + mi * 16 + quad * 4;
#pragma unroll
    for (int reg = 0; reg < 4; ++reg) {
      int m = mbase + reg;
      int rowl = (m - m0);
      size_t rowbase = ((size_t)(m & 31) * 64 + (m >> 5)) * 32000;
      float vs[4];
      float mx = -1e30f;
#pragma unroll
      for (int ni = 0; ni < 4; ++ni) {
        int n = n0 + wc * 64 + ni * 16 + l15;
        float v = acc[mi][ni][reg] + bo[n];
        out[rowbase + n] = v;
        vs[ni] = v;
        mx = fmaxf(mx, v);
      }
      float sl = __expf(vs[0] - mx) + __expf(vs[1] - mx) +
                 __expf(vs[2] - mx) + __expf(vs[3] - mx);
      pmx[rowl * 32 + wc * 16 + l15] = mx;
      psm[rowl * 32 + wc * 16 + l15] = sl;
    }
  }
  __syncthreads();
  // two-stage combine: 256 thr x 16 slots, then 128 thr x 2
  {
    int rowl = t >> 1, hh = (t & 1) * 16;
    float m = pmx[rowl * 32 + hh], sacc = psm[rowl * 32 + hh];
    for (int i = 1; i < 16; ++i) {
      float m2 = pmx[rowl * 32 + hh + i], s2 = psm[rowl * 32 + hh + i];
      float mn = fmaxf(m, m2);
      sacc = sacc * __expf(m - mn) + s2 * __expf(m2 - mn);
      m = mn;
    }
    pm2[t] = m;
    sm2[t] = sacc;
  }
  __syncthreads();
  if (t < 128) {
    float m1 = pm2[2 * t], m2 = pm2[2 * t + 1];
    float mn = fmaxf(m1, m2);
    float sacc = sm2[2 * t] * __expf(m1 - mn) + sm2[2 * t + 1] * __expf(m2 - mn);
    int mg = m0 + t;
    int outrow = (mg & 31) * 64 + (mg >> 5);
    pstats[(size_t)outrow * 256 + blockIdx.x] = make_float2(mn, sacc);
  }
}

// =====================================================================
// K7: row softmax normalize for one m-half (1024 rows), using pstats.
// =====================================================================
__global__ __launch_bounds__(256) void k7_softmax(
    float* __restrict__ out, const float2* __restrict__ pstats, int half)
{
  __shared__ float mred[256], sred[256];
  const int t = threadIdx.x;
  const int mg = half * 1024 + blockIdx.x;
  const int row = (mg & 31) * 64 + (mg >> 5);
  float m = -1e30f, s = 0.f;
  if (t < 250) {
    float2 p = pstats[(size_t)row * 256 + t];
    m = p.x;
    s = p.y;
  }
  mred[t] = m;
  sred[t] = s;
  __syncthreads();
  for (int st = 128; st > 0; st >>= 1) {
    if (t < st) {
      float m1 = mred[t], m2 = mred[t + st];
      float mn = fmaxf(m1, m2);
      sred[t] = sred[t] * __expf(m1 - mn) + sred[t + st] * __expf(m2 - mn);
      mred[t] = mn;
    }
    __syncthreads();
  }
  m = mred[0];
  const float inv = 1.f / sred[0];
  float* p = out + (size_t)row * 32000;
  for (int i = t; i < 8000; i += 256) {
    float4 v = *(const float4*)(p + i * 4);
    v.x = __expf(v.x - m) * inv;
    v.y = __expf(v.y - m) * inv;
    v.z = __expf(v.z - m) * inv;
    v.w = __expf(v.w - m) * inv;
    *(float4*)(p + i * 4) = v;
  }
}

// =====================================================================
extern "C" void kernel_launch(void* const* d_in, const int* in_sizes, int n_in,
                              void* d_out, int out_size, void* d_ws, size_t ws_size,
                              hipStream_t stream)
{
  const int* x = (const int*)d_in[0];
  const float* emb = (const float*)d_in[1];
  const float* Wxf = (const float*)d_in[2];
  const float* Whf = (const float*)d_in[3];
  const float* bfv = (const float*)d_in[4];
  const float* Wxb = (const float*)d_in[5];
  const float* Whb = (const float*)d_in[6];
  const float* bbv = (const float*)d_in[7];
  const float* W1 = (const float*)d_in[8];
  const float* b1 = (const float*)d_in[9];
  const float* W2 = (const float*)d_in[10];
  const float* b2 = (const float*)d_in[11];
  const float* Wxd = (const float*)d_in[12];
  const float* Whd = (const float*)d_in[13];
  const float* bd = (const float*)d_in[14];
  const float* Wo = (const float*)d_in[15];
  const float* bo = (const float*)d_in[16];

  float* ws = (float*)d_ws;
  // layout (float offsets)
  float* c_f = ws + 0;
  float* c_b = ws + 16384;
  float* c_d = ws + 32768;
  uint32_t* hfp0 = (uint32_t*)(ws + 49152);   // 32KB: [32 r][512 u] bf16 swz
  uint32_t* hfp1 = hfp0 + 8192;
  uint32_t* hbp0 = (uint32_t*)(ws + 65536);
  uint32_t* hbp1 = hbp0 + 8192;
  uint32_t* hdp0 = (uint32_t*)(ws + 81920);
  uint32_t* hdp1 = hdp0 + 8192;
  uint32_t* W1pbAll = (uint32_t*)(ws + 98304);     // 9216 u32 (paired full W1)
  uint32_t* Wencp = (uint32_t*)(ws + 114688);      // 1,048,576 u32 (4 MB)
  uint32_t* Wdp = (uint32_t*)(ws + 1163264);       // 524,288 u32 (Whd slabs)
  ushort* aB = (ushort*)(ws + 1687552);            // 2048x1024 bf16
  float* aw1 = ws + 2742272;                       // 32768
  float* Xf = ws + 2775040;                        // 2048x2048 fp32 [token][col]
  float* Xb = Xf + 4194304;                        // 2048x2048 fp32
  ushort* WxfT = (ushort*)(ws + 11163648);         // 2048x256 bf16
  ushort* WxbT = (ushort*)(ws + 11425792);         // 2048x256 bf16
  ushort* HsB = (ushort*)(ws + 13260800);          // 2048*512 bf16
  // post-encoder overlays:
  uint32_t* ApTb = (uint32_t*)Xf;                  // 2048x1024 u32 bf16-pairs
  ushort* WxdT = (ushort*)Xb;                      // 2048x1024 bf16
  ushort* WoT = (ushort*)Xf;                       // overlays after decoder
  float2* pstats = (float2*)Wencp;                 // 2048x256 float2 (dead Wencp)

  // zero recurrent states (c_f, c_b, c_d, packed h buffers)
  hipMemsetAsync(ws, 0, 98304 * sizeof(float), stream);

  k0_pack<<<6180, 256, 0, stream>>>(Whf, Whb, Wencp, Whd, Wdp, W1, W1pbAll);
  k_wT<<<dim3(32, 4), 256, 0, stream>>>(Wxf, WxfT, 256, 2048);
  k_wT<<<dim3(32, 4), 256, 0, stream>>>(Wxb, WxbT, 256, 2048);

  k1_embed_mfma<<<dim3(32, 16), 256, 0, stream>>>(x, emb, WxfT, WxbT,
                                                  bfv, bbv, Xf, Xb);

  for (int s = 0; s < 64; ++s) {
    const uint32_t* hfi = (s & 1) ? hfp1 : hfp0;
    uint32_t* hfo = (s & 1) ? hfp0 : hfp1;
    const uint32_t* hbi = (s & 1) ? hbp1 : hbp0;
    uint32_t* hbo = (s & 1) ? hbp0 : hbp1;
    k2_enc_step<<<512, 256, 0, stream>>>(Xf, Xb, Wencp, hfi, hfo, hbi, hbo,
                                         c_f, c_b, aB, s);
  }

  k5_aw1<<<2048, 256, 0, stream>>>(aB, W1pbAll, b1, aw1);
  k_wT<<<dim3(32, 16), 256, 0, stream>>>(Wxd, WxdT, 1024, 2048);
  kA_aprime<<<dim3(16, 16), 256, 0, stream>>>(WxdT, aB, ApTb);

  for (int s = 0; s < 64; ++s) {
    const uint32_t* hdi = (s & 1) ? hdp1 : hdp0;
    uint32_t* hdo = (s & 1) ? hdp0 : hdp1;
    k4_dec_step<<<512, 256, 0, stream>>>(ApTb, aw1, W1pbAll + 6144, W2, b2,
                                         hdi, Wdp, bd, hdo, c_d, HsB, s);
  }

  k_wT<<<dim3(500, 8), 256, 0, stream>>>(Wo, WoT, 512, 32000);
  // row-half split: each half's 131 MB of logits stays L3-resident
  // between its k6 (producer) and k7 (normalize) launches.
  k6_logits_mfma<<<dim3(250, 8), 256, 0, stream>>>(HsB, WoT, bo,
                                                   (float*)d_out, pstats, 0);
  k7_softmax<<<1024, 256, 0, stream>>>((float*)d_out, pstats, 0);
  k6_logits_mfma<<<dim3(250, 8), 256, 0, stream>>>(HsB, WoT, bo,
                                                   (float*)d_out, pstats, 8);
  k7_softmax<<<1024, 256, 0, stream>>>((float*)d_out, pstats, 1);
}

// Round 15
// 1445.693 us; speedup vs baseline: 1.1461x; 1.0077x over previous
//
#include <hip/hip_runtime.h>
#include <hip/hip_bf16.h>
#include <cstdint>

typedef float f32x4 __attribute__((ext_vector_type(4)));
typedef __bf16 bf16x8 __attribute__((ext_vector_type(8)));

// ---------- bf16 pack helpers (RNE) ----------
__device__ __forceinline__ uint32_t bf1(float x) {
  uint32_t u = __float_as_uint(x);
  return (u + 0x7fffu + ((u >> 16) & 1u)) >> 16;
}
__device__ __forceinline__ uint32_t bpack(float lo, float hi) {
  return bf1(lo) | (bf1(hi) << 16);
}
__device__ __forceinline__ float blo(uint32_t u) { return __uint_as_float(u << 16); }
__device__ __forceinline__ float bhi(uint32_t u) { return __uint_as_float(u & 0xffff0000u); }
__device__ __forceinline__ float sigm(float x) {
  return __fdividef(1.f, 1.f + exp2f(x * -1.4426950408889634f));
}
__device__ __forceinline__ float tanhf_fast(float x) {
  float e2 = exp2f(x * 2.8853900817779268f);
  return 1.f - __fdividef(2.f, e2 + 1.f);
}

// packed-bf16 dot2: acc += a.lo*b.lo + a.hi*b.hi (fp32 accumulate)
__device__ __forceinline__ float dot2bf(uint32_t a, uint32_t b, float acc) {
  asm("v_dot2_f32_bf16 %0, %1, %2, %0" : "+v"(acc) : "v"(a), "v"(b));
  return acc;
}

#define GLOAD_LDS16(g, l)                                                     \
  __builtin_amdgcn_global_load_lds(                                           \
      (const __attribute__((address_space(1))) void*)(g),                     \
      (__attribute__((address_space(3))) void*)(l), 16, 0, 0)
#define GLOAD_LDS4(g, l)                                                      \
  __builtin_amdgcn_global_load_lds(                                           \
      (const __attribute__((address_space(1))) void*)(g),                     \
      (__attribute__((address_space(3))) void*)(l), 4, 0, 0)

// =====================================================================
// K0: all weight packing in one launch.
// bid<4096: Whf/Whb -> MFMA-k2 layout: [dir][cg=128][c=16][512 k] bf16
//   (u32 view; slot XOR-swizzled: pos = p ^ ((c&7)<<2))
// bid<6144: Whd -> [ug=64][64 q4][32 cc][4 e], col=(cc>>3)*512+ug*8+(cc&7)
// else:     W1[0:1536,:10] bf16-paired -> [768 q][12 j]
// =====================================================================
__global__ __launch_bounds__(256) void k0_pack(
    const float* __restrict__ Whf, const float* __restrict__ Whb,
    uint32_t* __restrict__ Wencp, const float* __restrict__ Whd,
    uint32_t* __restrict__ Wdp, const float* __restrict__ W1,
    uint32_t* __restrict__ W1pbAll)
{
  int bid = blockIdx.x;
  if (bid < 4096) {
    int p = bid * 256 + threadIdx.x;             // 0..2^20-1
    int j2 = p & 3, slot = (p >> 2) & 63, c = (p >> 8) & 15;
    int cg = (p >> 12) & 127, dir = p >> 19;
    int k = slot * 8 + j2 * 2;
    const float* W = dir ? Whb : Whf;
    int colg = (c >> 2) * 512 + cg * 4 + (c & 3);
    Wencp[p ^ ((c & 7) << 2)] =
        bpack(W[(size_t)k * 2048 + colg], W[(size_t)(k + 1) * 2048 + colg]);
  } else if (bid < 6144) {
    int p = (bid - 4096) * 256 + threadIdx.x;    // 0..524287
    int e = p & 3, cc = (p >> 2) & 31, q4 = (p >> 7) & 63, ug = p >> 13;
    int k2 = 4 * q4 + e;
    int col = (cc >> 3) * 512 + ug * 8 + (cc & 7);
    int k = 2 * k2;
    Wdp[p] = bpack(Whd[(size_t)k * 2048 + col], Whd[(size_t)(k + 1) * 2048 + col]);
  } else {
    int p = (bid - 6144) * 256 + threadIdx.x;    // 0..9215
    if (p < 9216) {
      int q = p / 12, j = p % 12;
      float v0 = (j < 10) ? W1[(size_t)(2 * q) * 10 + j] : 0.f;
      float v1 = (j < 10) ? W1[(size_t)(2 * q + 1) * 10 + j] : 0.f;
      W1pbAll[p] = bpack(v0, v1);
    }
  }
}

// =====================================================================
// K_wT: generic transpose-pack: src[K][N] fp32 -> dst[N][K] bf16.
// grid (N/64, K/64).
// =====================================================================
__global__ __launch_bounds__(256) void k_wT(
    const float* __restrict__ src, ushort* __restrict__ dst, int K, int N)
{
  __shared__ float tile[64 * 65];
  const int t = threadIdx.x;
  const int n0 = blockIdx.x * 64, k0 = blockIdx.y * 64;
  for (int i = 0; i < 16; ++i) {
    int p = t + 256 * i;
    int kk = p >> 6, nn = p & 63;
    tile[kk * 65 + nn] = src[(size_t)(k0 + kk) * N + n0 + nn];
  }
  __syncthreads();
  for (int i = 0; i < 4; ++i) {
    int p = t + 256 * i;
    int nn = p >> 4, k4 = (p & 15) * 4;
    ushort4 o;
    o.x = (ushort)bf1(tile[(k4 + 0) * 65 + nn]);
    o.y = (ushort)bf1(tile[(k4 + 1) * 65 + nn]);
    o.z = (ushort)bf1(tile[(k4 + 2) * 65 + nn]);
    o.w = (ushort)bf1(tile[(k4 + 3) * 65 + nn]);
    *(ushort4*)(dst + (size_t)(n0 + nn) * K + k0 + k4) = o;
  }
}

// =====================================================================
// K_wTx: both Wxf and Wxb transposes in one launch (grid (32, 8)):
// blockIdx.y<4 -> Wxf tile, else Wxb tile. K=256, N=2048.
// =====================================================================
__global__ __launch_bounds__(256) void k_wTx(
    const float* __restrict__ Wxf, ushort* __restrict__ WxfT,
    const float* __restrict__ Wxb, ushort* __restrict__ WxbT)
{
  __shared__ float tile[64 * 65];
  const int t = threadIdx.x;
  const int ky = blockIdx.y;
  const float* src = (ky < 4) ? Wxf : Wxb;
  ushort* dst = (ky < 4) ? WxfT : WxbT;
  const int n0 = blockIdx.x * 64, k0 = (ky & 3) * 64;
  for (int i = 0; i < 16; ++i) {
    int p = t + 256 * i;
    int kk = p >> 6, nn = p & 63;
    tile[kk * 65 + nn] = src[(size_t)(k0 + kk) * 2048 + n0 + nn];
  }
  __syncthreads();
  for (int i = 0; i < 4; ++i) {
    int p = t + 256 * i;
    int nn = p >> 4, k4 = (p & 15) * 4;
    ushort4 o;
    o.x = (ushort)bf1(tile[(k4 + 0) * 65 + nn]);
    o.y = (ushort)bf1(tile[(k4 + 1) * 65 + nn]);
    o.z = (ushort)bf1(tile[(k4 + 2) * 65 + nn]);
    o.w = (ushort)bf1(tile[(k4 + 3) * 65 + nn]);
    *(ushort4*)(dst + (size_t)(n0 + nn) * 256 + k0 + k4) = o;
  }
}

// =====================================================================
// K1: X = gather(emb,x) @ Wx + b via MFMA bf16.
// grid (32 n-tiles, 16 m-tiles), 4 waves each own 32 C-rows x 128 cols.
// =====================================================================
__global__ __launch_bounds__(256) void k1_embed_mfma(
    const int* __restrict__ x, const float* __restrict__ emb,
    const ushort* __restrict__ WxfT, const ushort* __restrict__ WxbT,
    const float* __restrict__ bfv, const float* __restrict__ bbv,
    float* __restrict__ Xf, float* __restrict__ Xb)
{
  __shared__ float Afp[128 * 64];      // 32 KB
  __shared__ ushort Bs[128 * 64];      // 16 KB
  __shared__ int xid[128];
  const int t = threadIdx.x;
  const int n0g = blockIdx.x * 128;
  const int m0 = blockIdx.y * 128;
  const int isB = (n0g >= 2048);
  const int n0 = n0g & 2047;
  const ushort* WT = isB ? WxbT : WxfT;
  const float* bias = isB ? bbv : bfv;
  if (t < 128) xid[t] = x[m0 + t];
  __syncthreads();
  int xr[8];
#pragma unroll
  for (int i = 0; i < 8; ++i) xr[i] = xid[(t >> 4) + 16 * i];
  const int lane = t & 63, w = t >> 6;
  const int quad = lane >> 4, l15 = lane & 15;
  f32x4 acc[2][8] = {};
  for (int kc = 0; kc < 4; ++kc) {
    const int k0 = kc * 64;
    __syncthreads();
    for (int i = 0; i < 8; ++i) {
      int idx = t + 256 * i;
      int row = (t >> 4) + 16 * i, ch = idx & 15;
      int gr = (ch >> 1) ^ (row & 7), w16 = ch & 1;
      GLOAD_LDS16(emb + (size_t)xr[i] * 256 + k0 + gr * 8 + w16 * 4,
                  Afp + idx * 4);
    }
    for (int i = 0; i < 4; ++i) {
      int idx = t + 256 * i;
      int row = idx >> 3, s8 = (idx & 7) ^ (row & 7);
      GLOAD_LDS16(WT + (size_t)(n0 + row) * 256 + k0 + s8 * 8,
                  Bs + idx * 8);
    }
    __syncthreads();
#pragma unroll
    for (int ks = 0; ks < 2; ++ks) {
      int kq = ks * 4 + quad;
      bf16x8 af[2];
#pragma unroll
      for (int mi = 0; mi < 2; ++mi) {
        int row = w * 32 + mi * 16 + l15;
        int slot = kq ^ (row & 7);
        const float* ap = Afp + row * 64 + slot * 8;
        float4 a0 = *(const float4*)ap;
        float4 a1 = *(const float4*)(ap + 4);
        union { ushort u[8]; bf16x8 v; } cv;
        cv.u[0] = (ushort)bf1(a0.x); cv.u[1] = (ushort)bf1(a0.y);
        cv.u[2] = (ushort)bf1(a0.z); cv.u[3] = (ushort)bf1(a0.w);
        cv.u[4] = (ushort)bf1(a1.x); cv.u[5] = (ushort)bf1(a1.y);
        cv.u[6] = (ushort)bf1(a1.z); cv.u[7] = (ushort)bf1(a1.w);
        af[mi] = cv.v;
      }
#pragma unroll
      for (int ni = 0; ni < 8; ++ni) {
        int rowB = ni * 16 + l15;
        int slotB = kq ^ (rowB & 7);
        bf16x8 bfr = *(const bf16x8*)(Bs + rowB * 64 + slotB * 8);
#pragma unroll
        for (int mi = 0; mi < 2; ++mi)
          acc[mi][ni] = __builtin_amdgcn_mfma_f32_16x16x32_bf16(
              af[mi], bfr, acc[mi][ni], 0, 0, 0);
      }
    }
  }
  float* Xout = isB ? Xb : Xf;
  float bcol[8];
#pragma unroll
  for (int ni = 0; ni < 8; ++ni) bcol[ni] = bias[n0 + ni * 16 + l15];
#pragma unroll
  for (int mi = 0; mi < 2; ++mi) {
#pragma unroll
    for (int reg = 0; reg < 4; ++reg) {
      int token = m0 + w * 32 + mi * 16 + quad * 4 + reg;
#pragma unroll
      for (int ni = 0; ni < 8; ++ni) {
        int col = n0 + ni * 16 + l15;
        Xout[(size_t)token * 2048 + col] = acc[mi][ni][reg] + bcol[ni];
      }
    }
  }
}

// =====================================================================
// K2: one encoder step both dirs via MFMA bf16.
// 512 blocks = 2 dir x 2 row-halves x 128 col-groups (16 gate-cols each).
// =====================================================================
__global__ __launch_bounds__(256) void k2_enc_step(
    const float* __restrict__ Xf, const float* __restrict__ Xb,
    const uint32_t* __restrict__ Wencp,
    const uint32_t* __restrict__ hfi, uint32_t* __restrict__ hfo,
    const uint32_t* __restrict__ hbi, uint32_t* __restrict__ hbo,
    float* __restrict__ cf, float* __restrict__ cb,
    ushort* __restrict__ aB, int step)
{
  __shared__ ushort Hs[16 * 512];      // 16 KB, rows r0..r0+15 (swizzled)
  __shared__ ushort Ws[16 * 512];      // 16 KB, 16 cols (swizzled)
  __shared__ float zp[4 * 256];        // wave partials
  __shared__ float zx[256];
  __shared__ float zbuf[256];
  __shared__ float hl[64];
  const int t = threadIdx.x;
  const int dir = blockIdx.x >> 8;
  const int rh = (blockIdx.x >> 7) & 1;
  const int cg = blockIdx.x & 127;
  const int r0 = rh * 16, u0 = cg * 4;
  const float* XF = dir ? Xb : Xf;
  const uint32_t* hin = dir ? hbi : hfi;
  uint32_t* hout = dir ? hbo : hfo;
  float* cst = dir ? cb : cf;
  const int ta = dir ? (63 - step) : step;

  {
    const uint32_t* hinu = hin + r0 * 256;       // 256 u32 per row
    for (int i = 0; i < 4; ++i) {
      int b4 = (t >> 6) * 64 + 256 * i;
      GLOAD_LDS16(hinu + (size_t)(t + 256 * i) * 4, (uint32_t*)Hs + b4 * 4);
    }
    const uint32_t* wsrc = Wencp + ((size_t)dir * 128 + cg) * 4096;
    for (int i = 0; i < 4; ++i) {
      int b4 = (t >> 6) * 64 + 256 * i;
      GLOAD_LDS16(wsrc + (size_t)(t + 256 * i) * 4, (uint32_t*)Ws + b4 * 4);
    }
  }
  {
    int cl = t & 15, rl = t >> 4;
    int colg = (cl >> 2) * 512 + u0 + (cl & 3);
    GLOAD_LDS4(XF + (size_t)((r0 + rl) * 64 + ta) * 2048 + colg,
               zx + (t >> 6) * 64);
  }
  __syncthreads();
  const int lane = t & 63, w = t >> 6;
  const int quad = lane >> 4, l15 = lane & 15;
  f32x4 acc = {};
#pragma unroll
  for (int mm = 0; mm < 4; ++mm) {
    int m = w * 4 + mm;                          // K-chunk m*32..m*32+31
    int slot = m * 4 + quad;
    bf16x8 a = *(const bf16x8*)(Hs + l15 * 512 + (slot ^ (l15 & 7)) * 8);
    bf16x8 b = *(const bf16x8*)(Ws + l15 * 512 + (slot ^ (l15 & 7)) * 8);
    acc = __builtin_amdgcn_mfma_f32_16x16x32_bf16(a, b, acc, 0, 0, 0);
  }
#pragma unroll
  for (int reg = 0; reg < 4; ++reg)
    zp[w * 256 + (quad * 4 + reg) * 16 + l15] = acc[reg];
  __syncthreads();
  zbuf[t] = zp[t] + zp[256 + t] + zp[512 + t] + zp[768 + t] + zx[t];
  __syncthreads();
  if (t < 64) {
    int rl = t & 15, ui = t >> 4;
    int u = u0 + ui, r = r0 + rl;
    float zi = zbuf[rl * 16 + ui];
    float zf = zbuf[rl * 16 + 4 + ui];
    float zg = zbuf[rl * 16 + 8 + ui];
    float zo = zbuf[rl * 16 + 12 + ui];
    float cold = cst[u * 32 + r];
    float cn = sigm(zf) * cold + sigm(zi) * tanhf_fast(zg);
    float h = sigm(zo) * tanhf_fast(cn);
    cst[u * 32 + r] = cn;
    aB[((size_t)r * 64 + ta) * 1024 + dir * 512 + u] = (ushort)bf1(h);
    hl[rl * 4 + ui] = h;
  }
  __syncthreads();
  if (t < 16) {
    int r = r0 + t;
    uint32_t lo = bpack(hl[t * 4 + 0], hl[t * 4 + 1]);
    uint32_t hi = bpack(hl[t * 4 + 2], hl[t * 4 + 3]);
    uint32_t* dst = hout + r * 256 + (((cg >> 1) ^ (r & 7)) * 4) + (cg & 1) * 2;
    *(uint2*)dst = make_uint2(lo, hi);
  }
}

// =====================================================================
// K5: aw1[m][j] = aB[m]@W1[:1024,j] + b1[j] via dot2, padded to 16 cols.
// Launched with 2048 blocks (one row each; loop degenerates).
// =====================================================================
__global__ __launch_bounds__(256) void k5_aw1(
    const ushort* __restrict__ aB, const uint32_t* __restrict__ W1pbAll,
    const float* __restrict__ b1, float* __restrict__ aw1)
{
  __shared__ uint32_t ar[512];
  __shared__ float ps[16 * 17];
  const int t = threadIdx.x;
  const uint32_t* aBu = (const uint32_t*)aB;
  for (int m = blockIdx.x; m < 2048; m += gridDim.x) {
    __syncthreads();
    *(uint2*)(&ar[t * 2]) = *(const uint2*)(aBu + (size_t)m * 512 + t * 2);
    __syncthreads();
    int j = t & 15, part = t >> 4;
    int jj = j < 10 ? j : 0;
    float s = 0.f;
#pragma unroll 8
    for (int q = part * 32; q < part * 32 + 32; ++q)
      s = dot2bf(ar[q], W1pbAll[q * 12 + jj], s);
    ps[part * 17 + j] = s;
    __syncthreads();
    if (t < 16) {
      float sum = 0.f;
      if (t < 10) {
        for (int p = 0; p < 16; ++p) sum += ps[p * 17 + t];
        sum += b1[t];
      }
      aw1[m * 16 + t] = sum;
    }
  }
}

// =====================================================================
// KA: A'T = (a @ Wxd)^T via MFMA bf16, output PACKED bf16 pairs.
// =====================================================================
__global__ __launch_bounds__(256) void kA_aprime(
    const ushort* __restrict__ WxdT, const ushort* __restrict__ aB,
    uint32_t* __restrict__ ApTb)
{
  __shared__ ushort As[128 * 64];
  __shared__ ushort Bs[128 * 64];
  const int t = threadIdx.x;
  const int lane = t & 63, w = t >> 6;
  const int wr = w >> 1, wc = w & 1;
  const int m0 = blockIdx.y * 128, n0 = blockIdx.x * 128;
  const int lrow = lane >> 3, s = lane & 7;
  const int quad = lane >> 4, l15 = lane & 15;
  f32x4 acc[4][4] = {};
  for (int kc = 0; kc < 16; ++kc) {
    const int k0 = kc * 64;
    __syncthreads();
    for (int i = 0; i < 4; ++i) {
      int row = w * 32 + i * 8 + lrow;
      int k8 = s ^ (row & 7);
      GLOAD_LDS16(WxdT + (size_t)(m0 + row) * 1024 + k0 + k8 * 8,
                  As + (w * 32 + i * 8) * 64);
      GLOAD_LDS16(aB + (size_t)(n0 + row) * 1024 + k0 + k8 * 8,
                  Bs + (w * 32 + i * 8) * 64);
    }
    __syncthreads();
#pragma unroll
    for (int ks = 0; ks < 2; ++ks) {
      bf16x8 af[4], bfr[4];
      int kq = ks * 4 + quad;
#pragma unroll
      for (int mi = 0; mi < 4; ++mi) {
        int row = wr * 64 + mi * 16 + l15;
        int slot = kq ^ (row & 7);
        af[mi] = *(const bf16x8*)(As + row * 64 + slot * 8);
      }
#pragma unroll
      for (int ni = 0; ni < 4; ++ni) {
        int row = wc * 64 + ni * 16 + l15;
        int slot = kq ^ (row & 7);
        bfr[ni] = *(const bf16x8*)(Bs + row * 64 + slot * 8);
      }
#pragma unroll
      for (int mi = 0; mi < 4; ++mi)
#pragma unroll
        for (int ni = 0; ni < 4; ++ni)
          acc[mi][ni] = __builtin_amdgcn_mfma_f32_16x16x32_bf16(
              af[mi], bfr[ni], acc[mi][ni], 0, 0, 0);
    }
  }
#pragma unroll
  for (int mi = 0; mi < 4; ++mi) {
    int mbase = m0 + wr * 64 + mi * 16 + quad * 4;
#pragma unroll
    for (int reg = 0; reg < 4; ++reg) {
      int m = mbase + reg;
#pragma unroll
      for (int ni = 0; ni < 4; ++ni) {
        int n = n0 + wc * 64 + ni * 16 + l15;
        float v = acc[mi][ni][reg];
        float v2 = __shfl_xor(v, 1);
        if (!(l15 & 1))
          ApTb[(size_t)m * 1024 + (n >> 1)] = bpack(v, v2);
      }
    }
  }
}

// =====================================================================
// K4: FUSED decoder step, 512 blocks = 64 unit-groups x 8 row-groups
// (4 rows each). ~63 KB LDS -> 2 blocks/CU co-resident.
// hw1 reduce two-stage (serial chain 64 -> 20).
// =====================================================================
__global__ __launch_bounds__(256) void k4_dec_step(
    const uint32_t* __restrict__ ApTb, const float* __restrict__ aw1,
    const uint32_t* __restrict__ W1pb, const float* __restrict__ W2,
    const float* __restrict__ b2, const uint32_t* __restrict__ hdp_in,
    const uint32_t* __restrict__ Wdp, const float* __restrict__ bd,
    uint32_t* __restrict__ hdp_out, float* __restrict__ cd,
    ushort* __restrict__ HsB, int step)
{
  __shared__ uint32_t W1s[256 * 12];   // bf16-paired W1 rows (decoder half)
  __shared__ uint32_t hdT[1024];       // hd quads, 4-row slice [q4][4 r][4]
  __shared__ uint32_t Wsp[8192];       // Whd slab quads [q4][32 cc][4]
  __shared__ float ph[64 * 4 * 12];
  __shared__ float ph2[160];
  __shared__ float hw1[4 * 12];
  __shared__ float esc[4 * 65];
  __shared__ uint32_t escp[4 * 33];
  __shared__ float pm[4 * 9];
  __shared__ float mrow[4], srow[4];
  __shared__ float w2s[12];
  __shared__ float zp[2][128];
  __shared__ float zbuf[4 * 33];
  __shared__ float hl[32];
  const int t = threadIdx.x;
  const int ug = blockIdx.x >> 3;      // unit group: units u0..u0+7
  const int rg = blockIdx.x & 7;       // row group: rows r0..r0+3
  const int u0 = ug * 8, r0 = rg * 4;
  for (int i = 0; i < 3; ++i) {
    int b4 = (t >> 6) * 64 + 256 * i;
    GLOAD_LDS16(W1pb + (size_t)(t + 256 * i) * 4, W1s + (size_t)b4 * 4);
  }
  {
    int q4 = t >> 2, rl0 = t & 3;
    int b4 = (t >> 6) * 64;
    GLOAD_LDS16(hdp_in + (size_t)(q4 * 32 + r0 + rl0) * 4, hdT + (size_t)b4 * 4);
  }
  if (t < 12) w2s[t] = (t < 10) ? W2[t] : 0.f;
  __syncthreads();
  {
    const uint32_t* wsrc = Wdp + (size_t)ug * 8192;
    for (int i = 0; i < 8; ++i) {
      int b4 = (t >> 6) * 64 + 256 * i;
      GLOAD_LDS16(wsrc + (size_t)(t + 256 * i) * 4, Wsp + (size_t)b4 * 4);
    }
  }
  // ---- hw1 = hd @ W1[1024:1536, :10] for 4 rows; 64 k-parts ----
  {
    const int rl = t & 3, kp = t >> 2;
    const uint4* hd4 = (const uint4*)hdT;
    float acc[10] = {};
    {
      uint4 u4 = hd4[kp * 4 + rl];
      const uint32_t* w0 = &W1s[(4 * kp) * 12];
      const uint32_t* w1 = &W1s[(4 * kp + 1) * 12];
      const uint32_t* w2p = &W1s[(4 * kp + 2) * 12];
      const uint32_t* w3 = &W1s[(4 * kp + 3) * 12];
#pragma unroll
      for (int j = 0; j < 10; ++j) {
        acc[j] = dot2bf(u4.x, w0[j], acc[j]);
        acc[j] = dot2bf(u4.y, w1[j], acc[j]);
        acc[j] = dot2bf(u4.z, w2p[j], acc[j]);
        acc[j] = dot2bf(u4.w, w3[j], acc[j]);
      }
    }
#pragma unroll
    for (int j = 0; j < 10; ++j) ph[(kp * 4 + rl) * 12 + j] = acc[j];
  }
  __syncthreads();
  // two-stage reduce: 160 thr x 16 kp-terms, then 40 thr x 4
  if (t < 160) {
    int g = t / 40, rem = t - g * 40;
    int rl = rem / 10, j = rem % 10;
    float s = 0.f;
#pragma unroll
    for (int p = 0; p < 16; ++p)
      s += ph[((g * 16 + p) * 4 + rl) * 12 + j];
    ph2[t] = s;
  }
  __syncthreads();
  if (t < 40) {
    hw1[(t / 10) * 12 + (t % 10)] =
        ph2[t] + ph2[40 + t] + ph2[80 + t] + ph2[120 + t];
  }
  __syncthreads();
  // ---- scores (fast tanh), 4 rows x 64 tt = 1 per thread ----
  const float b2v = b2[0];
  {
    int rl = t >> 6, tt = t & 63;
    size_t m = (size_t)(r0 + rl) * 64 + tt;
    const float4* aw = (const float4*)(aw1 + m * 16);
    float4 q0 = aw[0], q1 = aw[1], q2 = aw[2];
    const float* hw = &hw1[rl * 12];
    float e = b2v;
    e += tanhf_fast(q0.x + hw[0]) * w2s[0];
    e += tanhf_fast(q0.y + hw[1]) * w2s[1];
    e += tanhf_fast(q0.z + hw[2]) * w2s[2];
    e += tanhf_fast(q0.w + hw[3]) * w2s[3];
    e += tanhf_fast(q1.x + hw[4]) * w2s[4];
    e += tanhf_fast(q1.y + hw[5]) * w2s[5];
    e += tanhf_fast(q1.z + hw[6]) * w2s[6];
    e += tanhf_fast(q1.w + hw[7]) * w2s[7];
    e += tanhf_fast(q2.x + hw[8]) * w2s[8];
    e += tanhf_fast(q2.y + hw[9]) * w2s[9];
    esc[rl * 65 + tt] = fmaxf(e, 0.f);
  }
  __syncthreads();
  if (t < 32) {
    int rl = t >> 3, part = t & 7;
    float m = -1e30f;
    for (int i = 0; i < 8; ++i) m = fmaxf(m, esc[rl * 65 + part * 8 + i]);
    pm[rl * 9 + part] = m;
  }
  __syncthreads();
  if (t < 4) {
    float m = pm[t * 9];
    for (int p = 1; p < 8; ++p) m = fmaxf(m, pm[t * 9 + p]);
    mrow[t] = m;
  }
  __syncthreads();
  if (t < 32) {
    int rl = t >> 3, part = t & 7;
    float m = mrow[rl];
    float s = 0.f;
    for (int i = 0; i < 8; ++i) s += __expf(esc[rl * 65 + part * 8 + i] - m);
    pm[rl * 9 + part] = s;
  }
  __syncthreads();
  if (t < 4) {
    float s = 0.f;
    for (int p = 0; p < 8; ++p) s += pm[t * 9 + p];
    srow[t] = __fdividef(1.f, s);
  }
  __syncthreads();
  if (t < 128) {
    int rl = t >> 5, q = t & 31;
    float m = mrow[rl], s = srow[rl];
    float v0 = __expf(esc[rl * 65 + 2 * q] - m) * s;
    float v1 = __expf(esc[rl * 65 + 2 * q + 1] - m) * s;
    escp[rl * 33 + q] = bpack(v0, v1);
  }
  __syncthreads();
  // ---- z = score@A'Tb + hd@Whd + bd (32 cols x 4 rows, K-split) ----
  {
    const int out = t & 127;
    const int ccB = out >> 2, rl = out & 3;
    const int kh = t >> 7;
    const int colg = (ccB >> 3) * 512 + u0 + (ccB & 7);
    float acc = 0.f;
    {
      const uint4* hd4 = (const uint4*)hdT;
      const uint4* wd4 = (const uint4*)Wsp;
#pragma unroll 8
      for (int q4 = kh * 32; q4 < kh * 32 + 32; ++q4) {
        uint4 ua = hd4[q4 * 4 + rl];
        uint4 ub = wd4[q4 * 32 + ccB];
        acc = dot2bf(ua.x, ub.x, acc);
        acc = dot2bf(ua.y, ub.y, acc);
        acc = dot2bf(ua.z, ub.z, acc);
        acc = dot2bf(ua.w, ub.w, acc);
      }
    }
    {
      const uint32_t* ap = ApTb + (size_t)colg * 1024 + (r0 + rl) * 32;
      const uint32_t* ep = &escp[rl * 33];
#pragma unroll
      for (int i8 = kh * 4; i8 < kh * 4 + 4; ++i8) {
        uint4 v = *(const uint4*)(ap + i8 * 4);
        acc = dot2bf(v.x, ep[4 * i8 + 0], acc);
        acc = dot2bf(v.y, ep[4 * i8 + 1], acc);
        acc = dot2bf(v.z, ep[4 * i8 + 2], acc);
        acc = dot2bf(v.w, ep[4 * i8 + 3], acc);
      }
    }
    zp[kh][out] = acc;
  }
  __syncthreads();
  if (t < 128) {
    int ccB = t >> 2, rl = t & 3;
    int colg = (ccB >> 3) * 512 + u0 + (ccB & 7);
    zbuf[rl * 33 + ccB] = zp[0][t] + zp[1][t] + bd[colg];
  }
  __syncthreads();
  if (t < 32) {
    int j = t >> 2, rr = t & 3;
    int u = u0 + j, rgl = r0 + rr;
    float zi = zbuf[rr * 33 + j];
    float zf = zbuf[rr * 33 + 8 + j];
    float zg = zbuf[rr * 33 + 16 + j];
    float zo = zbuf[rr * 33 + 24 + j];
    float cold = cd[u * 32 + rgl];
    float cn = sigm(zf) * cold + sigm(zi) * tanhf_fast(zg);
    float h = sigm(zo) * tanhf_fast(cn);
    cd[u * 32 + rgl] = cn;
    HsB[(size_t)(step * 32 + rgl) * 512 + u] = (ushort)bf1(h);
    hl[j * 4 + rr] = h;
  }
  __syncthreads();
  if (t < 16) {
    int p = t >> 2, rr = t & 3;
    hdp_out[ug * 128 + (r0 + rr) * 4 + p] =
        bpack(hl[(2 * p) * 4 + rr], hl[(2 * p + 1) * 4 + rr]);
  }
}

// =====================================================================
// K6: logits = HsB[2048,512] @ WoT^T + bo via MFMA bf16.
// m-tile offset moff lets the launch run in row-halves (L3 reuse).
// Epilogue emits per-(outrow, ntile) softmax partials (two-stage combine).
// =====================================================================
__global__ __launch_bounds__(256) void k6_logits_mfma(
    const ushort* __restrict__ HsB, const ushort* __restrict__ WoT,
    const float* __restrict__ bo, float* __restrict__ out,
    float2* __restrict__ pstats, int moff)
{
  __shared__ ushort As[128 * 64];
  __shared__ ushort Bs[128 * 64];
  __shared__ float pm2[256], sm2[256];
  const int t = threadIdx.x;
  const int lane = t & 63, w = t >> 6;
  const int wr = w >> 1, wc = w & 1;
  const int m0 = (blockIdx.y + moff) * 128, n0 = blockIdx.x * 128;
  const int lrow = lane >> 3, s = lane & 7;
  const int quad = lane >> 4, l15 = lane & 15;
  f32x4 acc[4][4] = {};
  for (int kc = 0; kc < 8; ++kc) {
    const int k0 = kc * 64;
    __syncthreads();
    for (int i = 0; i < 4; ++i) {
      int row = w * 32 + i * 8 + lrow;
      int k8 = s ^ (row & 7);
      GLOAD_LDS16(HsB + (size_t)(m0 + row) * 512 + k0 + k8 * 8,
                  As + (w * 32 + i * 8) * 64);
      GLOAD_LDS16(WoT + (size_t)(n0 + row) * 512 + k0 + k8 * 8,
                  Bs + (w * 32 + i * 8) * 64);
    }
    __syncthreads();
#pragma unroll
    for (int ks = 0; ks < 2; ++ks) {
      bf16x8 af[4], bfr[4];
      int kq = ks * 4 + quad;
#pragma unroll
      for (int mi = 0; mi < 4; ++mi) {
        int row = wr * 64 + mi * 16 + l15;
        int slot = kq ^ (row & 7);
        af[mi] = *(const bf16x8*)(As + row * 64 + slot * 8);
      }
#pragma unroll
      for (int ni = 0; ni < 4; ++ni) {
        int row = wc * 64 + ni * 16 + l15;
        int slot = kq ^ (row & 7);
        bfr[ni] = *(const bf16x8*)(Bs + row * 64 + slot * 8);
      }
#pragma unroll
      for (int mi = 0; mi < 4; ++mi)
#pragma unroll
        for (int ni = 0; ni < 4; ++ni)
          acc[mi][ni] = __builtin_amdgcn_mfma_f32_16x16x32_bf16(
              af[mi], bfr[ni], acc[mi][ni], 0, 0, 0);
    }
  }
  __syncthreads();                    // As/Bs dead; reuse as partial arrays
  float* pmx = (float*)As;            // [128 rows][32 slots]
  float* psm = (float*)Bs;
  float bon[4];
#pragma unroll
  for (int ni = 0; ni < 4; ++ni)
    bon[ni] = bo[n0 + wc * 64 + ni * 16 + l15];
#pragma unroll
  for (int mi = 0; mi < 4; ++mi) {
    int mbase = m0 + wr * 64 + mi * 16 + quad * 4;
#pragma unroll
    for (int reg = 0; reg < 4; ++reg) {
      int m = mbase + reg;
      int rowl = (m - m0);
      size_t rowbase = ((size_t)(m & 31) * 64 + (m >> 5)) * 32000;
      float vs[4];
      float mx = -1e30f;
#pragma unroll
      for (int ni = 0; ni < 4; ++ni) {
        int n = n0 + wc * 64 + ni * 16 + l15;
        float v = acc[mi][ni][reg] + bon[ni];
        out[rowbase + n] = v;
        vs[ni] = v;
        mx = fmaxf(mx, v);
      }
      float sl = __expf(vs[0] - mx) + __expf(vs[1] - mx) +
                 __expf(vs[2] - mx) + __expf(vs[3] - mx);
      pmx[rowl * 32 + wc * 16 + l15] = mx;
      psm[rowl * 32 + wc * 16 + l15] = sl;
    }
  }
  __syncthreads();
  // two-stage combine: 256 thr x 16 slots, then 128 thr x 2
  {
    int rowl = t >> 1, hh = (t & 1) * 16;
    float m = pmx[rowl * 32 + hh], sacc = psm[rowl * 32 + hh];
    for (int i = 1; i < 16; ++i) {
      float m2 = pmx[rowl * 32 + hh + i], s2 = psm[rowl * 32 + hh + i];
      float mn = fmaxf(m, m2);
      sacc = sacc * __expf(m - mn) + s2 * __expf(m2 - mn);
      m = mn;
    }
    pm2[t] = m;
    sm2[t] = sacc;
  }
  __syncthreads();
  if (t < 128) {
    float m1 = pm2[2 * t], m2 = pm2[2 * t + 1];
    float mn = fmaxf(m1, m2);
    float sacc = sm2[2 * t] * __expf(m1 - mn) + sm2[2 * t + 1] * __expf(m2 - mn);
    int mg = m0 + t;
    int outrow = (mg & 31) * 64 + (mg >> 5);
    pstats[(size_t)outrow * 256 + blockIdx.x] = make_float2(mn, sacc);
  }
}

// =====================================================================
// K7: row softmax normalize for one m-half (1024 rows), using pstats.
// =====================================================================
__global__ __launch_bounds__(256) void k7_softmax(
    float* __restrict__ out, const float2* __restrict__ pstats, int half)
{
  __shared__ float mred[256], sred[256];
  const int t = threadIdx.x;
  const int mg = half * 1024 + blockIdx.x;
  const int row = (mg & 31) * 64 + (mg >> 5);
  float m = -1e30f, s = 0.f;
  if (t < 250) {
    float2 p = pstats[(size_t)row * 256 + t];
    m = p.x;
    s = p.y;
  }
  mred[t] = m;
  sred[t] = s;
  __syncthreads();
  for (int st = 128; st > 0; st >>= 1) {
    if (t < st) {
      float m1 = mred[t], m2 = mred[t + st];
      float mn = fmaxf(m1, m2);
      sred[t] = sred[t] * __expf(m1 - mn) + sred[t + st] * __expf(m2 - mn);
      mred[t] = mn;
    }
    __syncthreads();
  }
  m = mred[0];
  const float inv = 1.f / sred[0];
  float* p = out + (size_t)row * 32000;
  for (int i = t; i < 8000; i += 256) {
    float4 v = *(const float4*)(p + i * 4);
    v.x = __expf(v.x - m) * inv;
    v.y = __expf(v.y - m) * inv;
    v.z = __expf(v.z - m) * inv;
    v.w = __expf(v.w - m) * inv;
    *(float4*)(p + i * 4) = v;
  }
}

// =====================================================================
extern "C" void kernel_launch(void* const* d_in, const int* in_sizes, int n_in,
                              void* d_out, int out_size, void* d_ws, size_t ws_size,
                              hipStream_t stream)
{
  const int* x = (const int*)d_in[0];
  const float* emb = (const float*)d_in[1];
  const float* Wxf = (const float*)d_in[2];
  const float* Whf = (const float*)d_in[3];
  const float* bfv = (const float*)d_in[4];
  const float* Wxb = (const float*)d_in[5];
  const float* Whb = (const float*)d_in[6];
  const float* bbv = (const float*)d_in[7];
  const float* W1 = (const float*)d_in[8];
  const float* b1 = (const float*)d_in[9];
  const float* W2 = (const float*)d_in[10];
  const float* b2 = (const float*)d_in[11];
  const float* Wxd = (const float*)d_in[12];
  const float* Whd = (const float*)d_in[13];
  const float* bd = (const float*)d_in[14];
  const float* Wo = (const float*)d_in[15];
  const float* bo = (const float*)d_in[16];

  float* ws = (float*)d_ws;
  // layout (float offsets)
  float* c_f = ws + 0;
  float* c_b = ws + 16384;
  float* c_d = ws + 32768;
  uint32_t* hfp0 = (uint32_t*)(ws + 49152);   // 32KB: [32 r][512 u] bf16 swz
  uint32_t* hfp1 = hfp0 + 8192;
  uint32_t* hbp0 = (uint32_t*)(ws + 65536);
  uint32_t* hbp1 = hbp0 + 8192;
  uint32_t* hdp0 = (uint32_t*)(ws + 81920);
  uint32_t* hdp1 = hdp0 + 8192;
  uint32_t* W1pbAll = (uint32_t*)(ws + 98304);     // 9216 u32 (paired full W1)
  uint32_t* Wencp = (uint32_t*)(ws + 114688);      // 1,048,576 u32 (4 MB)
  uint32_t* Wdp = (uint32_t*)(ws + 1163264);       // 524,288 u32 (Whd slabs)
  ushort* aB = (ushort*)(ws + 1687552);            // 2048x1024 bf16
  float* aw1 = ws + 2742272;                       // 32768
  float* Xf = ws + 2775040;                        // 2048x2048 fp32 [token][col]
  float* Xb = Xf + 4194304;                        // 2048x2048 fp32
  ushort* WxfT = (ushort*)(ws + 11163648);         // 2048x256 bf16
  ushort* WxbT = (ushort*)(ws + 11425792);         // 2048x256 bf16
  ushort* HsB = (ushort*)(ws + 13260800);          // 2048*512 bf16
  // post-encoder overlays:
  uint32_t* ApTb = (uint32_t*)Xf;                  // 2048x1024 u32 bf16-pairs
  ushort* WxdT = (ushort*)Xb;                      // 2048x1024 bf16
  ushort* WoT = (ushort*)Xf;                       // overlays after decoder
  float2* pstats = (float2*)Wencp;                 // 2048x256 float2 (dead Wencp)

  // zero recurrent states (c_f, c_b, c_d, packed h buffers)
  hipMemsetAsync(ws, 0, 98304 * sizeof(float), stream);

  k0_pack<<<6180, 256, 0, stream>>>(Whf, Whb, Wencp, Whd, Wdp, W1, W1pbAll);
  k_wTx<<<dim3(32, 8), 256, 0, stream>>>(Wxf, WxfT, Wxb, WxbT);

  k1_embed_mfma<<<dim3(32, 16), 256, 0, stream>>>(x, emb, WxfT, WxbT,
                                                  bfv, bbv, Xf, Xb);

  for (int s = 0; s < 64; ++s) {
    const uint32_t* hfi = (s & 1) ? hfp1 : hfp0;
    uint32_t* hfo = (s & 1) ? hfp0 : hfp1;
    const uint32_t* hbi = (s & 1) ? hbp1 : hbp0;
    uint32_t* hbo = (s & 1) ? hbp0 : hbp1;
    k2_enc_step<<<512, 256, 0, stream>>>(Xf, Xb, Wencp, hfi, hfo, hbi, hbo,
                                         c_f, c_b, aB, s);
  }

  k5_aw1<<<2048, 256, 0, stream>>>(aB, W1pbAll, b1, aw1);
  k_wT<<<dim3(32, 16), 256, 0, stream>>>(Wxd, WxdT, 1024, 2048);
  kA_aprime<<<dim3(16, 16), 256, 0, stream>>>(WxdT, aB, ApTb);

  for (int s = 0; s < 64; ++s) {
    const uint32_t* hdi = (s & 1) ? hdp1 : hdp0;
    uint32_t* hdo = (s & 1) ? hdp0 : hdp1;
    k4_dec_step<<<512, 256, 0, stream>>>(ApTb, aw1, W1pbAll + 6144, W2, b2,
                                         hdi, Wdp, bd, hdo, c_d, HsB, s);
  }

  k_wT<<<dim3(500, 8), 256, 0, stream>>>(Wo, WoT, 512, 32000);
  // row-half split: each half's 131 MB of logits stays L3-resident
  // between its k6 (producer) and k7 (normalize) launches.
  k6_logits_mfma<<<dim3(250, 8), 256, 0, stream>>>(HsB, WoT, bo,
                                                   (float*)d_out, pstats, 0);
  k7_softmax<<<1024, 256, 0, stream>>>((float*)d_out, pstats, 0);
  k6_logits_mfma<<<dim3(250, 8), 256, 0, stream>>>(HsB, WoT, bo,
                                                   (float*)d_out, pstats, 8);
  k7_softmax<<<1024, 256, 0, stream>>>((float*)d_out, pstats, 1);
}